// Round 1
// baseline (269.107 us; speedup 1.0000x reference)
//
#include <hip/hip_runtime.h>

#define TOK 4096
#define EMB 1024

typedef __attribute__((ext_vector_type(8))) short s16x8;
typedef __attribute__((ext_vector_type(4))) float f32x4;

__device__ __forceinline__ unsigned short f2bf(float f) {
  union { float f; unsigned int u; } v; v.f = f;
  unsigned int r = v.u + 0x7FFFu + ((v.u >> 16) & 1u);
  return (unsigned short)(r >> 16);
}

#define GLOAD_LDS16(g, l) __builtin_amdgcn_global_load_lds( \
    (const __attribute__((address_space(1))) void*)(g), \
    (__attribute__((address_space(3))) void*)(l), 16, 0, 0)

// ---------------- GEMM: C[M,N] = A[M,K] @ B[N,K]^T (+bias, +res, relu, dtype)
// m97 structure: 128x128 tile, BK=64, 4 waves in 2x2, 4x4 16x16x32 frags each.
template<int OUT_BF16, int RELU, int ADD_RES>
__global__ __launch_bounds__(256)
void gemm_bt(const unsigned short* __restrict__ A,
             const unsigned short* __restrict__ B,
             const float* __restrict__ bias,
             const float* __restrict__ res,
             void* __restrict__ Cout, int M, int N, int K)
{
  __shared__ unsigned short As[128 * 64];
  __shared__ unsigned short Bs[128 * 64];
  const int tid = threadIdx.x;
  const int lane = tid & 63;
  const int w = tid >> 6;
  const int wr = w >> 1, wc = w & 1;
  const int l15 = lane & 15, lhi = lane >> 4;
  const int nbm = M >> 7;
  const int bm = blockIdx.x % nbm;
  const int bn = blockIdx.x / nbm;
  const int m0 = bm << 7, n0 = bn << 7;

  f32x4 acc[4][4];
#pragma unroll
  for (int m = 0; m < 4; ++m)
#pragma unroll
    for (int n = 0; n < 4; ++n)
#pragma unroll
      for (int j = 0; j < 4; ++j) acc[m][n][j] = 0.f;

  const int trow = tid >> 3, tcol = (tid & 7) << 3;
  const unsigned short* Ag = A + (size_t)(m0 + trow) * K + tcol;
  const unsigned short* Bg = B + (size_t)(n0 + trow) * K + tcol;
  unsigned short* Adst = As + (w << 9);   // wave-uniform LDS base
  unsigned short* Bdst = Bs + (w << 9);

  for (int kt = 0; kt < K; kt += 64) {
    __syncthreads();   // prev compute done reading LDS
#pragma unroll
    for (int i = 0; i < 4; ++i) {
      GLOAD_LDS16(Ag + (size_t)(i * 32) * K + kt, Adst + i * 2048);
      GLOAD_LDS16(Bg + (size_t)(i * 32) * K + kt, Bdst + i * 2048);
    }
    __syncthreads();   // drains vmcnt before barrier
#pragma unroll
    for (int ks = 0; ks < 2; ++ks) {
      s16x8 af[4], bfr[4];
#pragma unroll
      for (int m = 0; m < 4; ++m)
        af[m] = *(const s16x8*)(As + ((wr * 64 + m * 16 + l15) << 6) + ks * 32 + lhi * 8);
#pragma unroll
      for (int n = 0; n < 4; ++n)
        bfr[n] = *(const s16x8*)(Bs + ((wc * 64 + n * 16 + l15) << 6) + ks * 32 + lhi * 8);
#pragma unroll
      for (int m = 0; m < 4; ++m)
#pragma unroll
        for (int n = 0; n < 4; ++n)
          acc[m][n] = __builtin_amdgcn_mfma_f32_16x16x32_bf16(af[m], bfr[n], acc[m][n], 0, 0, 0);
    }
  }

#pragma unroll
  for (int m = 0; m < 4; ++m) {
    const int row = m0 + wr * 64 + m * 16 + lhi * 4;
#pragma unroll
    for (int n = 0; n < 4; ++n) {
      const int col = n0 + wc * 64 + n * 16 + l15;
      const float bv = bias[col];
#pragma unroll
      for (int j = 0; j < 4; ++j) {
        float v = acc[m][n][j] + bv;
        if (RELU) v = fmaxf(v, 0.f);
        if (ADD_RES) v += res[(size_t)(row + j) * N + col];
        if (OUT_BF16)
          ((unsigned short*)Cout)[(size_t)(row + j) * N + col] = f2bf(v);
        else
          ((float*)Cout)[(size_t)(row + j) * N + col] = v;
      }
    }
  }
}

// ---------------- LayerNorm fp32 -> bf16 (one block per row of 1024)
__global__ __launch_bounds__(256)
void ln_bf16(const float* __restrict__ x, const float* __restrict__ wt,
             const float* __restrict__ bs, unsigned short* __restrict__ out)
{
  const int row = blockIdx.x;
  const int t = threadIdx.x;
  const float4 v = ((const float4*)(x + (size_t)row * EMB))[t];
  float s = v.x + v.y + v.z + v.w;
  float s2 = v.x * v.x + v.y * v.y + v.z * v.z + v.w * v.w;
#pragma unroll
  for (int off = 1; off < 64; off <<= 1) { s += __shfl_xor(s, off); s2 += __shfl_xor(s2, off); }
  __shared__ float red[8];
  if ((t & 63) == 0) { red[t >> 6] = s; red[4 + (t >> 6)] = s2; }
  __syncthreads();
  s = red[0] + red[1] + red[2] + red[3];
  s2 = red[4] + red[5] + red[6] + red[7];
  const float mu = s * (1.f / EMB);
  const float rs = rsqrtf(s2 * (1.f / EMB) - mu * mu + 1e-5f);
  const float4 wv = ((const float4*)wt)[t];
  const float4 bv = ((const float4*)bs)[t];
  ushort4 o;
  o.x = f2bf((v.x - mu) * rs * wv.x + bv.x);
  o.y = f2bf((v.y - mu) * rs * wv.y + bv.y);
  o.z = f2bf((v.z - mu) * rs * wv.z + bv.z);
  o.w = f2bf((v.w - mu) * rs * wv.w + bv.w);
  ((ushort4*)(out + (size_t)row * EMB))[t] = o;
}

// ---------------- fp32 -> bf16 weight conversion
__global__ __launch_bounds__(256)
void cvt_bf16(const float* __restrict__ in, unsigned short* __restrict__ out, int n4)
{
  const int i = blockIdx.x * 256 + threadIdx.x;
  if (i >= n4) return;
  const float4 v = ((const float4*)in)[i];
  ushort4 o;
  o.x = f2bf(v.x); o.y = f2bf(v.y); o.z = f2bf(v.z); o.w = f2bf(v.w);
  ((ushort4*)out)[i] = o;
}

// ---------------- sliding-window causal attention, flash-style
// grid (T/64, B*H); 4 waves x 16 q-rows; 5 K-tiles of 64 in window.
__global__ __launch_bounds__(256)
void attn_win(const unsigned short* __restrict__ qkv, unsigned short* __restrict__ aout)
{
  __shared__ unsigned short Ks[64 * 136];  // K tile, pad 128->136
  __shared__ unsigned short Vt[128 * 72];  // V^T tile, pad 64->72
  __shared__ unsigned short Ps[4 * 16 * 72];
  const int bh = blockIdx.y;
  const int b = bh >> 3, hh = bh & 7;
  const int q0 = blockIdx.x << 6;
  const int tid = threadIdx.x, lane = tid & 63, w = tid >> 6;
  const int l15 = lane & 15, lhi = lane >> 4;
  const size_t base = (size_t)b * 2048 * 3072;

  s16x8 qf[4];
  {
    const unsigned short* qp = qkv + base + (size_t)(q0 + w * 16 + l15) * 3072 + hh * 128 + lhi * 8;
#pragma unroll
    for (int ks = 0; ks < 4; ++ks) qf[ks] = *(const s16x8*)(qp + ks * 32);
  }

  f32x4 o[8];
#pragma unroll
  for (int n = 0; n < 8; ++n)
#pragma unroll
    for (int j = 0; j < 4; ++j) o[n][j] = 0.f;
  float mrow[4] = {-1e30f, -1e30f, -1e30f, -1e30f};
  float lrow[4] = {0.f, 0.f, 0.f, 0.f};

  for (int t = 0; t < 5; ++t) {
    const int kt0 = q0 - 256 + t * 64;
    if (kt0 < 0) continue;          // block-uniform
    __syncthreads();
    {
      const unsigned short* kg = qkv + base + (size_t)kt0 * 3072 + 1024 + hh * 128;
#pragma unroll
      for (int i = 0; i < 4; ++i) {
        const int c = tid + i * 256;
        const int r = c >> 4, cc = (c & 15) << 3;
        *(s16x8*)(Ks + r * 136 + cc) = *(const s16x8*)(kg + (size_t)r * 3072 + cc);
      }
      const unsigned short* vg = qkv + base + (size_t)kt0 * 3072 + 2048 + hh * 128;
#pragma unroll
      for (int i = 0; i < 2; ++i) {
        const int c = tid + i * 256;
        const int r2 = c >> 4, cc = (c & 15) << 3;
        s16x8 v0 = *(const s16x8*)(vg + (size_t)(2 * r2) * 3072 + cc);
        s16x8 v1 = *(const s16x8*)(vg + (size_t)(2 * r2 + 1) * 3072 + cc);
#pragma unroll
        for (int jj = 0; jj < 8; ++jj) {
          unsigned int pk = (unsigned int)(unsigned short)v0[jj] |
                            ((unsigned int)(unsigned short)v1[jj] << 16);
          *(unsigned int*)(Vt + (cc + jj) * 72 + 2 * r2) = pk;
        }
      }
    }
    __syncthreads();

    f32x4 s[4];
#pragma unroll
    for (int n = 0; n < 4; ++n)
#pragma unroll
      for (int j = 0; j < 4; ++j) s[n][j] = 0.f;
#pragma unroll
    for (int ks = 0; ks < 4; ++ks) {
#pragma unroll
      for (int n = 0; n < 4; ++n) {
        s16x8 kf = *(const s16x8*)(Ks + (n * 16 + l15) * 136 + ks * 32 + lhi * 8);
        s[n] = __builtin_amdgcn_mfma_f32_16x16x32_bf16(qf[ks], kf, s[n], 0, 0, 0);
      }
    }
    const bool mlo = (t == 0);        // window lower bound: keep kcol >= qrow
    const bool mhi = (kt0 == q0);     // causal: keep kcol <= qrow
#pragma unroll
    for (int n = 0; n < 4; ++n) {
      const int kcol = n * 16 + l15;
#pragma unroll
      for (int j = 0; j < 4; ++j) {
        const int qrow = w * 16 + lhi * 4 + j;
        float v = s[n][j] * 0.08838834764831845f;  // 1/sqrt(128)
        if ((mlo && kcol < qrow) || (mhi && kcol > qrow)) v = -1e30f;
        s[n][j] = v;
      }
    }
    float alpha[4];
#pragma unroll
    for (int j = 0; j < 4; ++j) {
      float mx = fmaxf(fmaxf(s[0][j], s[1][j]), fmaxf(s[2][j], s[3][j]));
#pragma unroll
      for (int off = 1; off < 16; off <<= 1) mx = fmaxf(mx, __shfl_xor(mx, off));
      const float mn = fmaxf(mrow[j], mx);
      alpha[j] = __expf(mrow[j] - mn);
      mrow[j] = mn;
    }
    float rowsum[4] = {0.f, 0.f, 0.f, 0.f};
#pragma unroll
    for (int n = 0; n < 4; ++n)
#pragma unroll
      for (int j = 0; j < 4; ++j) {
        const float p = __expf(s[n][j] - mrow[j]);
        rowsum[j] += p;
        Ps[(w * 16 + lhi * 4 + j) * 72 + n * 16 + l15] = f2bf(p);
      }
#pragma unroll
    for (int j = 0; j < 4; ++j) {
      float rs = rowsum[j];
#pragma unroll
      for (int off = 1; off < 16; off <<= 1) rs += __shfl_xor(rs, off);
      lrow[j] = lrow[j] * alpha[j] + rs;
    }
#pragma unroll
    for (int n = 0; n < 8; ++n)
#pragma unroll
      for (int j = 0; j < 4; ++j) o[n][j] *= alpha[j];
#pragma unroll
    for (int ks = 0; ks < 2; ++ks) {
      const s16x8 pf = *(const s16x8*)(Ps + (w * 16 + l15) * 72 + ks * 32 + lhi * 8);
#pragma unroll
      for (int n = 0; n < 8; ++n) {
        const s16x8 vf = *(const s16x8*)(Vt + (n * 16 + l15) * 72 + ks * 32 + lhi * 8);
        o[n] = __builtin_amdgcn_mfma_f32_16x16x32_bf16(pf, vf, o[n], 0, 0, 0);
      }
    }
  }
  unsigned short* op = aout + (size_t)(b * 2048 + q0 + w * 16) * 1024 + hh * 128;
#pragma unroll
  for (int n = 0; n < 8; ++n)
#pragma unroll
    for (int j = 0; j < 4; ++j)
      op[(size_t)(lhi * 4 + j) * 1024 + n * 16 + l15] = f2bf(o[n][j] / lrow[j]);
}

extern "C" void kernel_launch(void* const* d_in, const int* in_sizes, int n_in,
                              void* d_out, int out_size, void* d_ws, size_t ws_size,
                              hipStream_t stream)
{
  (void)in_sizes; (void)n_in; (void)out_size; (void)ws_size;
  const float* x         = (const float*)d_in[0];
  const float* ln1_w     = (const float*)d_in[1];
  const float* ln1_b     = (const float*)d_in[2];
  const float* ln2_w     = (const float*)d_in[3];
  const float* ln2_b     = (const float*)d_in[4];
  const float* in_proj_w = (const float*)d_in[5];
  const float* in_proj_b = (const float*)d_in[6];
  const float* out_w     = (const float*)d_in[7];
  const float* out_b     = (const float*)d_in[8];
  const float* w1        = (const float*)d_in[9];
  const float* b1        = (const float*)d_in[10];
  const float* w2        = (const float*)d_in[11];
  const float* b2        = (const float*)d_in[12];
  float* out = (float*)d_out;

  char* ws = (char*)d_ws;
  unsigned short* h    = (unsigned short*)(ws);                 //  8 MiB  LN1 out bf16
  unsigned short* wqkv = (unsigned short*)(ws + (8u << 20));    //  6 MiB
  unsigned short* wout = (unsigned short*)(ws + (14u << 20));   //  2 MiB
  unsigned short* w1b  = (unsigned short*)(ws + (16u << 20));   //  8 MiB
  unsigned short* w2b  = (unsigned short*)(ws + (24u << 20));   //  8 MiB
  unsigned short* qkv  = (unsigned short*)(ws + (32u << 20));   // 24 MiB
  unsigned short* aout = (unsigned short*)(ws + (56u << 20));   //  8 MiB
  float*          h2   = (float*)(ws + (64u << 20));            // 16 MiB
  unsigned short* m_in = (unsigned short*)(ws + (80u << 20));   //  8 MiB
  unsigned short* act  = (unsigned short*)(ws + (88u << 20));   // 32 MiB (ends 120 MiB)

  cvt_bf16<<<dim3(3072 * 1024 / 4 / 256), 256, 0, stream>>>(in_proj_w, wqkv, 3072 * 1024 / 4);
  cvt_bf16<<<dim3(1024 * 1024 / 4 / 256), 256, 0, stream>>>(out_w, wout, 1024 * 1024 / 4);
  cvt_bf16<<<dim3(4096 * 1024 / 4 / 256), 256, 0, stream>>>(w1, w1b, 4096 * 1024 / 4);
  cvt_bf16<<<dim3(1024 * 4096 / 4 / 256), 256, 0, stream>>>(w2, w2b, 1024 * 4096 / 4);

  ln_bf16<<<dim3(TOK), 256, 0, stream>>>(x, ln1_w, ln1_b, h);
  gemm_bt<1, 0, 0><<<dim3(32 * 24), 256, 0, stream>>>(h, wqkv, in_proj_b, nullptr, qkv, 4096, 3072, 1024);
  attn_win<<<dim3(32, 16), 256, 0, stream>>>(qkv, aout);
  gemm_bt<0, 0, 1><<<dim3(32 * 8), 256, 0, stream>>>(aout, wout, out_b, x, h2, 4096, 1024, 1024);
  ln_bf16<<<dim3(TOK), 256, 0, stream>>>(h2, ln2_w, ln2_b, m_in);
  gemm_bt<1, 1, 0><<<dim3(32 * 32), 256, 0, stream>>>(m_in, w1b, b1, nullptr, act, 4096, 4096, 1024);
  gemm_bt<0, 0, 1><<<dim3(32 * 8), 256, 0, stream>>>(act, w2b, b2, h2, out, 4096, 1024, 4096);
}

// Round 2
// 244.619 us; speedup vs baseline: 1.1001x; 1.1001x over previous
//
#include <hip/hip_runtime.h>

#define TOK 4096
#define EMB 1024

typedef __attribute__((ext_vector_type(8))) short s16x8;
typedef __attribute__((ext_vector_type(4))) float f32x4;

__device__ __forceinline__ unsigned short f2bf(float f) {
  union { float f; unsigned int u; } v; v.f = f;
  unsigned int r = v.u + 0x7FFFu + ((v.u >> 16) & 1u);
  return (unsigned short)(r >> 16);
}
__device__ __forceinline__ float bf2f(unsigned short u) {
  union { unsigned int u; float f; } v; v.u = ((unsigned int)u) << 16; return v.f;
}

#define GLOAD_LDS16(g, l) __builtin_amdgcn_global_load_lds( \
    (const __attribute__((address_space(1))) void*)(g), \
    (__attribute__((address_space(3))) void*)(l), 16, 0, 0)

// ---------------- GEMM: C[M,N] = A[M,K] @ B[N,K]^T (+bias, +res, relu, dtype)
// m97 structure: 128x128 tile, BK=64, 4 waves in 2x2, 4x4 16x16x32 frags each.
template<int OUT_BF16, int RELU, int ADD_RES>
__global__ __launch_bounds__(256)
void gemm_bt(const unsigned short* __restrict__ A,
             const unsigned short* __restrict__ B,
             const float* __restrict__ bias,
             const float* __restrict__ res,
             void* __restrict__ Cout, int M, int N, int K)
{
  __shared__ unsigned short As[128 * 64];
  __shared__ unsigned short Bs[128 * 64];
  const int tid = threadIdx.x;
  const int lane = tid & 63;
  const int w = tid >> 6;
  const int wr = w >> 1, wc = w & 1;
  const int l15 = lane & 15, lhi = lane >> 4;
  const int nbm = M >> 7;
  const int bm = blockIdx.x % nbm;
  const int bn = blockIdx.x / nbm;
  const int m0 = bm << 7, n0 = bn << 7;

  f32x4 acc[4][4];
#pragma unroll
  for (int m = 0; m < 4; ++m)
#pragma unroll
    for (int n = 0; n < 4; ++n)
#pragma unroll
      for (int j = 0; j < 4; ++j) acc[m][n][j] = 0.f;

  const int trow = tid >> 3, tcol = (tid & 7) << 3;
  const unsigned short* Ag = A + (size_t)(m0 + trow) * K + tcol;
  const unsigned short* Bg = B + (size_t)(n0 + trow) * K + tcol;
  unsigned short* Adst = As + (w << 9);   // wave-uniform LDS base
  unsigned short* Bdst = Bs + (w << 9);

  for (int kt = 0; kt < K; kt += 64) {
    __syncthreads();   // prev compute done reading LDS
#pragma unroll
    for (int i = 0; i < 4; ++i) {
      GLOAD_LDS16(Ag + (size_t)(i * 32) * K + kt, Adst + i * 2048);
      GLOAD_LDS16(Bg + (size_t)(i * 32) * K + kt, Bdst + i * 2048);
    }
    __syncthreads();   // drains vmcnt before barrier
#pragma unroll
    for (int ks = 0; ks < 2; ++ks) {
      s16x8 af[4], bfr[4];
#pragma unroll
      for (int m = 0; m < 4; ++m)
        af[m] = *(const s16x8*)(As + ((wr * 64 + m * 16 + l15) << 6) + ks * 32 + lhi * 8);
#pragma unroll
      for (int n = 0; n < 4; ++n)
        bfr[n] = *(const s16x8*)(Bs + ((wc * 64 + n * 16 + l15) << 6) + ks * 32 + lhi * 8);
#pragma unroll
      for (int m = 0; m < 4; ++m)
#pragma unroll
        for (int n = 0; n < 4; ++n)
          acc[m][n] = __builtin_amdgcn_mfma_f32_16x16x32_bf16(af[m], bfr[n], acc[m][n], 0, 0, 0);
    }
  }

#pragma unroll
  for (int m = 0; m < 4; ++m) {
    const int row = m0 + wr * 64 + m * 16 + lhi * 4;
#pragma unroll
    for (int n = 0; n < 4; ++n) {
      const int col = n0 + wc * 64 + n * 16 + l15;
      const float bv = bias[col];
#pragma unroll
      for (int j = 0; j < 4; ++j) {
        float v = acc[m][n][j] + bv;
        if (RELU) v = fmaxf(v, 0.f);
        if (ADD_RES) v += res[(size_t)(row + j) * N + col];
        if (OUT_BF16)
          ((unsigned short*)Cout)[(size_t)(row + j) * N + col] = f2bf(v);
        else
          ((float*)Cout)[(size_t)(row + j) * N + col] = v;
      }
    }
  }
}

// ---------------- split-K GEMM: partial[s][M,N] = A[M, k0:k0+Kc] @ B[.,k0:k0+Kc]^T
// grid = (nbm*nbn, S); bf16 partials, no bias/res.
__global__ __launch_bounds__(256)
void gemm_bt_sk(const unsigned short* __restrict__ A,
                const unsigned short* __restrict__ B,
                unsigned short* __restrict__ Cpart, int M, int N, int K, int Kc)
{
  __shared__ unsigned short As[128 * 64];
  __shared__ unsigned short Bs[128 * 64];
  const int tid = threadIdx.x;
  const int lane = tid & 63;
  const int w = tid >> 6;
  const int wr = w >> 1, wc = w & 1;
  const int l15 = lane & 15, lhi = lane >> 4;
  const int nbm = M >> 7;
  const int bm = blockIdx.x % nbm;
  const int bn = blockIdx.x / nbm;
  const int m0 = bm << 7, n0 = bn << 7;
  const int k0 = blockIdx.y * Kc;

  f32x4 acc[4][4];
#pragma unroll
  for (int m = 0; m < 4; ++m)
#pragma unroll
    for (int n = 0; n < 4; ++n)
#pragma unroll
      for (int j = 0; j < 4; ++j) acc[m][n][j] = 0.f;

  const int trow = tid >> 3, tcol = (tid & 7) << 3;
  const unsigned short* Ag = A + (size_t)(m0 + trow) * K + tcol;
  const unsigned short* Bg = B + (size_t)(n0 + trow) * K + tcol;
  unsigned short* Adst = As + (w << 9);
  unsigned short* Bdst = Bs + (w << 9);

  for (int kt = k0; kt < k0 + Kc; kt += 64) {
    __syncthreads();
#pragma unroll
    for (int i = 0; i < 4; ++i) {
      GLOAD_LDS16(Ag + (size_t)(i * 32) * K + kt, Adst + i * 2048);
      GLOAD_LDS16(Bg + (size_t)(i * 32) * K + kt, Bdst + i * 2048);
    }
    __syncthreads();
#pragma unroll
    for (int ks = 0; ks < 2; ++ks) {
      s16x8 af[4], bfr[4];
#pragma unroll
      for (int m = 0; m < 4; ++m)
        af[m] = *(const s16x8*)(As + ((wr * 64 + m * 16 + l15) << 6) + ks * 32 + lhi * 8);
#pragma unroll
      for (int n = 0; n < 4; ++n)
        bfr[n] = *(const s16x8*)(Bs + ((wc * 64 + n * 16 + l15) << 6) + ks * 32 + lhi * 8);
#pragma unroll
      for (int m = 0; m < 4; ++m)
#pragma unroll
        for (int n = 0; n < 4; ++n)
          acc[m][n] = __builtin_amdgcn_mfma_f32_16x16x32_bf16(af[m], bfr[n], acc[m][n], 0, 0, 0);
    }
  }

  unsigned short* Cp = Cpart + (size_t)blockIdx.y * M * N;
#pragma unroll
  for (int m = 0; m < 4; ++m) {
    const int row = m0 + wr * 64 + m * 16 + lhi * 4;
#pragma unroll
    for (int n = 0; n < 4; ++n) {
      const int col = n0 + wc * 64 + n * 16 + l15;
#pragma unroll
      for (int j = 0; j < 4; ++j)
        Cp[(size_t)(row + j) * N + col] = f2bf(acc[m][n][j]);
    }
  }
}

// ---------------- reduce split-K partials + bias + residual -> fp32 out (MLP2 tail)
__global__ __launch_bounds__(256)
void reduce_add(const unsigned short* __restrict__ part, const float* __restrict__ res,
                const float* __restrict__ bias, float* __restrict__ out,
                int MN, int N, int S)
{
  const int i4 = (blockIdx.x * 256 + threadIdx.x) * 4;
  if (i4 >= MN) return;
  const int col = i4 & (N - 1);
  float4 v = *(const float4*)(res + i4);
  v.x += bias[col]; v.y += bias[col + 1]; v.z += bias[col + 2]; v.w += bias[col + 3];
  for (int s = 0; s < S; ++s) {
    const ushort4 p = *(const ushort4*)(part + (size_t)s * MN + i4);
    v.x += bf2f(p.x); v.y += bf2f(p.y); v.z += bf2f(p.z); v.w += bf2f(p.w);
  }
  *(float4*)(out + i4) = v;
}

// ---------------- reduce out-proj partials + bias + residual, then LayerNorm2
// one block per row: h2 (fp32) and m_in (bf16 LN2 output) in one pass.
__global__ __launch_bounds__(256)
void reduce_ln(const unsigned short* __restrict__ part, const float* __restrict__ x,
               const float* __restrict__ ob, const float* __restrict__ ln_w,
               const float* __restrict__ ln_b, float* __restrict__ h2,
               unsigned short* __restrict__ m_in, int S)
{
  const int row = blockIdx.x;
  const int t = threadIdx.x;
  const size_t off = (size_t)row * EMB + t * 4;
  float4 v = *(const float4*)(x + off);
  const float4 obv = ((const float4*)ob)[t];
  v.x += obv.x; v.y += obv.y; v.z += obv.z; v.w += obv.w;
  for (int s = 0; s < S; ++s) {
    const ushort4 p = *(const ushort4*)(part + (size_t)s * TOK * EMB + off);
    v.x += bf2f(p.x); v.y += bf2f(p.y); v.z += bf2f(p.z); v.w += bf2f(p.w);
  }
  *(float4*)(h2 + off) = v;

  float s1 = v.x + v.y + v.z + v.w;
  float s2 = v.x * v.x + v.y * v.y + v.z * v.z + v.w * v.w;
#pragma unroll
  for (int o = 1; o < 64; o <<= 1) { s1 += __shfl_xor(s1, o); s2 += __shfl_xor(s2, o); }
  __shared__ float red[8];
  if ((t & 63) == 0) { red[t >> 6] = s1; red[4 + (t >> 6)] = s2; }
  __syncthreads();
  s1 = red[0] + red[1] + red[2] + red[3];
  s2 = red[4] + red[5] + red[6] + red[7];
  const float mu = s1 * (1.f / EMB);
  const float rs = rsqrtf(s2 * (1.f / EMB) - mu * mu + 1e-5f);
  const float4 wv = ((const float4*)ln_w)[t];
  const float4 bv = ((const float4*)ln_b)[t];
  ushort4 o;
  o.x = f2bf((v.x - mu) * rs * wv.x + bv.x);
  o.y = f2bf((v.y - mu) * rs * wv.y + bv.y);
  o.z = f2bf((v.z - mu) * rs * wv.z + bv.z);
  o.w = f2bf((v.w - mu) * rs * wv.w + bv.w);
  ((ushort4*)(m_in + (size_t)row * EMB))[t] = o;
}

// ---------------- LayerNorm fp32 -> bf16 (one block per row of 1024)
__global__ __launch_bounds__(256)
void ln_bf16(const float* __restrict__ x, const float* __restrict__ wt,
             const float* __restrict__ bs, unsigned short* __restrict__ out)
{
  const int row = blockIdx.x;
  const int t = threadIdx.x;
  const float4 v = ((const float4*)(x + (size_t)row * EMB))[t];
  float s = v.x + v.y + v.z + v.w;
  float s2 = v.x * v.x + v.y * v.y + v.z * v.z + v.w * v.w;
#pragma unroll
  for (int off = 1; off < 64; off <<= 1) { s += __shfl_xor(s, off); s2 += __shfl_xor(s2, off); }
  __shared__ float red[8];
  if ((t & 63) == 0) { red[t >> 6] = s; red[4 + (t >> 6)] = s2; }
  __syncthreads();
  s = red[0] + red[1] + red[2] + red[3];
  s2 = red[4] + red[5] + red[6] + red[7];
  const float mu = s * (1.f / EMB);
  const float rs = rsqrtf(s2 * (1.f / EMB) - mu * mu + 1e-5f);
  const float4 wv = ((const float4*)wt)[t];
  const float4 bv = ((const float4*)bs)[t];
  ushort4 o;
  o.x = f2bf((v.x - mu) * rs * wv.x + bv.x);
  o.y = f2bf((v.y - mu) * rs * wv.y + bv.y);
  o.z = f2bf((v.z - mu) * rs * wv.z + bv.z);
  o.w = f2bf((v.w - mu) * rs * wv.w + bv.w);
  ((ushort4*)(out + (size_t)row * EMB))[t] = o;
}

// ---------------- fp32 -> bf16 weight conversion
__global__ __launch_bounds__(256)
void cvt_bf16(const float* __restrict__ in, unsigned short* __restrict__ out, int n4)
{
  const int i = blockIdx.x * 256 + threadIdx.x;
  if (i >= n4) return;
  const float4 v = ((const float4*)in)[i];
  ushort4 o;
  o.x = f2bf(v.x); o.y = f2bf(v.y); o.z = f2bf(v.z); o.w = f2bf(v.w);
  ((ushort4*)out)[i] = o;
}

// ---------------- sliding-window causal attention, flash-style
// grid (T/64, B*H); 4 waves x 16 q-rows; 5 K-tiles of 64 in window.
__global__ __launch_bounds__(256)
void attn_win(const unsigned short* __restrict__ qkv, unsigned short* __restrict__ aout)
{
  __shared__ unsigned short Ks[64 * 136];  // K tile, pad 128->136
  __shared__ unsigned short Vt[128 * 72];  // V^T tile, pad 64->72
  __shared__ unsigned short Ps[4 * 16 * 72];
  const int bh = blockIdx.y;
  const int b = bh >> 3, hh = bh & 7;
  const int q0 = blockIdx.x << 6;
  const int tid = threadIdx.x, lane = tid & 63, w = tid >> 6;
  const int l15 = lane & 15, lhi = lane >> 4;
  const size_t base = (size_t)b * 2048 * 3072;

  s16x8 qf[4];
  {
    const unsigned short* qp = qkv + base + (size_t)(q0 + w * 16 + l15) * 3072 + hh * 128 + lhi * 8;
#pragma unroll
    for (int ks = 0; ks < 4; ++ks) qf[ks] = *(const s16x8*)(qp + ks * 32);
  }

  f32x4 o[8];
#pragma unroll
  for (int n = 0; n < 8; ++n)
#pragma unroll
    for (int j = 0; j < 4; ++j) o[n][j] = 0.f;
  float mrow[4] = {-1e30f, -1e30f, -1e30f, -1e30f};
  float lrow[4] = {0.f, 0.f, 0.f, 0.f};

  for (int t = 0; t < 5; ++t) {
    const int kt0 = q0 - 256 + t * 64;
    if (kt0 < 0) continue;          // block-uniform
    __syncthreads();
    {
      const unsigned short* kg = qkv + base + (size_t)kt0 * 3072 + 1024 + hh * 128;
#pragma unroll
      for (int i = 0; i < 4; ++i) {
        const int c = tid + i * 256;
        const int r = c >> 4, cc = (c & 15) << 3;
        *(s16x8*)(Ks + r * 136 + cc) = *(const s16x8*)(kg + (size_t)r * 3072 + cc);
      }
      const unsigned short* vg = qkv + base + (size_t)kt0 * 3072 + 2048 + hh * 128;
#pragma unroll
      for (int i = 0; i < 2; ++i) {
        const int c = tid + i * 256;
        const int r2 = c >> 4, cc = (c & 15) << 3;
        s16x8 v0 = *(const s16x8*)(vg + (size_t)(2 * r2) * 3072 + cc);
        s16x8 v1 = *(const s16x8*)(vg + (size_t)(2 * r2 + 1) * 3072 + cc);
#pragma unroll
        for (int jj = 0; jj < 8; ++jj) {
          unsigned int pk = (unsigned int)(unsigned short)v0[jj] |
                            ((unsigned int)(unsigned short)v1[jj] << 16);
          *(unsigned int*)(Vt + (cc + jj) * 72 + 2 * r2) = pk;
        }
      }
    }
    __syncthreads();

    f32x4 s[4];
#pragma unroll
    for (int n = 0; n < 4; ++n)
#pragma unroll
      for (int j = 0; j < 4; ++j) s[n][j] = 0.f;
#pragma unroll
    for (int ks = 0; ks < 4; ++ks) {
#pragma unroll
      for (int n = 0; n < 4; ++n) {
        s16x8 kf = *(const s16x8*)(Ks + (n * 16 + l15) * 136 + ks * 32 + lhi * 8);
        s[n] = __builtin_amdgcn_mfma_f32_16x16x32_bf16(qf[ks], kf, s[n], 0, 0, 0);
      }
    }
    const bool mlo = (t == 0);        // window lower bound: keep kcol >= qrow
    const bool mhi = (kt0 == q0);     // causal: keep kcol <= qrow
#pragma unroll
    for (int n = 0; n < 4; ++n) {
      const int kcol = n * 16 + l15;
#pragma unroll
      for (int j = 0; j < 4; ++j) {
        const int qrow = w * 16 + lhi * 4 + j;
        float v = s[n][j] * 0.08838834764831845f;  // 1/sqrt(128)
        if ((mlo && kcol < qrow) || (mhi && kcol > qrow)) v = -1e30f;
        s[n][j] = v;
      }
    }
    float alpha[4];
#pragma unroll
    for (int j = 0; j < 4; ++j) {
      float mx = fmaxf(fmaxf(s[0][j], s[1][j]), fmaxf(s[2][j], s[3][j]));
#pragma unroll
      for (int off = 1; off < 16; off <<= 1) mx = fmaxf(mx, __shfl_xor(mx, off));
      const float mn = fmaxf(mrow[j], mx);
      alpha[j] = __expf(mrow[j] - mn);
      mrow[j] = mn;
    }
    float rowsum[4] = {0.f, 0.f, 0.f, 0.f};
#pragma unroll
    for (int n = 0; n < 4; ++n)
#pragma unroll
      for (int j = 0; j < 4; ++j) {
        const float p = __expf(s[n][j] - mrow[j]);
        rowsum[j] += p;
        Ps[(w * 16 + lhi * 4 + j) * 72 + n * 16 + l15] = f2bf(p);
      }
#pragma unroll
    for (int j = 0; j < 4; ++j) {
      float rs = rowsum[j];
#pragma unroll
      for (int off = 1; off < 16; off <<= 1) rs += __shfl_xor(rs, off);
      lrow[j] = lrow[j] * alpha[j] + rs;
    }
#pragma unroll
    for (int n = 0; n < 8; ++n)
#pragma unroll
      for (int j = 0; j < 4; ++j) o[n][j] *= alpha[j];
#pragma unroll
    for (int ks = 0; ks < 2; ++ks) {
      const s16x8 pf = *(const s16x8*)(Ps + (w * 16 + l15) * 72 + ks * 32 + lhi * 8);
#pragma unroll
      for (int n = 0; n < 8; ++n) {
        const s16x8 vf = *(const s16x8*)(Vt + (n * 16 + l15) * 72 + ks * 32 + lhi * 8);
        o[n] = __builtin_amdgcn_mfma_f32_16x16x32_bf16(pf, vf, o[n], 0, 0, 0);
      }
    }
  }
  unsigned short* op = aout + (size_t)(b * 2048 + q0 + w * 16) * 1024 + hh * 128;
#pragma unroll
  for (int n = 0; n < 8; ++n)
#pragma unroll
    for (int j = 0; j < 4; ++j)
      op[(size_t)(lhi * 4 + j) * 1024 + n * 16 + l15] = f2bf(o[n][j] / lrow[j]);
}

extern "C" void kernel_launch(void* const* d_in, const int* in_sizes, int n_in,
                              void* d_out, int out_size, void* d_ws, size_t ws_size,
                              hipStream_t stream)
{
  (void)in_sizes; (void)n_in; (void)out_size; (void)ws_size;
  const float* x         = (const float*)d_in[0];
  const float* ln1_w     = (const float*)d_in[1];
  const float* ln1_b     = (const float*)d_in[2];
  const float* ln2_w     = (const float*)d_in[3];
  const float* ln2_b     = (const float*)d_in[4];
  const float* in_proj_w = (const float*)d_in[5];
  const float* in_proj_b = (const float*)d_in[6];
  const float* out_w     = (const float*)d_in[7];
  const float* out_b     = (const float*)d_in[8];
  const float* w1        = (const float*)d_in[9];
  const float* b1        = (const float*)d_in[10];
  const float* w2        = (const float*)d_in[11];
  const float* b2        = (const float*)d_in[12];
  float* out = (float*)d_out;

  char* ws = (char*)d_ws;
  unsigned short* h    = (unsigned short*)(ws);                 //  8 MiB  LN1 out bf16
  unsigned short* wqkv = (unsigned short*)(ws + (8u << 20));    //  6 MiB
  unsigned short* wout = (unsigned short*)(ws + (14u << 20));   //  2 MiB
  unsigned short* w1b  = (unsigned short*)(ws + (16u << 20));   //  8 MiB
  unsigned short* w2b  = (unsigned short*)(ws + (24u << 20));   //  8 MiB
  unsigned short* qkv  = (unsigned short*)(ws + (32u << 20));   // 24 MiB
  unsigned short* aout = (unsigned short*)(ws + (56u << 20));   //  8 MiB
  float*          h2   = (float*)(ws + (64u << 20));            // 16 MiB
  unsigned short* m_in = (unsigned short*)(ws + (80u << 20));   //  8 MiB
  unsigned short* act  = (unsigned short*)(ws + (88u << 20));   // 32 MiB (ends 120 MiB)
  // split-K partial buffers reuse dead regions:
  unsigned short* part_op = (unsigned short*)(ws + (88u << 20)); // 16 MiB, act region (dead until MLP1)
  unsigned short* part_m2 = (unsigned short*)(ws + (32u << 20)); // 32 MiB, qkv+aout region (dead after out-proj)

  cvt_bf16<<<dim3(3072 * 1024 / 4 / 256), 256, 0, stream>>>(in_proj_w, wqkv, 3072 * 1024 / 4);
  cvt_bf16<<<dim3(1024 * 1024 / 4 / 256), 256, 0, stream>>>(out_w, wout, 1024 * 1024 / 4);
  cvt_bf16<<<dim3(4096 * 1024 / 4 / 256), 256, 0, stream>>>(w1, w1b, 4096 * 1024 / 4);
  cvt_bf16<<<dim3(1024 * 4096 / 4 / 256), 256, 0, stream>>>(w2, w2b, 1024 * 4096 / 4);

  ln_bf16<<<dim3(TOK), 256, 0, stream>>>(x, ln1_w, ln1_b, h);
  gemm_bt<1, 0, 0><<<dim3(32 * 24), 256, 0, stream>>>(h, wqkv, in_proj_b, nullptr, qkv, 4096, 3072, 1024);
  attn_win<<<dim3(32, 16), 256, 0, stream>>>(qkv, aout);

  // out-proj: split-K=2 (grid 512) -> bf16 partials -> fused reduce+residual+LN2
  gemm_bt_sk<<<dim3(32 * 8, 2), 256, 0, stream>>>(aout, wout, part_op, 4096, 1024, 1024, 512);
  reduce_ln<<<dim3(TOK), 256, 0, stream>>>(part_op, x, out_b, ln2_w, ln2_b, h2, m_in, 2);

  gemm_bt<1, 1, 0><<<dim3(32 * 32), 256, 0, stream>>>(m_in, w1b, b1, nullptr, act, 4096, 4096, 1024);

  // MLP2: split-K=4 (grid 1024) -> bf16 partials -> fused reduce+bias+residual
  gemm_bt_sk<<<dim3(32 * 8, 4), 256, 0, stream>>>(act, w2b, part_m2, 4096, 1024, 4096, 1024);
  reduce_add<<<dim3(4096 * 1024 / 4 / 256), 256, 0, stream>>>(part_m2, h2, b2, out, 4096 * 1024, 1024, 4);
}

// Round 4
// 210.742 us; speedup vs baseline: 1.2769x; 1.1607x over previous
//
#include <hip/hip_runtime.h>

#define TOK 4096
#define EMB 1024

typedef __attribute__((ext_vector_type(8))) short s16x8;
typedef __attribute__((ext_vector_type(4))) float f32x4;

__device__ __forceinline__ unsigned short f2bf(float f) {
  union { float f; unsigned int u; } v; v.f = f;
  unsigned int r = v.u + 0x7FFFu + ((v.u >> 16) & 1u);
  return (unsigned short)(r >> 16);
}
__device__ __forceinline__ float bf2f(unsigned short u) {
  union { unsigned int u; float f; } v; v.u = ((unsigned int)u) << 16; return v.f;
}

#define GLOAD_LDS16(g, l) __builtin_amdgcn_global_load_lds( \
    (const __attribute__((address_space(1))) void*)(g), \
    (__attribute__((address_space(3))) void*)(l), 16, 0, 0)

// =================== 256x256 8-phase GEMM: C[M,N] = A[M,K] @ B[N,K]^T + bias
// 512 threads = 8 waves (2M x 4N). Per-wave out 128x64 (8x4 frags of 16x16).
// BK=64, double-buffered LDS (128 KiB).
// Phase plan (race-free ledger, fixed from round 3):
//   P1: ds_read alow(mf0-3)+bf0(nf0-1); stage HB1(kt+1)->buf p^1; MFMA q00.
//   P2: ds_read ahigh(mf4-7)+bf1(nf2-3); MFMA q10.   <- ALL buf-p reads done here
//   P3: stage HA0(kt+2)+HB0(kt+2)->buf p;            MFMA q01.
//   P4: stage HA1(kt+2)->buf p;                      MFMA q11; vmcnt(6) gate.
// Stage writes for buf p are issued only AFTER the end-P2 barrier (last reader).
// vmcnt(6) at gate = the 6 kt+2 loads outstanding; everything older complete.
// LDS XOR-swizzle (T2): linear dest + inverse-swizzled GLOBAL src + swizzled read.
template<int RELU>
__global__ __launch_bounds__(512)
void gemm256(const unsigned short* __restrict__ A,
             const unsigned short* __restrict__ B,
             const float* __restrict__ bias,
             unsigned short* __restrict__ C, int M, int N, int K)
{
  __shared__ unsigned short lds[2][2][256 * 64];  // [buf][0=A,1=B]
  const int tid = threadIdx.x;
  const int lane = tid & 63;
  const int w = tid >> 6;                 // 0..7
  const int wr = w >> 2, wc = w & 3;      // 2 x 4 wave grid
  const int l15 = lane & 15, lhi = lane >> 4;
  const int nbm = M >> 8;
  const int bm = blockIdx.x % nbm, bn = blockIdx.x / nbm;
  const int m0 = bm << 8, n0 = bn << 8;
  const int NT = K >> 6;

  const char* Abase = (const char*)(A + (size_t)m0 * K);
  const char* Bbase = (const char*)(B + (size_t)n0 * K);
  const size_t rowb = (size_t)K * 2;      // global row stride bytes

  // staging: thread t covers LDS half-tile byte t*16 (linear); global src col
  // pre-XORed so LDS[row][cc] holds global[row][cc ^ ((row&7)<<4)].
  const int srt = tid >> 3;               // row within 64-row block
  const int sccx = ((tid & 7) << 4) ^ ((srt & 7) << 4);

  auto stage = [&](const char* Gb, int kt, int h, int ab, int buf) {
    char* ldsb = (char*)&lds[buf][ab][0] + h * 16384 + (w << 10);  // wave-uniform
    const char* g = Gb + (size_t)(h * 128 + srt) * rowb + kt * 128 + sccx;
    GLOAD_LDS16(g, ldsb);
    GLOAD_LDS16(g + 64 * rowb, ldsb + 8192);
  };

  const int rdxor = (l15 & 7) << 4;
  auto rdA = [&](int buf, int mf, int ks) -> s16x8 {
    const int r = wr * 128 + mf * 16 + l15;
    const int cc = (ks * 64 + lhi * 16) ^ rdxor;
    return *(const s16x8*)((const char*)&lds[buf][0][0] + r * 128 + cc);
  };
  auto rdB = [&](int buf, int nf, int ks) -> s16x8 {
    const int r = wc * 64 + nf * 16 + l15;
    const int cc = (ks * 64 + lhi * 16) ^ rdxor;
    return *(const s16x8*)((const char*)&lds[buf][1][0] + r * 128 + cc);
  };

  f32x4 acc[8][4];
#pragma unroll
  for (int mf = 0; mf < 8; ++mf)
#pragma unroll
    for (int nf = 0; nf < 4; ++nf)
#pragma unroll
      for (int j = 0; j < 4; ++j) acc[mf][nf][j] = 0.f;

  // ---- prologue: tile0 fully + tile1 {HA0,HA1,HB0} = 14 loads; HB1(1) comes in P1
  stage(Abase, 0, 0, 0, 0); stage(Abase, 0, 1, 0, 0);
  stage(Bbase, 0, 0, 1, 0); stage(Bbase, 0, 1, 1, 0);
  stage(Abase, 1, 0, 0, 1); stage(Abase, 1, 1, 0, 1);
  stage(Bbase, 1, 0, 1, 1);
  asm volatile("s_waitcnt vmcnt(6)" ::: "memory");
  __builtin_amdgcn_s_barrier();

  s16x8 af[4][2], af2[4][2], bf0[2][2], bf1[2][2];

  for (int kt = 0; kt < NT; ++kt) {
    const int p = kt & 1;

    // ---- P1: read alow + bf0; stage HB1(kt+1) -> buf p^1; mfma q00
#pragma unroll
    for (int mi = 0; mi < 4; ++mi) { af[mi][0] = rdA(p, mi, 0); af[mi][1] = rdA(p, mi, 1); }
#pragma unroll
    for (int ni = 0; ni < 2; ++ni) { bf0[ni][0] = rdB(p, ni, 0); bf0[ni][1] = rdB(p, ni, 1); }
    if (kt + 1 < NT) stage(Bbase, kt + 1, 1, 1, p ^ 1);
    __builtin_amdgcn_s_barrier();
    asm volatile("s_waitcnt lgkmcnt(0)" ::: "memory");
    __builtin_amdgcn_sched_barrier(0);
    __builtin_amdgcn_s_setprio(1);
#pragma unroll
    for (int mi = 0; mi < 4; ++mi)
#pragma unroll
      for (int ni = 0; ni < 2; ++ni)
#pragma unroll
        for (int ks = 0; ks < 2; ++ks)
          acc[mi][ni] = __builtin_amdgcn_mfma_f32_16x16x32_bf16(af[mi][ks], bf0[ni][ks], acc[mi][ni], 0, 0, 0);
    __builtin_amdgcn_s_setprio(0);
    __builtin_amdgcn_s_barrier();

    // ---- P2: read ahigh + bf1 (completes ALL buf-p reads); mfma q10
#pragma unroll
    for (int mi = 0; mi < 4; ++mi) { af2[mi][0] = rdA(p, 4 + mi, 0); af2[mi][1] = rdA(p, 4 + mi, 1); }
#pragma unroll
    for (int ni = 0; ni < 2; ++ni) { bf1[ni][0] = rdB(p, 2 + ni, 0); bf1[ni][1] = rdB(p, 2 + ni, 1); }
    __builtin_amdgcn_s_barrier();
    asm volatile("s_waitcnt lgkmcnt(0)" ::: "memory");
    __builtin_amdgcn_sched_barrier(0);
    __builtin_amdgcn_s_setprio(1);
#pragma unroll
    for (int mi = 0; mi < 4; ++mi)
#pragma unroll
      for (int ni = 0; ni < 2; ++ni)
#pragma unroll
        for (int ks = 0; ks < 2; ++ks)
          acc[4 + mi][ni] = __builtin_amdgcn_mfma_f32_16x16x32_bf16(af2[mi][ks], bf0[ni][ks], acc[4 + mi][ni], 0, 0, 0);
    __builtin_amdgcn_s_setprio(0);
    __builtin_amdgcn_s_barrier();

    // ---- P3: stage HA0+HB0(kt+2) into buf p (all readers done at end-P2); mfma q01
    if (kt + 2 < NT) { stage(Abase, kt + 2, 0, 0, p); stage(Bbase, kt + 2, 0, 1, p); }
    __builtin_amdgcn_s_barrier();
    __builtin_amdgcn_s_setprio(1);
#pragma unroll
    for (int mi = 0; mi < 4; ++mi)
#pragma unroll
      for (int ni = 0; ni < 2; ++ni)
#pragma unroll
        for (int ks = 0; ks < 2; ++ks)
          acc[mi][2 + ni] = __builtin_amdgcn_mfma_f32_16x16x32_bf16(af[mi][ks], bf1[ni][ks], acc[mi][2 + ni], 0, 0, 0);
    __builtin_amdgcn_s_setprio(0);
    __builtin_amdgcn_s_barrier();

    // ---- P4: stage HA1(kt+2); mfma q11; end-of-tile vmcnt gate
    if (kt + 2 < NT) stage(Abase, kt + 2, 1, 0, p);
    __builtin_amdgcn_s_barrier();
    __builtin_amdgcn_s_setprio(1);
#pragma unroll
    for (int mi = 0; mi < 4; ++mi)
#pragma unroll
      for (int ni = 0; ni < 2; ++ni)
#pragma unroll
        for (int ks = 0; ks < 2; ++ks)
          acc[4 + mi][2 + ni] = __builtin_amdgcn_mfma_f32_16x16x32_bf16(af2[mi][ks], bf1[ni][ks], acc[4 + mi][2 + ni], 0, 0, 0);
    __builtin_amdgcn_s_setprio(0);
    if (kt + 1 < NT) {
      if (kt + 2 < NT) asm volatile("s_waitcnt vmcnt(6)" ::: "memory");
      else             asm volatile("s_waitcnt vmcnt(0)" ::: "memory");
      __builtin_amdgcn_s_barrier();
    }
  }

  // ---- epilogue: bias (+relu) -> bf16
#pragma unroll
  for (int mf = 0; mf < 8; ++mf) {
    const int row = m0 + wr * 128 + mf * 16 + lhi * 4;
#pragma unroll
    for (int nf = 0; nf < 4; ++nf) {
      const int col = n0 + wc * 64 + nf * 16 + l15;
      const float bv = bias[col];
#pragma unroll
      for (int j = 0; j < 4; ++j) {
        float v = acc[mf][nf][j] + bv;
        if (RELU) v = fmaxf(v, 0.f);
        C[(size_t)(row + j) * N + col] = f2bf(v);
      }
    }
  }
}

// ---------------- split-K GEMM (m97 128x128 structure): bf16 partials
__global__ __launch_bounds__(256)
void gemm_bt_sk(const unsigned short* __restrict__ A,
                const unsigned short* __restrict__ B,
                unsigned short* __restrict__ Cpart, int M, int N, int K, int Kc)
{
  __shared__ unsigned short As[128 * 64];
  __shared__ unsigned short Bs[128 * 64];
  const int tid = threadIdx.x;
  const int lane = tid & 63;
  const int w = tid >> 6;
  const int wr = w >> 1, wc = w & 1;
  const int l15 = lane & 15, lhi = lane >> 4;
  const int nbm = M >> 7;
  const int bm = blockIdx.x % nbm;
  const int bn = blockIdx.x / nbm;
  const int m0 = bm << 7, n0 = bn << 7;
  const int k0 = blockIdx.y * Kc;

  f32x4 acc[4][4];
#pragma unroll
  for (int m = 0; m < 4; ++m)
#pragma unroll
    for (int n = 0; n < 4; ++n)
#pragma unroll
      for (int j = 0; j < 4; ++j) acc[m][n][j] = 0.f;

  const int trow = tid >> 3, tcol = (tid & 7) << 3;
  const unsigned short* Ag = A + (size_t)(m0 + trow) * K + tcol;
  const unsigned short* Bg = B + (size_t)(n0 + trow) * K + tcol;
  unsigned short* Adst = As + (w << 9);
  unsigned short* Bdst = Bs + (w << 9);

  for (int kt = k0; kt < k0 + Kc; kt += 64) {
    __syncthreads();
#pragma unroll
    for (int i = 0; i < 4; ++i) {
      GLOAD_LDS16(Ag + (size_t)(i * 32) * K + kt, Adst + i * 2048);
      GLOAD_LDS16(Bg + (size_t)(i * 32) * K + kt, Bdst + i * 2048);
    }
    __syncthreads();
#pragma unroll
    for (int ks = 0; ks < 2; ++ks) {
      s16x8 af[4], bfr[4];
#pragma unroll
      for (int m = 0; m < 4; ++m)
        af[m] = *(const s16x8*)(As + ((wr * 64 + m * 16 + l15) << 6) + ks * 32 + lhi * 8);
#pragma unroll
      for (int n = 0; n < 4; ++n)
        bfr[n] = *(const s16x8*)(Bs + ((wc * 64 + n * 16 + l15) << 6) + ks * 32 + lhi * 8);
#pragma unroll
      for (int m = 0; m < 4; ++m)
#pragma unroll
        for (int n = 0; n < 4; ++n)
          acc[m][n] = __builtin_amdgcn_mfma_f32_16x16x32_bf16(af[m], bfr[n], acc[m][n], 0, 0, 0);
    }
  }

  unsigned short* Cp = Cpart + (size_t)blockIdx.y * M * N;
#pragma unroll
  for (int m = 0; m < 4; ++m) {
    const int row = m0 + wr * 64 + m * 16 + lhi * 4;
#pragma unroll
    for (int n = 0; n < 4; ++n) {
      const int col = n0 + wc * 64 + n * 16 + l15;
#pragma unroll
      for (int j = 0; j < 4; ++j)
        Cp[(size_t)(row + j) * N + col] = f2bf(acc[m][n][j]);
    }
  }
}

// ---------------- reduce split-K partials + bias + residual -> fp32 out (MLP2 tail)
__global__ __launch_bounds__(256)
void reduce_add(const unsigned short* __restrict__ part, const float* __restrict__ res,
                const float* __restrict__ bias, float* __restrict__ out,
                int MN, int N, int S)
{
  const int i4 = (blockIdx.x * 256 + threadIdx.x) * 4;
  if (i4 >= MN) return;
  const int col = i4 & (N - 1);
  float4 v = *(const float4*)(res + i4);
  v.x += bias[col]; v.y += bias[col + 1]; v.z += bias[col + 2]; v.w += bias[col + 3];
  for (int s = 0; s < S; ++s) {
    const ushort4 p = *(const ushort4*)(part + (size_t)s * MN + i4);
    v.x += bf2f(p.x); v.y += bf2f(p.y); v.z += bf2f(p.z); v.w += bf2f(p.w);
  }
  *(float4*)(out + i4) = v;
}

// ---------------- reduce out-proj partials + bias + residual, then LayerNorm2
__global__ __launch_bounds__(256)
void reduce_ln(const unsigned short* __restrict__ part, const float* __restrict__ x,
               const float* __restrict__ ob, const float* __restrict__ ln_w,
               const float* __restrict__ ln_b, float* __restrict__ h2,
               unsigned short* __restrict__ m_in, int S)
{
  const int row = blockIdx.x;
  const int t = threadIdx.x;
  const size_t off = (size_t)row * EMB + t * 4;
  float4 v = *(const float4*)(x + off);
  const float4 obv = ((const float4*)ob)[t];
  v.x += obv.x; v.y += obv.y; v.z += obv.z; v.w += obv.w;
  for (int s = 0; s < S; ++s) {
    const ushort4 p = *(const ushort4*)(part + (size_t)s * TOK * EMB + off);
    v.x += bf2f(p.x); v.y += bf2f(p.y); v.z += bf2f(p.z); v.w += bf2f(p.w);
  }
  *(float4*)(h2 + off) = v;

  float s1 = v.x + v.y + v.z + v.w;
  float s2 = v.x * v.x + v.y * v.y + v.z * v.z + v.w * v.w;
#pragma unroll
  for (int o = 1; o < 64; o <<= 1) { s1 += __shfl_xor(s1, o); s2 += __shfl_xor(s2, o); }
  __shared__ float red[8];
  if ((t & 63) == 0) { red[t >> 6] = s1; red[4 + (t >> 6)] = s2; }
  __syncthreads();
  s1 = red[0] + red[1] + red[2] + red[3];
  s2 = red[4] + red[5] + red[6] + red[7];
  const float mu = s1 * (1.f / EMB);
  const float rs = rsqrtf(s2 * (1.f / EMB) - mu * mu + 1e-5f);
  const float4 wv = ((const float4*)ln_w)[t];
  const float4 bv = ((const float4*)ln_b)[t];
  ushort4 o;
  o.x = f2bf((v.x - mu) * rs * wv.x + bv.x);
  o.y = f2bf((v.y - mu) * rs * wv.y + bv.y);
  o.z = f2bf((v.z - mu) * rs * wv.z + bv.z);
  o.w = f2bf((v.w - mu) * rs * wv.w + bv.w);
  ((ushort4*)(m_in + (size_t)row * EMB))[t] = o;
}

// ---------------- LayerNorm fp32 -> bf16 (one block per row of 1024)
__global__ __launch_bounds__(256)
void ln_bf16(const float* __restrict__ x, const float* __restrict__ wt,
             const float* __restrict__ bs, unsigned short* __restrict__ out)
{
  const int row = blockIdx.x;
  const int t = threadIdx.x;
  const float4 v = ((const float4*)(x + (size_t)row * EMB))[t];
  float s = v.x + v.y + v.z + v.w;
  float s2 = v.x * v.x + v.y * v.y + v.z * v.z + v.w * v.w;
#pragma unroll
  for (int off = 1; off < 64; off <<= 1) { s += __shfl_xor(s, off); s2 += __shfl_xor(s2, off); }
  __shared__ float red[8];
  if ((t & 63) == 0) { red[t >> 6] = s; red[4 + (t >> 6)] = s2; }
  __syncthreads();
  s = red[0] + red[1] + red[2] + red[3];
  s2 = red[4] + red[5] + red[6] + red[7];
  const float mu = s * (1.f / EMB);
  const float rs = rsqrtf(s2 * (1.f / EMB) - mu * mu + 1e-5f);
  const float4 wv = ((const float4*)wt)[t];
  const float4 bv = ((const float4*)bs)[t];
  ushort4 o;
  o.x = f2bf((v.x - mu) * rs * wv.x + bv.x);
  o.y = f2bf((v.y - mu) * rs * wv.y + bv.y);
  o.z = f2bf((v.z - mu) * rs * wv.z + bv.z);
  o.w = f2bf((v.w - mu) * rs * wv.w + bv.w);
  ((ushort4*)(out + (size_t)row * EMB))[t] = o;
}

// ---------------- fp32 -> bf16 conversion of all four weight matrices, one launch
#define Q0 786432            // in_proj_w quads (3072*1024/4)
#define Q1 (Q0 + 262144)     // + out_w
#define Q2 (Q1 + 1048576)    // + w1
#define Q3 (Q2 + 1048576)    // + w2
__global__ __launch_bounds__(256)
void cvt4(const float* __restrict__ s0, const float* __restrict__ s1,
          const float* __restrict__ s2, const float* __restrict__ s3,
          unsigned short* __restrict__ d0, unsigned short* __restrict__ d1,
          unsigned short* __restrict__ d2, unsigned short* __restrict__ d3)
{
  const int i = blockIdx.x * 256 + threadIdx.x;
  const float* s; unsigned short* d; int off;
  if (i < Q0)      { s = s0; d = d0; off = i; }
  else if (i < Q1) { s = s1; d = d1; off = i - Q0; }
  else if (i < Q2) { s = s2; d = d2; off = i - Q1; }
  else             { s = s3; d = d3; off = i - Q2; }
  const float4 v = ((const float4*)s)[off];
  ushort4 o;
  o.x = f2bf(v.x); o.y = f2bf(v.y); o.z = f2bf(v.z); o.w = f2bf(v.w);
  ((ushort4*)d)[off] = o;
}

// ---------------- sliding-window causal attention, flash-style
__global__ __launch_bounds__(256)
void attn_win(const unsigned short* __restrict__ qkv, unsigned short* __restrict__ aout)
{
  __shared__ unsigned short Ks[64 * 136];
  __shared__ unsigned short Vt[128 * 72];
  __shared__ unsigned short Ps[4 * 16 * 72];
  const int bh = blockIdx.y;
  const int b = bh >> 3, hh = bh & 7;
  const int q0 = blockIdx.x << 6;
  const int tid = threadIdx.x, lane = tid & 63, w = tid >> 6;
  const int l15 = lane & 15, lhi = lane >> 4;
  const size_t base = (size_t)b * 2048 * 3072;

  s16x8 qf[4];
  {
    const unsigned short* qp = qkv + base + (size_t)(q0 + w * 16 + l15) * 3072 + hh * 128 + lhi * 8;
#pragma unroll
    for (int ks = 0; ks < 4; ++ks) qf[ks] = *(const s16x8*)(qp + ks * 32);
  }

  f32x4 o[8];
#pragma unroll
  for (int n = 0; n < 8; ++n)
#pragma unroll
    for (int j = 0; j < 4; ++j) o[n][j] = 0.f;
  float mrow[4] = {-1e30f, -1e30f, -1e30f, -1e30f};
  float lrow[4] = {0.f, 0.f, 0.f, 0.f};

  for (int t = 0; t < 5; ++t) {
    const int kt0 = q0 - 256 + t * 64;
    if (kt0 < 0) continue;
    __syncthreads();
    {
      const unsigned short* kg = qkv + base + (size_t)kt0 * 3072 + 1024 + hh * 128;
#pragma unroll
      for (int i = 0; i < 4; ++i) {
        const int c = tid + i * 256;
        const int r = c >> 4, cc = (c & 15) << 3;
        *(s16x8*)(Ks + r * 136 + cc) = *(const s16x8*)(kg + (size_t)r * 3072 + cc);
      }
      const unsigned short* vg = qkv + base + (size_t)kt0 * 3072 + 2048 + hh * 128;
#pragma unroll
      for (int i = 0; i < 2; ++i) {
        const int c = tid + i * 256;
        const int r2 = c >> 4, cc = (c & 15) << 3;
        s16x8 v0 = *(const s16x8*)(vg + (size_t)(2 * r2) * 3072 + cc);
        s16x8 v1 = *(const s16x8*)(vg + (size_t)(2 * r2 + 1) * 3072 + cc);
#pragma unroll
        for (int jj = 0; jj < 8; ++jj) {
          unsigned int pk = (unsigned int)(unsigned short)v0[jj] |
                            ((unsigned int)(unsigned short)v1[jj] << 16);
          *(unsigned int*)(Vt + (cc + jj) * 72 + 2 * r2) = pk;
        }
      }
    }
    __syncthreads();

    f32x4 s[4];
#pragma unroll
    for (int n = 0; n < 4; ++n)
#pragma unroll
      for (int j = 0; j < 4; ++j) s[n][j] = 0.f;
#pragma unroll
    for (int ks = 0; ks < 4; ++ks) {
#pragma unroll
      for (int n = 0; n < 4; ++n) {
        s16x8 kf = *(const s16x8*)(Ks + (n * 16 + l15) * 136 + ks * 32 + lhi * 8);
        s[n] = __builtin_amdgcn_mfma_f32_16x16x32_bf16(qf[ks], kf, s[n], 0, 0, 0);
      }
    }
    const bool mlo = (t == 0);
    const bool mhi = (kt0 == q0);
#pragma unroll
    for (int n = 0; n < 4; ++n) {
      const int kcol = n * 16 + l15;
#pragma unroll
      for (int j = 0; j < 4; ++j) {
        const int qrow = w * 16 + lhi * 4 + j;
        float v = s[n][j] * 0.08838834764831845f;
        if ((mlo && kcol < qrow) || (mhi && kcol > qrow)) v = -1e30f;
        s[n][j] = v;
      }
    }
    float alpha[4];
#pragma unroll
    for (int j = 0; j < 4; ++j) {
      float mx = fmaxf(fmaxf(s[0][j], s[1][j]), fmaxf(s[2][j], s[3][j]));
#pragma unroll
      for (int off = 1; off < 16; off <<= 1) mx = fmaxf(mx, __shfl_xor(mx, off));
      const float mn = fmaxf(mrow[j], mx);
      alpha[j] = __expf(mrow[j] - mn);
      mrow[j] = mn;
    }
    float rowsum[4] = {0.f, 0.f, 0.f, 0.f};
#pragma unroll
    for (int n = 0; n < 4; ++n)
#pragma unroll
      for (int j = 0; j < 4; ++j) {
        const float p = __expf(s[n][j] - mrow[j]);
        rowsum[j] += p;
        Ps[(w * 16 + lhi * 4 + j) * 72 + n * 16 + l15] = f2bf(p);
      }
#pragma unroll
    for (int j = 0; j < 4; ++j) {
      float rs = rowsum[j];
#pragma unroll
      for (int off = 1; off < 16; off <<= 1) rs += __shfl_xor(rs, off);
      lrow[j] = lrow[j] * alpha[j] + rs;
    }
#pragma unroll
    for (int n = 0; n < 8; ++n)
#pragma unroll
      for (int j = 0; j < 4; ++j) o[n][j] *= alpha[j];
#pragma unroll
    for (int ks = 0; ks < 2; ++ks) {
      const s16x8 pf = *(const s16x8*)(Ps + (w * 16 + l15) * 72 + ks * 32 + lhi * 8);
#pragma unroll
      for (int n = 0; n < 8; ++n) {
        const s16x8 vf = *(const s16x8*)(Vt + (n * 16 + l15) * 72 + ks * 32 + lhi * 8);
        o[n] = __builtin_amdgcn_mfma_f32_16x16x32_bf16(pf, vf, o[n], 0, 0, 0);
      }
    }
  }
  unsigned short* op = aout + (size_t)(b * 2048 + q0 + w * 16) * 1024 + hh * 128;
#pragma unroll
  for (int n = 0; n < 8; ++n)
#pragma unroll
    for (int j = 0; j < 4; ++j)
      op[(size_t)(lhi * 4 + j) * 1024 + n * 16 + l15] = f2bf(o[n][j] / lrow[j]);
}

extern "C" void kernel_launch(void* const* d_in, const int* in_sizes, int n_in,
                              void* d_out, int out_size, void* d_ws, size_t ws_size,
                              hipStream_t stream)
{
  (void)in_sizes; (void)n_in; (void)out_size; (void)ws_size;
  const float* x         = (const float*)d_in[0];
  const float* ln1_w     = (const float*)d_in[1];
  const float* ln1_b     = (const float*)d_in[2];
  const float* ln2_w     = (const float*)d_in[3];
  const float* ln2_b     = (const float*)d_in[4];
  const float* in_proj_w = (const float*)d_in[5];
  const float* in_proj_b = (const float*)d_in[6];
  const float* out_w     = (const float*)d_in[7];
  const float* out_b     = (const float*)d_in[8];
  const float* w1        = (const float*)d_in[9];
  const float* b1        = (const float*)d_in[10];
  const float* w2        = (const float*)d_in[11];
  const float* b2        = (const float*)d_in[12];
  float* out = (float*)d_out;

  char* ws = (char*)d_ws;
  unsigned short* h    = (unsigned short*)(ws);                 //  8 MiB  LN1 out bf16
  unsigned short* wqkv = (unsigned short*)(ws + (8u << 20));    //  6 MiB
  unsigned short* wout = (unsigned short*)(ws + (14u << 20));   //  2 MiB
  unsigned short* w1b  = (unsigned short*)(ws + (16u << 20));   //  8 MiB
  unsigned short* w2b  = (unsigned short*)(ws + (24u << 20));   //  8 MiB
  unsigned short* qkv  = (unsigned short*)(ws + (32u << 20));   // 24 MiB
  unsigned short* aout = (unsigned short*)(ws + (56u << 20));   //  8 MiB
  float*          h2   = (float*)(ws + (64u << 20));            // 16 MiB
  unsigned short* m_in = (unsigned short*)(ws + (80u << 20));   //  8 MiB
  unsigned short* act  = (unsigned short*)(ws + (88u << 20));   // 32 MiB (ends 120 MiB)
  unsigned short* part_op = (unsigned short*)(ws + (88u << 20)); // 16 MiB, act region (dead until MLP1)
  unsigned short* part_m2 = (unsigned short*)(ws + (32u << 20)); // 32 MiB, qkv+aout region (dead after out-proj)

  cvt4<<<dim3(Q3 / 256), 256, 0, stream>>>(in_proj_w, out_w, w1, w2, wqkv, wout, w1b, w2b);
  ln_bf16<<<dim3(TOK), 256, 0, stream>>>(x, ln1_w, ln1_b, h);

  // QKV: 256^2 8-phase (grid 16x12)
  gemm256<0><<<dim3(16 * 12), 512, 0, stream>>>(h, wqkv, in_proj_b, qkv, 4096, 3072, 1024);
  attn_win<<<dim3(32, 16), 256, 0, stream>>>(qkv, aout);

  // out-proj: split-K=2 -> fused reduce+residual+LN2
  gemm_bt_sk<<<dim3(32 * 8, 2), 256, 0, stream>>>(aout, wout, part_op, 4096, 1024, 1024, 512);
  reduce_ln<<<dim3(TOK), 256, 0, stream>>>(part_op, x, out_b, ln2_w, ln2_b, h2, m_in, 2);

  // MLP1: 256^2 8-phase (grid 16x16) + relu
  gemm256<1><<<dim3(16 * 16), 512, 0, stream>>>(m_in, w1b, b1, act, 4096, 4096, 1024);

  // MLP2: split-K=4 -> fused reduce+bias+residual
  gemm_bt_sk<<<dim3(32 * 8, 4), 256, 0, stream>>>(act, w2b, part_m2, 4096, 1024, 4096, 1024);
  reduce_add<<<dim3(4096 * 1024 / 4 / 256), 256, 0, stream>>>(part_m2, h2, b2, out, 4096 * 1024, 1024, 4);
}

// Round 5
// 199.575 us; speedup vs baseline: 1.3484x; 1.0560x over previous
//
#include <hip/hip_runtime.h>

#define TOK 4096
#define EMB 1024

typedef __attribute__((ext_vector_type(8))) short s16x8;
typedef __attribute__((ext_vector_type(4))) float f32x4;

__device__ __forceinline__ unsigned short f2bf(float f) {
  union { float f; unsigned int u; } v; v.f = f;
  unsigned int r = v.u + 0x7FFFu + ((v.u >> 16) & 1u);
  return (unsigned short)(r >> 16);
}
__device__ __forceinline__ float bf2f(unsigned short u) {
  union { unsigned int u; float f; } v; v.u = ((unsigned int)u) << 16; return v.f;
}

#define GLOAD_LDS16(g, l) __builtin_amdgcn_global_load_lds( \
    (const __attribute__((address_space(1))) void*)(g), \
    (__attribute__((address_space(3))) void*)(l), 16, 0, 0)

// =================== 256x256 8-phase GEMM: C = A[M,K] @ B[N,K]^T (+bias/relu)
// 512 threads = 8 waves (2M x 4N). Per-wave out 128x64 (8x4 frags of 16x16).
// BK=64, double-buffered LDS (128 KiB). Optional split-K: blockIdx.y selects a
// Kc-wide K-slice; PART=1 writes bf16 partials at C + y*M*N (no bias).
// Phase plan (race-free ledger, verified round 4):
//   P1: ds_read alow(mf0-3)+bf0(nf0-1); stage HB1(kt+1)->buf p^1; MFMA q00.
//   P2: ds_read ahigh(mf4-7)+bf1(nf2-3); MFMA q10.   <- ALL buf-p reads done here
//   P3: stage HA0+HB0(kt+2)->buf p;                  MFMA q01.
//   P4: stage HA1(kt+2)->buf p;                      MFMA q11; vmcnt(6) gate.
// Gate invariant: 6 newest outstanding = the kt+2 stages; everything older
// (incl. HB1(kt+1)) complete -> tile kt+1 fully valid at its P1.
template<int RELU, int PART>
__global__ __launch_bounds__(512)
void gemm256(const unsigned short* __restrict__ A,
             const unsigned short* __restrict__ B,
             const float* __restrict__ bias,
             unsigned short* __restrict__ C, int M, int N, int K, int Kc)
{
  __shared__ unsigned short lds[2][2][256 * 64];  // [buf][0=A,1=B]
  const int tid = threadIdx.x;
  const int lane = tid & 63;
  const int w = tid >> 6;                 // 0..7
  const int wr = w >> 2, wc = w & 3;      // 2 x 4 wave grid
  const int l15 = lane & 15, lhi = lane >> 4;
  const int nbm = M >> 8;
  const int bm = blockIdx.x % nbm, bn = blockIdx.x / nbm;
  const int m0 = bm << 8, n0 = bn << 8;
  const int k0 = blockIdx.y * Kc;
  const int NT = Kc >> 6;

  const char* Abase = (const char*)(A + (size_t)m0 * K) + (size_t)k0 * 2;
  const char* Bbase = (const char*)(B + (size_t)n0 * K) + (size_t)k0 * 2;
  const size_t rowb = (size_t)K * 2;      // global row stride bytes

  // staging: thread t covers LDS half-tile byte t*16 (linear); global src col
  // pre-XORed so LDS[row][cc] holds global[row][cc ^ ((row&7)<<4)].
  const int srt = tid >> 3;               // row within 64-row block
  const int sccx = ((tid & 7) << 4) ^ ((srt & 7) << 4);

  auto stage = [&](const char* Gb, int kt, int h, int ab, int buf) {
    char* ldsb = (char*)&lds[buf][ab][0] + h * 16384 + (w << 10);  // wave-uniform
    const char* g = Gb + (size_t)(h * 128 + srt) * rowb + kt * 128 + sccx;
    GLOAD_LDS16(g, ldsb);
    GLOAD_LDS16(g + 64 * rowb, ldsb + 8192);
  };

  const int rdxor = (l15 & 7) << 4;
  auto rdA = [&](int buf, int mf, int ks) -> s16x8 {
    const int r = wr * 128 + mf * 16 + l15;
    const int cc = (ks * 64 + lhi * 16) ^ rdxor;
    return *(const s16x8*)((const char*)&lds[buf][0][0] + r * 128 + cc);
  };
  auto rdB = [&](int buf, int nf, int ks) -> s16x8 {
    const int r = wc * 64 + nf * 16 + l15;
    const int cc = (ks * 64 + lhi * 16) ^ rdxor;
    return *(const s16x8*)((const char*)&lds[buf][1][0] + r * 128 + cc);
  };

  f32x4 acc[8][4];
#pragma unroll
  for (int mf = 0; mf < 8; ++mf)
#pragma unroll
    for (int nf = 0; nf < 4; ++nf)
#pragma unroll
      for (int j = 0; j < 4; ++j) acc[mf][nf][j] = 0.f;

  // ---- prologue: tile0 fully + tile1 {HA0,HA1,HB0} = 14 loads; HB1(1) in P1
  stage(Abase, 0, 0, 0, 0); stage(Abase, 0, 1, 0, 0);
  stage(Bbase, 0, 0, 1, 0); stage(Bbase, 0, 1, 1, 0);
  stage(Abase, 1, 0, 0, 1); stage(Abase, 1, 1, 0, 1);
  stage(Bbase, 1, 0, 1, 1);
  asm volatile("s_waitcnt vmcnt(6)" ::: "memory");
  __builtin_amdgcn_s_barrier();

  s16x8 af[4][2], af2[4][2], bf0[2][2], bf1[2][2];

  for (int kt = 0; kt < NT; ++kt) {
    const int p = kt & 1;

    // ---- P1: read alow + bf0; stage HB1(kt+1) -> buf p^1; mfma q00
#pragma unroll
    for (int mi = 0; mi < 4; ++mi) { af[mi][0] = rdA(p, mi, 0); af[mi][1] = rdA(p, mi, 1); }
#pragma unroll
    for (int ni = 0; ni < 2; ++ni) { bf0[ni][0] = rdB(p, ni, 0); bf0[ni][1] = rdB(p, ni, 1); }
    if (kt + 1 < NT) stage(Bbase, kt + 1, 1, 1, p ^ 1);
    __builtin_amdgcn_s_barrier();
    asm volatile("s_waitcnt lgkmcnt(0)" ::: "memory");
    __builtin_amdgcn_sched_barrier(0);
    __builtin_amdgcn_s_setprio(1);
#pragma unroll
    for (int mi = 0; mi < 4; ++mi)
#pragma unroll
      for (int ni = 0; ni < 2; ++ni)
#pragma unroll
        for (int ks = 0; ks < 2; ++ks)
          acc[mi][ni] = __builtin_amdgcn_mfma_f32_16x16x32_bf16(af[mi][ks], bf0[ni][ks], acc[mi][ni], 0, 0, 0);
    __builtin_amdgcn_s_setprio(0);
    __builtin_amdgcn_s_barrier();

    // ---- P2: read ahigh + bf1 (completes ALL buf-p reads); mfma q10
#pragma unroll
    for (int mi = 0; mi < 4; ++mi) { af2[mi][0] = rdA(p, 4 + mi, 0); af2[mi][1] = rdA(p, 4 + mi, 1); }
#pragma unroll
    for (int ni = 0; ni < 2; ++ni) { bf1[ni][0] = rdB(p, 2 + ni, 0); bf1[ni][1] = rdB(p, 2 + ni, 1); }
    __builtin_amdgcn_s_barrier();
    asm volatile("s_waitcnt lgkmcnt(0)" ::: "memory");
    __builtin_amdgcn_sched_barrier(0);
    __builtin_amdgcn_s_setprio(1);
#pragma unroll
    for (int mi = 0; mi < 4; ++mi)
#pragma unroll
      for (int ni = 0; ni < 2; ++ni)
#pragma unroll
        for (int ks = 0; ks < 2; ++ks)
          acc[4 + mi][ni] = __builtin_amdgcn_mfma_f32_16x16x32_bf16(af2[mi][ks], bf0[ni][ks], acc[4 + mi][ni], 0, 0, 0);
    __builtin_amdgcn_s_setprio(0);
    __builtin_amdgcn_s_barrier();

    // ---- P3: stage HA0+HB0(kt+2) into buf p (all readers done at end-P2); mfma q01
    if (kt + 2 < NT) { stage(Abase, kt + 2, 0, 0, p); stage(Bbase, kt + 2, 0, 1, p); }
    __builtin_amdgcn_s_barrier();
    __builtin_amdgcn_s_setprio(1);
#pragma unroll
    for (int mi = 0; mi < 4; ++mi)
#pragma unroll
      for (int ni = 0; ni < 2; ++ni)
#pragma unroll
        for (int ks = 0; ks < 2; ++ks)
          acc[mi][2 + ni] = __builtin_amdgcn_mfma_f32_16x16x32_bf16(af[mi][ks], bf1[ni][ks], acc[mi][2 + ni], 0, 0, 0);
    __builtin_amdgcn_s_setprio(0);
    __builtin_amdgcn_s_barrier();

    // ---- P4: stage HA1(kt+2); mfma q11; end-of-tile vmcnt gate
    if (kt + 2 < NT) stage(Abase, kt + 2, 1, 0, p);
    __builtin_amdgcn_s_barrier();
    __builtin_amdgcn_s_setprio(1);
#pragma unroll
    for (int mi = 0; mi < 4; ++mi)
#pragma unroll
      for (int ni = 0; ni < 2; ++ni)
#pragma unroll
        for (int ks = 0; ks < 2; ++ks)
          acc[4 + mi][2 + ni] = __builtin_amdgcn_mfma_f32_16x16x32_bf16(af2[mi][ks], bf1[ni][ks], acc[4 + mi][2 + ni], 0, 0, 0);
    __builtin_amdgcn_s_setprio(0);
    if (kt + 1 < NT) {
      if (kt + 2 < NT) asm volatile("s_waitcnt vmcnt(6)" ::: "memory");
      else             asm volatile("s_waitcnt vmcnt(0)" ::: "memory");
      __builtin_amdgcn_s_barrier();
    }
  }

  // ---- epilogue
  unsigned short* Cw = PART ? C + (size_t)blockIdx.y * M * N : C;
#pragma unroll
  for (int mf = 0; mf < 8; ++mf) {
    const int row = m0 + wr * 128 + mf * 16 + lhi * 4;
#pragma unroll
    for (int nf = 0; nf < 4; ++nf) {
      const int col = n0 + wc * 64 + nf * 16 + l15;
      const float bv = PART ? 0.f : bias[col];
#pragma unroll
      for (int j = 0; j < 4; ++j) {
        float v = acc[mf][nf][j] + bv;
        if (RELU) v = fmaxf(v, 0.f);
        Cw[(size_t)(row + j) * N + col] = f2bf(v);
      }
    }
  }
}

// ---------------- reduce split-K partials + bias + residual -> fp32 out (MLP2 tail)
__global__ __launch_bounds__(256)
void reduce_add(const unsigned short* __restrict__ part, const float* __restrict__ res,
                const float* __restrict__ bias, float* __restrict__ out,
                int MN, int N, int S)
{
  const int i4 = (blockIdx.x * 256 + threadIdx.x) * 4;
  if (i4 >= MN) return;
  const int col = i4 & (N - 1);
  float4 v = *(const float4*)(res + i4);
  v.x += bias[col]; v.y += bias[col + 1]; v.z += bias[col + 2]; v.w += bias[col + 3];
  for (int s = 0; s < S; ++s) {
    const ushort4 p = *(const ushort4*)(part + (size_t)s * MN + i4);
    v.x += bf2f(p.x); v.y += bf2f(p.y); v.z += bf2f(p.z); v.w += bf2f(p.w);
  }
  *(float4*)(out + i4) = v;
}

// ---------------- reduce out-proj partials + bias + residual, then LayerNorm2
__global__ __launch_bounds__(256)
void reduce_ln(const unsigned short* __restrict__ part, const float* __restrict__ x,
               const float* __restrict__ ob, const float* __restrict__ ln_w,
               const float* __restrict__ ln_b, float* __restrict__ h2,
               unsigned short* __restrict__ m_in, int S)
{
  const int row = blockIdx.x;
  const int t = threadIdx.x;
  const size_t off = (size_t)row * EMB + t * 4;
  float4 v = *(const float4*)(x + off);
  const float4 obv = ((const float4*)ob)[t];
  v.x += obv.x; v.y += obv.y; v.z += obv.z; v.w += obv.w;
  for (int s = 0; s < S; ++s) {
    const ushort4 p = *(const ushort4*)(part + (size_t)s * TOK * EMB + off);
    v.x += bf2f(p.x); v.y += bf2f(p.y); v.z += bf2f(p.z); v.w += bf2f(p.w);
  }
  *(float4*)(h2 + off) = v;

  float s1 = v.x + v.y + v.z + v.w;
  float s2 = v.x * v.x + v.y * v.y + v.z * v.z + v.w * v.w;
#pragma unroll
  for (int o = 1; o < 64; o <<= 1) { s1 += __shfl_xor(s1, o); s2 += __shfl_xor(s2, o); }
  __shared__ float red[8];
  if ((t & 63) == 0) { red[t >> 6] = s1; red[4 + (t >> 6)] = s2; }
  __syncthreads();
  s1 = red[0] + red[1] + red[2] + red[3];
  s2 = red[4] + red[5] + red[6] + red[7];
  const float mu = s1 * (1.f / EMB);
  const float rs = rsqrtf(s2 * (1.f / EMB) - mu * mu + 1e-5f);
  const float4 wv = ((const float4*)ln_w)[t];
  const float4 bv = ((const float4*)ln_b)[t];
  ushort4 o;
  o.x = f2bf((v.x - mu) * rs * wv.x + bv.x);
  o.y = f2bf((v.y - mu) * rs * wv.y + bv.y);
  o.z = f2bf((v.z - mu) * rs * wv.z + bv.z);
  o.w = f2bf((v.w - mu) * rs * wv.w + bv.w);
  ((ushort4*)(m_in + (size_t)row * EMB))[t] = o;
}

// ---------------- LayerNorm fp32 -> bf16 (one block per row of 1024)
__global__ __launch_bounds__(256)
void ln_bf16(const float* __restrict__ x, const float* __restrict__ wt,
             const float* __restrict__ bs, unsigned short* __restrict__ out)
{
  const int row = blockIdx.x;
  const int t = threadIdx.x;
  const float4 v = ((const float4*)(x + (size_t)row * EMB))[t];
  float s = v.x + v.y + v.z + v.w;
  float s2 = v.x * v.x + v.y * v.y + v.z * v.z + v.w * v.w;
#pragma unroll
  for (int off = 1; off < 64; off <<= 1) { s += __shfl_xor(s, off); s2 += __shfl_xor(s2, off); }
  __shared__ float red[8];
  if ((t & 63) == 0) { red[t >> 6] = s; red[4 + (t >> 6)] = s2; }
  __syncthreads();
  s = red[0] + red[1] + red[2] + red[3];
  s2 = red[4] + red[5] + red[6] + red[7];
  const float mu = s * (1.f / EMB);
  const float rs = rsqrtf(s2 * (1.f / EMB) - mu * mu + 1e-5f);
  const float4 wv = ((const float4*)wt)[t];
  const float4 bv = ((const float4*)bs)[t];
  ushort4 o;
  o.x = f2bf((v.x - mu) * rs * wv.x + bv.x);
  o.y = f2bf((v.y - mu) * rs * wv.y + bv.y);
  o.z = f2bf((v.z - mu) * rs * wv.z + bv.z);
  o.w = f2bf((v.w - mu) * rs * wv.w + bv.w);
  ((ushort4*)(out + (size_t)row * EMB))[t] = o;
}

// ---------------- fp32 -> bf16 conversion of all four weight matrices, one launch
#define Q0 786432            // in_proj_w quads (3072*1024/4)
#define Q1 (Q0 + 262144)     // + out_w
#define Q2 (Q1 + 1048576)    // + w1
#define Q3 (Q2 + 1048576)    // + w2
__global__ __launch_bounds__(256)
void cvt4(const float* __restrict__ s0, const float* __restrict__ s1,
          const float* __restrict__ s2, const float* __restrict__ s3,
          unsigned short* __restrict__ d0, unsigned short* __restrict__ d1,
          unsigned short* __restrict__ d2, unsigned short* __restrict__ d3)
{
  const int i = blockIdx.x * 256 + threadIdx.x;
  const float* s; unsigned short* d; int off;
  if (i < Q0)      { s = s0; d = d0; off = i; }
  else if (i < Q1) { s = s1; d = d1; off = i - Q0; }
  else if (i < Q2) { s = s2; d = d2; off = i - Q1; }
  else             { s = s3; d = d3; off = i - Q2; }
  const float4 v = ((const float4*)s)[off];
  ushort4 o;
  o.x = f2bf(v.x); o.y = f2bf(v.y); o.z = f2bf(v.z); o.w = f2bf(v.w);
  ((ushort4*)d)[off] = o;
}

// ---------------- sliding-window causal attention, flash-style
__global__ __launch_bounds__(256)
void attn_win(const unsigned short* __restrict__ qkv, unsigned short* __restrict__ aout)
{
  __shared__ unsigned short Ks[64 * 136];
  __shared__ unsigned short Vt[128 * 72];
  __shared__ unsigned short Ps[4 * 16 * 72];
  const int bh = blockIdx.y;
  const int b = bh >> 3, hh = bh & 7;
  const int q0 = blockIdx.x << 6;
  const int tid = threadIdx.x, lane = tid & 63, w = tid >> 6;
  const int l15 = lane & 15, lhi = lane >> 4;
  const size_t base = (size_t)b * 2048 * 3072;

  s16x8 qf[4];
  {
    const unsigned short* qp = qkv + base + (size_t)(q0 + w * 16 + l15) * 3072 + hh * 128 + lhi * 8;
#pragma unroll
    for (int ks = 0; ks < 4; ++ks) qf[ks] = *(const s16x8*)(qp + ks * 32);
  }

  f32x4 o[8];
#pragma unroll
  for (int n = 0; n < 8; ++n)
#pragma unroll
    for (int j = 0; j < 4; ++j) o[n][j] = 0.f;
  float mrow[4] = {-1e30f, -1e30f, -1e30f, -1e30f};
  float lrow[4] = {0.f, 0.f, 0.f, 0.f};

  for (int t = 0; t < 5; ++t) {
    const int kt0 = q0 - 256 + t * 64;
    if (kt0 < 0) continue;
    __syncthreads();
    {
      const unsigned short* kg = qkv + base + (size_t)kt0 * 3072 + 1024 + hh * 128;
#pragma unroll
      for (int i = 0; i < 4; ++i) {
        const int c = tid + i * 256;
        const int r = c >> 4, cc = (c & 15) << 3;
        *(s16x8*)(Ks + r * 136 + cc) = *(const s16x8*)(kg + (size_t)r * 3072 + cc);
      }
      const unsigned short* vg = qkv + base + (size_t)kt0 * 3072 + 2048 + hh * 128;
#pragma unroll
      for (int i = 0; i < 2; ++i) {
        const int c = tid + i * 256;
        const int r2 = c >> 4, cc = (c & 15) << 3;
        s16x8 v0 = *(const s16x8*)(vg + (size_t)(2 * r2) * 3072 + cc);
        s16x8 v1 = *(const s16x8*)(vg + (size_t)(2 * r2 + 1) * 3072 + cc);
#pragma unroll
        for (int jj = 0; jj < 8; ++jj) {
          unsigned int pk = (unsigned int)(unsigned short)v0[jj] |
                            ((unsigned int)(unsigned short)v1[jj] << 16);
          *(unsigned int*)(Vt + (cc + jj) * 72 + 2 * r2) = pk;
        }
      }
    }
    __syncthreads();

    f32x4 s[4];
#pragma unroll
    for (int n = 0; n < 4; ++n)
#pragma unroll
      for (int j = 0; j < 4; ++j) s[n][j] = 0.f;
#pragma unroll
    for (int ks = 0; ks < 4; ++ks) {
#pragma unroll
      for (int n = 0; n < 4; ++n) {
        s16x8 kf = *(const s16x8*)(Ks + (n * 16 + l15) * 136 + ks * 32 + lhi * 8);
        s[n] = __builtin_amdgcn_mfma_f32_16x16x32_bf16(qf[ks], kf, s[n], 0, 0, 0);
      }
    }
    const bool mlo = (t == 0);
    const bool mhi = (kt0 == q0);
#pragma unroll
    for (int n = 0; n < 4; ++n) {
      const int kcol = n * 16 + l15;
#pragma unroll
      for (int j = 0; j < 4; ++j) {
        const int qrow = w * 16 + lhi * 4 + j;
        float v = s[n][j] * 0.08838834764831845f;
        if ((mlo && kcol < qrow) || (mhi && kcol > qrow)) v = -1e30f;
        s[n][j] = v;
      }
    }
    float alpha[4];
#pragma unroll
    for (int j = 0; j < 4; ++j) {
      float mx = fmaxf(fmaxf(s[0][j], s[1][j]), fmaxf(s[2][j], s[3][j]));
#pragma unroll
      for (int off = 1; off < 16; off <<= 1) mx = fmaxf(mx, __shfl_xor(mx, off));
      const float mn = fmaxf(mrow[j], mx);
      alpha[j] = __expf(mrow[j] - mn);
      mrow[j] = mn;
    }
    float rowsum[4] = {0.f, 0.f, 0.f, 0.f};
#pragma unroll
    for (int n = 0; n < 4; ++n)
#pragma unroll
      for (int j = 0; j < 4; ++j) {
        const float p = __expf(s[n][j] - mrow[j]);
        rowsum[j] += p;
        Ps[(w * 16 + lhi * 4 + j) * 72 + n * 16 + l15] = f2bf(p);
      }
#pragma unroll
    for (int j = 0; j < 4; ++j) {
      float rs = rowsum[j];
#pragma unroll
      for (int off = 1; off < 16; off <<= 1) rs += __shfl_xor(rs, off);
      lrow[j] = lrow[j] * alpha[j] + rs;
    }
#pragma unroll
    for (int n = 0; n < 8; ++n)
#pragma unroll
      for (int j = 0; j < 4; ++j) o[n][j] *= alpha[j];
#pragma unroll
    for (int ks = 0; ks < 2; ++ks) {
      const s16x8 pf = *(const s16x8*)(Ps + (w * 16 + l15) * 72 + ks * 32 + lhi * 8);
#pragma unroll
      for (int n = 0; n < 8; ++n) {
        const s16x8 vf = *(const s16x8*)(Vt + (n * 16 + l15) * 72 + ks * 32 + lhi * 8);
        o[n] = __builtin_amdgcn_mfma_f32_16x16x32_bf16(pf, vf, o[n], 0, 0, 0);
      }
    }
  }
  unsigned short* op = aout + (size_t)(b * 2048 + q0 + w * 16) * 1024 + hh * 128;
#pragma unroll
  for (int n = 0; n < 8; ++n)
#pragma unroll
    for (int j = 0; j < 4; ++j)
      op[(size_t)(lhi * 4 + j) * 1024 + n * 16 + l15] = f2bf(o[n][j] / lrow[j]);
}

extern "C" void kernel_launch(void* const* d_in, const int* in_sizes, int n_in,
                              void* d_out, int out_size, void* d_ws, size_t ws_size,
                              hipStream_t stream)
{
  (void)in_sizes; (void)n_in; (void)out_size; (void)ws_size;
  const float* x         = (const float*)d_in[0];
  const float* ln1_w     = (const float*)d_in[1];
  const float* ln1_b     = (const float*)d_in[2];
  const float* ln2_w     = (const float*)d_in[3];
  const float* ln2_b     = (const float*)d_in[4];
  const float* in_proj_w = (const float*)d_in[5];
  const float* in_proj_b = (const float*)d_in[6];
  const float* out_w     = (const float*)d_in[7];
  const float* out_b     = (const float*)d_in[8];
  const float* w1        = (const float*)d_in[9];
  const float* b1        = (const float*)d_in[10];
  const float* w2        = (const float*)d_in[11];
  const float* b2        = (const float*)d_in[12];
  float* out = (float*)d_out;

  char* ws = (char*)d_ws;
  unsigned short* h    = (unsigned short*)(ws);                 //  8 MiB  LN1 out bf16
  unsigned short* wqkv = (unsigned short*)(ws + (8u << 20));    //  6 MiB
  unsigned short* wout = (unsigned short*)(ws + (14u << 20));   //  2 MiB
  unsigned short* w1b  = (unsigned short*)(ws + (16u << 20));   //  8 MiB
  unsigned short* w2b  = (unsigned short*)(ws + (24u << 20));   //  8 MiB
  unsigned short* qkv  = (unsigned short*)(ws + (32u << 20));   // 24 MiB
  unsigned short* aout = (unsigned short*)(ws + (56u << 20));   //  8 MiB
  float*          h2   = (float*)(ws + (64u << 20));            // 16 MiB
  unsigned short* m_in = (unsigned short*)(ws + (80u << 20));   //  8 MiB
  unsigned short* act  = (unsigned short*)(ws + (88u << 20));   // 32 MiB (ends 120 MiB)
  unsigned short* part_op = (unsigned short*)(ws + (88u << 20)); // 32 MiB, act region (dead until MLP1)
  unsigned short* part_m2 = (unsigned short*)(ws + (32u << 20)); // 32 MiB, qkv+aout region (dead after out-proj)

  cvt4<<<dim3(Q3 / 256), 256, 0, stream>>>(in_proj_w, out_w, w1, w2, wqkv, wout, w1b, w2b);
  ln_bf16<<<dim3(TOK), 256, 0, stream>>>(x, ln1_w, ln1_b, h);

  // QKV: 256^2 8-phase (grid 16x12)
  gemm256<0, 0><<<dim3(16 * 12), 512, 0, stream>>>(h, wqkv, in_proj_b, qkv, 4096, 3072, 1024, 1024);
  attn_win<<<dim3(32, 16), 256, 0, stream>>>(qkv, aout);

  // out-proj: 8-phase split-K=4 (grid 64x4 = 256 blocks, NT=4) -> reduce+res+LN2
  gemm256<0, 1><<<dim3(16 * 4, 4), 512, 0, stream>>>(aout, wout, nullptr, part_op, 4096, 1024, 1024, 256);
  reduce_ln<<<dim3(TOK), 256, 0, stream>>>(part_op, x, out_b, ln2_w, ln2_b, h2, m_in, 4);

  // MLP1: 256^2 8-phase (grid 16x16) + relu
  gemm256<1, 0><<<dim3(16 * 16), 512, 0, stream>>>(m_in, w1b, b1, act, 4096, 4096, 1024, 1024);

  // MLP2: 8-phase split-K=4 (grid 64x4 = 256 blocks, NT=16) -> reduce+bias+res
  gemm256<0, 1><<<dim3(16 * 4, 4), 512, 0, stream>>>(act, w2b, nullptr, part_m2, 4096, 1024, 4096, 1024);
  reduce_add<<<dim3(4096 * 1024 / 4 / 256), 256, 0, stream>>>(part_m2, h2, b2, out, 4096 * 1024, 1024, 4);
}

// Round 6
// 197.956 us; speedup vs baseline: 1.3594x; 1.0082x over previous
//
#include <hip/hip_runtime.h>

#define TOK 4096
#define EMB 1024

typedef __attribute__((ext_vector_type(8))) short s16x8;
typedef __attribute__((ext_vector_type(4))) float f32x4;

__device__ __forceinline__ unsigned short f2bf(float f) {
  union { float f; unsigned int u; } v; v.f = f;
  unsigned int r = v.u + 0x7FFFu + ((v.u >> 16) & 1u);
  return (unsigned short)(r >> 16);
}
__device__ __forceinline__ float bf2f(unsigned short u) {
  union { unsigned int u; float f; } v; v.u = ((unsigned int)u) << 16; return v.f;
}

#define GLOAD_LDS16(g, l) __builtin_amdgcn_global_load_lds( \
    (const __attribute__((address_space(1))) void*)(g), \
    (__attribute__((address_space(3))) void*)(l), 16, 0, 0)

// =================== 256x256 8-phase GEMM: C = A[M,K] @ B[N,K]^T (+bias/relu)
// 512 threads = 8 waves (2M x 4N). Per-wave out 128x64 (8x4 frags of 16x16).
// BK=64, double-buffered LDS (128 KiB). Optional split-K via blockIdx.y/Kc.
// Phase plan (race-free ledger, re-audited round 6; reads spread 12/8/4/0):
//   P1: ds_read alow+bf0; stage HB1(kt+1)->buf p^1;  MFMA q00 (alow x bf0).
//   P2: ds_read ahigh;                               MFMA q10 (ahigh x bf0).
//       <- ALL buf-p A-region reads done at end-P2 barrier
//   P3: ds_read bf1; stage HA0+HA1(kt+2)->buf p;     MFMA q01 (alow x bf1).
//       <- ALL buf-p B-region reads done at end-P3 barrier
//   P4: stage HB0(kt+2)->buf p;                      MFMA q11; vmcnt(6) gate.
// Gate invariant: 6 newest outstanding = the kt+2 stages (HA0,HA1,HB0);
// everything older (incl. HB1(kt+1)) complete -> tile kt+1 fully valid at P1.
// XCD-rectangle remap (T1): default dispatch = XCD(lin)=lin&7; give each XCD a
// contiguous 8(bm) x nwg/64(bn) rectangle so its 32 concurrent blocks share
// A/B slabs (~6MB working set vs 16MB linear) -> staging L2-served, not L3.
template<int RELU, int PART>
__global__ __launch_bounds__(512)
void gemm256(const unsigned short* __restrict__ A,
             const unsigned short* __restrict__ B,
             const float* __restrict__ bias,
             unsigned short* __restrict__ C, int M, int N, int K, int Kc)
{
  __shared__ unsigned short lds[2][2][256 * 64];  // [buf][0=A,1=B]
  const int tid = threadIdx.x;
  const int lane = tid & 63;
  const int w = tid >> 6;                 // 0..7
  const int wr = w >> 2, wc = w & 3;      // 2 x 4 wave grid
  const int l15 = lane & 15, lhi = lane >> 4;
  const int nbm = M >> 8;                 // == 16 for all launches
  const int nwg = gridDim.x;              // multiple of 64
  const int xcd = blockIdx.x & 7;
  const int ii = blockIdx.x >> 3;
  const int bnR = nwg >> 6;               // bn-extent per XCD rectangle
  const int bm = ((xcd & 1) << 3) + (ii & 7);
  const int bn = (xcd >> 1) * bnR + (ii >> 3);
  const int m0 = bm << 8, n0 = bn << 8;
  const int k0 = blockIdx.y * Kc;
  const int NT = Kc >> 6;
  (void)nbm;

  const char* Abase = (const char*)(A + (size_t)m0 * K) + (size_t)k0 * 2;
  const char* Bbase = (const char*)(B + (size_t)n0 * K) + (size_t)k0 * 2;
  const size_t rowb = (size_t)K * 2;      // global row stride bytes

  // staging: thread t covers LDS half-tile byte t*16 (linear); global src col
  // pre-XORed so LDS[row][cc] holds global[row][cc ^ ((row&7)<<4)].
  const int srt = tid >> 3;               // row within 64-row block
  const int sccx = ((tid & 7) << 4) ^ ((srt & 7) << 4);

  auto stage = [&](const char* Gb, int kt, int h, int ab, int buf) {
    char* ldsb = (char*)&lds[buf][ab][0] + h * 16384 + (w << 10);  // wave-uniform
    const char* g = Gb + (size_t)(h * 128 + srt) * rowb + kt * 128 + sccx;
    GLOAD_LDS16(g, ldsb);
    GLOAD_LDS16(g + 64 * rowb, ldsb + 8192);
  };

  const int rdxor = (l15 & 7) << 4;
  auto rdA = [&](int buf, int mf, int ks) -> s16x8 {
    const int r = wr * 128 + mf * 16 + l15;
    const int cc = (ks * 64 + lhi * 16) ^ rdxor;
    return *(const s16x8*)((const char*)&lds[buf][0][0] + r * 128 + cc);
  };
  auto rdB = [&](int buf, int nf, int ks) -> s16x8 {
    const int r = wc * 64 + nf * 16 + l15;
    const int cc = (ks * 64 + lhi * 16) ^ rdxor;
    return *(const s16x8*)((const char*)&lds[buf][1][0] + r * 128 + cc);
  };

  f32x4 acc[8][4];
#pragma unroll
  for (int mf = 0; mf < 8; ++mf)
#pragma unroll
    for (int nf = 0; nf < 4; ++nf)
#pragma unroll
      for (int j = 0; j < 4; ++j) acc[mf][nf][j] = 0.f;

  // ---- prologue: tile0 fully + tile1 {HA0,HA1,HB0} = 14 loads; HB1(1) in P1
  stage(Abase, 0, 0, 0, 0); stage(Abase, 0, 1, 0, 0);
  stage(Bbase, 0, 0, 1, 0); stage(Bbase, 0, 1, 1, 0);
  stage(Abase, 1, 0, 0, 1); stage(Abase, 1, 1, 0, 1);
  stage(Bbase, 1, 0, 1, 1);
  asm volatile("s_waitcnt vmcnt(6)" ::: "memory");
  __builtin_amdgcn_s_barrier();

  s16x8 af[4][2], af2[4][2], bf0[2][2], bf1[2][2];

  for (int kt = 0; kt < NT; ++kt) {
    const int p = kt & 1;

    // ---- P1: read alow + bf0; stage HB1(kt+1) -> buf p^1; mfma q00
#pragma unroll
    for (int mi = 0; mi < 4; ++mi) { af[mi][0] = rdA(p, mi, 0); af[mi][1] = rdA(p, mi, 1); }
#pragma unroll
    for (int ni = 0; ni < 2; ++ni) { bf0[ni][0] = rdB(p, ni, 0); bf0[ni][1] = rdB(p, ni, 1); }
    if (kt + 1 < NT) stage(Bbase, kt + 1, 1, 1, p ^ 1);
    __builtin_amdgcn_s_barrier();
    asm volatile("s_waitcnt lgkmcnt(0)" ::: "memory");
    __builtin_amdgcn_sched_barrier(0);
    __builtin_amdgcn_s_setprio(1);
#pragma unroll
    for (int mi = 0; mi < 4; ++mi)
#pragma unroll
      for (int ni = 0; ni < 2; ++ni)
#pragma unroll
        for (int ks = 0; ks < 2; ++ks)
          acc[mi][ni] = __builtin_amdgcn_mfma_f32_16x16x32_bf16(af[mi][ks], bf0[ni][ks], acc[mi][ni], 0, 0, 0);
    __builtin_amdgcn_s_setprio(0);
    __builtin_amdgcn_s_barrier();

    // ---- P2: read ahigh (completes buf-p A reads); mfma q10
#pragma unroll
    for (int mi = 0; mi < 4; ++mi) { af2[mi][0] = rdA(p, 4 + mi, 0); af2[mi][1] = rdA(p, 4 + mi, 1); }
    __builtin_amdgcn_s_barrier();
    asm volatile("s_waitcnt lgkmcnt(0)" ::: "memory");
    __builtin_amdgcn_sched_barrier(0);
    __builtin_amdgcn_s_setprio(1);
#pragma unroll
    for (int mi = 0; mi < 4; ++mi)
#pragma unroll
      for (int ni = 0; ni < 2; ++ni)
#pragma unroll
        for (int ks = 0; ks < 2; ++ks)
          acc[4 + mi][ni] = __builtin_amdgcn_mfma_f32_16x16x32_bf16(af2[mi][ks], bf0[ni][ks], acc[4 + mi][ni], 0, 0, 0);
    __builtin_amdgcn_s_setprio(0);
    __builtin_amdgcn_s_barrier();

    // ---- P3: read bf1 (completes buf-p B reads); stage HA0+HA1(kt+2)->buf p; mfma q01
#pragma unroll
    for (int ni = 0; ni < 2; ++ni) { bf1[ni][0] = rdB(p, 2 + ni, 0); bf1[ni][1] = rdB(p, 2 + ni, 1); }
    if (kt + 2 < NT) { stage(Abase, kt + 2, 0, 0, p); stage(Abase, kt + 2, 1, 0, p); }
    __builtin_amdgcn_s_barrier();
    asm volatile("s_waitcnt lgkmcnt(0)" ::: "memory");
    __builtin_amdgcn_sched_barrier(0);
    __builtin_amdgcn_s_setprio(1);
#pragma unroll
    for (int mi = 0; mi < 4; ++mi)
#pragma unroll
      for (int ni = 0; ni < 2; ++ni)
#pragma unroll
        for (int ks = 0; ks < 2; ++ks)
          acc[mi][2 + ni] = __builtin_amdgcn_mfma_f32_16x16x32_bf16(af[mi][ks], bf1[ni][ks], acc[mi][2 + ni], 0, 0, 0);
    __builtin_amdgcn_s_setprio(0);
    __builtin_amdgcn_s_barrier();

    // ---- P4: stage HB0(kt+2)->buf p; mfma q11; end-of-tile vmcnt gate
    if (kt + 2 < NT) stage(Bbase, kt + 2, 0, 1, p);
    __builtin_amdgcn_s_barrier();
    __builtin_amdgcn_s_setprio(1);
#pragma unroll
    for (int mi = 0; mi < 4; ++mi)
#pragma unroll
      for (int ni = 0; ni < 2; ++ni)
#pragma unroll
        for (int ks = 0; ks < 2; ++ks)
          acc[4 + mi][2 + ni] = __builtin_amdgcn_mfma_f32_16x16x32_bf16(af2[mi][ks], bf1[ni][ks], acc[4 + mi][2 + ni], 0, 0, 0);
    __builtin_amdgcn_s_setprio(0);
    if (kt + 1 < NT) {
      if (kt + 2 < NT) asm volatile("s_waitcnt vmcnt(6)" ::: "memory");
      else             asm volatile("s_waitcnt vmcnt(0)" ::: "memory");
      __builtin_amdgcn_s_barrier();
    }
  }

  // ---- epilogue
  unsigned short* Cw = PART ? C + (size_t)blockIdx.y * M * N : C;
#pragma unroll
  for (int mf = 0; mf < 8; ++mf) {
    const int row = m0 + wr * 128 + mf * 16 + lhi * 4;
#pragma unroll
    for (int nf = 0; nf < 4; ++nf) {
      const int col = n0 + wc * 64 + nf * 16 + l15;
      const float bv = PART ? 0.f : bias[col];
#pragma unroll
      for (int j = 0; j < 4; ++j) {
        float v = acc[mf][nf][j] + bv;
        if (RELU) v = fmaxf(v, 0.f);
        Cw[(size_t)(row + j) * N + col] = f2bf(v);
      }
    }
  }
}

// ---------------- reduce split-K partials + bias + residual -> fp32 out (MLP2 tail)
__global__ __launch_bounds__(256)
void reduce_add(const unsigned short* __restrict__ part, const float* __restrict__ res,
                const float* __restrict__ bias, float* __restrict__ out,
                int MN, int N, int S)
{
  const int i4 = (blockIdx.x * 256 + threadIdx.x) * 4;
  if (i4 >= MN) return;
  const int col = i4 & (N - 1);
  float4 v = *(const float4*)(res + i4);
  v.x += bias[col]; v.y += bias[col + 1]; v.z += bias[col + 2]; v.w += bias[col + 3];
  for (int s = 0; s < S; ++s) {
    const ushort4 p = *(const ushort4*)(part + (size_t)s * MN + i4);
    v.x += bf2f(p.x); v.y += bf2f(p.y); v.z += bf2f(p.z); v.w += bf2f(p.w);
  }
  *(float4*)(out + i4) = v;
}

// ---------------- reduce out-proj partials + bias + residual, then LayerNorm2
__global__ __launch_bounds__(256)
void reduce_ln(const unsigned short* __restrict__ part, const float* __restrict__ x,
               const float* __restrict__ ob, const float* __restrict__ ln_w,
               const float* __restrict__ ln_b, float* __restrict__ h2,
               unsigned short* __restrict__ m_in, int S)
{
  const int row = blockIdx.x;
  const int t = threadIdx.x;
  const size_t off = (size_t)row * EMB + t * 4;
  float4 v = *(const float4*)(x + off);
  const float4 obv = ((const float4*)ob)[t];
  v.x += obv.x; v.y += obv.y; v.z += obv.z; v.w += obv.w;
  for (int s = 0; s < S; ++s) {
    const ushort4 p = *(const ushort4*)(part + (size_t)s * TOK * EMB + off);
    v.x += bf2f(p.x); v.y += bf2f(p.y); v.z += bf2f(p.z); v.w += bf2f(p.w);
  }
  *(float4*)(h2 + off) = v;

  float s1 = v.x + v.y + v.z + v.w;
  float s2 = v.x * v.x + v.y * v.y + v.z * v.z + v.w * v.w;
#pragma unroll
  for (int o = 1; o < 64; o <<= 1) { s1 += __shfl_xor(s1, o); s2 += __shfl_xor(s2, o); }
  __shared__ float red[8];
  if ((t & 63) == 0) { red[t >> 6] = s1; red[4 + (t >> 6)] = s2; }
  __syncthreads();
  s1 = red[0] + red[1] + red[2] + red[3];
  s2 = red[4] + red[5] + red[6] + red[7];
  const float mu = s1 * (1.f / EMB);
  const float rs = rsqrtf(s2 * (1.f / EMB) - mu * mu + 1e-5f);
  const float4 wv = ((const float4*)ln_w)[t];
  const float4 bv = ((const float4*)ln_b)[t];
  ushort4 o;
  o.x = f2bf((v.x - mu) * rs * wv.x + bv.x);
  o.y = f2bf((v.y - mu) * rs * wv.y + bv.y);
  o.z = f2bf((v.z - mu) * rs * wv.z + bv.z);
  o.w = f2bf((v.w - mu) * rs * wv.w + bv.w);
  ((ushort4*)(m_in + (size_t)row * EMB))[t] = o;
}

// ---------------- LayerNorm fp32 -> bf16 (one block per row of 1024)
__global__ __launch_bounds__(256)
void ln_bf16(const float* __restrict__ x, const float* __restrict__ wt,
             const float* __restrict__ bs, unsigned short* __restrict__ out)
{
  const int row = blockIdx.x;
  const int t = threadIdx.x;
  const float4 v = ((const float4*)(x + (size_t)row * EMB))[t];
  float s = v.x + v.y + v.z + v.w;
  float s2 = v.x * v.x + v.y * v.y + v.z * v.z + v.w * v.w;
#pragma unroll
  for (int off = 1; off < 64; off <<= 1) { s += __shfl_xor(s, off); s2 += __shfl_xor(s2, off); }
  __shared__ float red[8];
  if ((t & 63) == 0) { red[t >> 6] = s; red[4 + (t >> 6)] = s2; }
  __syncthreads();
  s = red[0] + red[1] + red[2] + red[3];
  s2 = red[4] + red[5] + red[6] + red[7];
  const float mu = s * (1.f / EMB);
  const float rs = rsqrtf(s2 * (1.f / EMB) - mu * mu + 1e-5f);
  const float4 wv = ((const float4*)wt)[t];
  const float4 bv = ((const float4*)bs)[t];
  ushort4 o;
  o.x = f2bf((v.x - mu) * rs * wv.x + bv.x);
  o.y = f2bf((v.y - mu) * rs * wv.y + bv.y);
  o.z = f2bf((v.z - mu) * rs * wv.z + bv.z);
  o.w = f2bf((v.w - mu) * rs * wv.w + bv.w);
  ((ushort4*)(out + (size_t)row * EMB))[t] = o;
}

// ---------------- fp32 -> bf16 conversion of all four weight matrices, one launch
#define Q0 786432            // in_proj_w quads (3072*1024/4)
#define Q1 (Q0 + 262144)     // + out_w
#define Q2 (Q1 + 1048576)    // + w1
#define Q3 (Q2 + 1048576)    // + w2
__global__ __launch_bounds__(256)
void cvt4(const float* __restrict__ s0, const float* __restrict__ s1,
          const float* __restrict__ s2, const float* __restrict__ s3,
          unsigned short* __restrict__ d0, unsigned short* __restrict__ d1,
          unsigned short* __restrict__ d2, unsigned short* __restrict__ d3)
{
  const int i = blockIdx.x * 256 + threadIdx.x;
  const float* s; unsigned short* d; int off;
  if (i < Q0)      { s = s0; d = d0; off = i; }
  else if (i < Q1) { s = s1; d = d1; off = i - Q0; }
  else if (i < Q2) { s = s2; d = d2; off = i - Q1; }
  else             { s = s3; d = d3; off = i - Q2; }
  const float4 v = ((const float4*)s)[off];
  ushort4 o;
  o.x = f2bf(v.x); o.y = f2bf(v.y); o.z = f2bf(v.z); o.w = f2bf(v.w);
  ((ushort4*)d)[off] = o;
}

// ---------------- sliding-window causal attention, flash-style
__global__ __launch_bounds__(256)
void attn_win(const unsigned short* __restrict__ qkv, unsigned short* __restrict__ aout)
{
  __shared__ unsigned short Ks[64 * 136];
  __shared__ unsigned short Vt[128 * 72];
  __shared__ unsigned short Ps[4 * 16 * 72];
  const int bh = blockIdx.y;
  const int b = bh >> 3, hh = bh & 7;
  const int q0 = blockIdx.x << 6;
  const int tid = threadIdx.x, lane = tid & 63, w = tid >> 6;
  const int l15 = lane & 15, lhi = lane >> 4;
  const size_t base = (size_t)b * 2048 * 3072;

  s16x8 qf[4];
  {
    const unsigned short* qp = qkv + base + (size_t)(q0 + w * 16 + l15) * 3072 + hh * 128 + lhi * 8;
#pragma unroll
    for (int ks = 0; ks < 4; ++ks) qf[ks] = *(const s16x8*)(qp + ks * 32);
  }

  f32x4 o[8];
#pragma unroll
  for (int n = 0; n < 8; ++n)
#pragma unroll
    for (int j = 0; j < 4; ++j) o[n][j] = 0.f;
  float mrow[4] = {-1e30f, -1e30f, -1e30f, -1e30f};
  float lrow[4] = {0.f, 0.f, 0.f, 0.f};

  for (int t = 0; t < 5; ++t) {
    const int kt0 = q0 - 256 + t * 64;
    if (kt0 < 0) continue;
    __syncthreads();
    {
      const unsigned short* kg = qkv + base + (size_t)kt0 * 3072 + 1024 + hh * 128;
#pragma unroll
      for (int i = 0; i < 4; ++i) {
        const int c = tid + i * 256;
        const int r = c >> 4, cc = (c & 15) << 3;
        *(s16x8*)(Ks + r * 136 + cc) = *(const s16x8*)(kg + (size_t)r * 3072 + cc);
      }
      const unsigned short* vg = qkv + base + (size_t)kt0 * 3072 + 2048 + hh * 128;
#pragma unroll
      for (int i = 0; i < 2; ++i) {
        const int c = tid + i * 256;
        const int r2 = c >> 4, cc = (c & 15) << 3;
        s16x8 v0 = *(const s16x8*)(vg + (size_t)(2 * r2) * 3072 + cc);
        s16x8 v1 = *(const s16x8*)(vg + (size_t)(2 * r2 + 1) * 3072 + cc);
#pragma unroll
        for (int jj = 0; jj < 8; ++jj) {
          unsigned int pk = (unsigned int)(unsigned short)v0[jj] |
                            ((unsigned int)(unsigned short)v1[jj] << 16);
          *(unsigned int*)(Vt + (cc + jj) * 72 + 2 * r2) = pk;
        }
      }
    }
    __syncthreads();

    f32x4 s[4];
#pragma unroll
    for (int n = 0; n < 4; ++n)
#pragma unroll
      for (int j = 0; j < 4; ++j) s[n][j] = 0.f;
#pragma unroll
    for (int ks = 0; ks < 4; ++ks) {
#pragma unroll
      for (int n = 0; n < 4; ++n) {
        s16x8 kf = *(const s16x8*)(Ks + (n * 16 + l15) * 136 + ks * 32 + lhi * 8);
        s[n] = __builtin_amdgcn_mfma_f32_16x16x32_bf16(qf[ks], kf, s[n], 0, 0, 0);
      }
    }
    const bool mlo = (t == 0);
    const bool mhi = (kt0 == q0);
#pragma unroll
    for (int n = 0; n < 4; ++n) {
      const int kcol = n * 16 + l15;
#pragma unroll
      for (int j = 0; j < 4; ++j) {
        const int qrow = w * 16 + lhi * 4 + j;
        float v = s[n][j] * 0.08838834764831845f;
        if ((mlo && kcol < qrow) || (mhi && kcol > qrow)) v = -1e30f;
        s[n][j] = v;
      }
    }
    float alpha[4];
#pragma unroll
    for (int j = 0; j < 4; ++j) {
      float mx = fmaxf(fmaxf(s[0][j], s[1][j]), fmaxf(s[2][j], s[3][j]));
#pragma unroll
      for (int off = 1; off < 16; off <<= 1) mx = fmaxf(mx, __shfl_xor(mx, off));
      const float mn = fmaxf(mrow[j], mx);
      alpha[j] = __expf(mrow[j] - mn);
      mrow[j] = mn;
    }
    float rowsum[4] = {0.f, 0.f, 0.f, 0.f};
#pragma unroll
    for (int n = 0; n < 4; ++n)
#pragma unroll
      for (int j = 0; j < 4; ++j) {
        const float p = __expf(s[n][j] - mrow[j]);
        rowsum[j] += p;
        Ps[(w * 16 + lhi * 4 + j) * 72 + n * 16 + l15] = f2bf(p);
      }
#pragma unroll
    for (int j = 0; j < 4; ++j) {
      float rs = rowsum[j];
#pragma unroll
      for (int off = 1; off < 16; off <<= 1) rs += __shfl_xor(rs, off);
      lrow[j] = lrow[j] * alpha[j] + rs;
    }
#pragma unroll
    for (int n = 0; n < 8; ++n)
#pragma unroll
      for (int j = 0; j < 4; ++j) o[n][j] *= alpha[j];
#pragma unroll
    for (int ks = 0; ks < 2; ++ks) {
      const s16x8 pf = *(const s16x8*)(Ps + (w * 16 + l15) * 72 + ks * 32 + lhi * 8);
#pragma unroll
      for (int n = 0; n < 8; ++n) {
        const s16x8 vf = *(const s16x8*)(Vt + (n * 16 + l15) * 72 + ks * 32 + lhi * 8);
        o[n] = __builtin_amdgcn_mfma_f32_16x16x32_bf16(pf, vf, o[n], 0, 0, 0);
      }
    }
  }
  unsigned short* op = aout + (size_t)(b * 2048 + q0 + w * 16) * 1024 + hh * 128;
#pragma unroll
  for (int n = 0; n < 8; ++n)
#pragma unroll
    for (int j = 0; j < 4; ++j)
      op[(size_t)(lhi * 4 + j) * 1024 + n * 16 + l15] = f2bf(o[n][j] / lrow[j]);
}

extern "C" void kernel_launch(void* const* d_in, const int* in_sizes, int n_in,
                              void* d_out, int out_size, void* d_ws, size_t ws_size,
                              hipStream_t stream)
{
  (void)in_sizes; (void)n_in; (void)out_size; (void)ws_size;
  const float* x         = (const float*)d_in[0];
  const float* ln1_w     = (const float*)d_in[1];
  const float* ln1_b     = (const float*)d_in[2];
  const float* ln2_w     = (const float*)d_in[3];
  const float* ln2_b     = (const float*)d_in[4];
  const float* in_proj_w = (const float*)d_in[5];
  const float* in_proj_b = (const float*)d_in[6];
  const float* out_w     = (const float*)d_in[7];
  const float* out_b     = (const float*)d_in[8];
  const float* w1        = (const float*)d_in[9];
  const float* b1        = (const float*)d_in[10];
  const float* w2        = (const float*)d_in[11];
  const float* b2        = (const float*)d_in[12];
  float* out = (float*)d_out;

  char* ws = (char*)d_ws;
  unsigned short* h    = (unsigned short*)(ws);                 //  8 MiB  LN1 out bf16
  unsigned short* wqkv = (unsigned short*)(ws + (8u << 20));    //  6 MiB
  unsigned short* wout = (unsigned short*)(ws + (14u << 20));   //  2 MiB
  unsigned short* w1b  = (unsigned short*)(ws + (16u << 20));   //  8 MiB
  unsigned short* w2b  = (unsigned short*)(ws + (24u << 20));   //  8 MiB
  unsigned short* qkv  = (unsigned short*)(ws + (32u << 20));   // 24 MiB
  unsigned short* aout = (unsigned short*)(ws + (56u << 20));   //  8 MiB
  float*          h2   = (float*)(ws + (64u << 20));            // 16 MiB
  unsigned short* m_in = (unsigned short*)(ws + (80u << 20));   //  8 MiB
  unsigned short* act  = (unsigned short*)(ws + (88u << 20));   // 32 MiB (ends 120 MiB)
  unsigned short* part_op = (unsigned short*)(ws + (88u << 20)); // 32 MiB, act region (dead until MLP1)
  unsigned short* part_m2 = (unsigned short*)(ws + (32u << 20)); // 32 MiB, qkv+aout region (dead after out-proj)

  cvt4<<<dim3(Q3 / 256), 256, 0, stream>>>(in_proj_w, out_w, w1, w2, wqkv, wout, w1b, w2b);
  ln_bf16<<<dim3(TOK), 256, 0, stream>>>(x, ln1_w, ln1_b, h);

  // QKV: 256^2 8-phase (grid 192)
  gemm256<0, 0><<<dim3(16 * 12), 512, 0, stream>>>(h, wqkv, in_proj_b, qkv, 4096, 3072, 1024, 1024);
  attn_win<<<dim3(32, 16), 256, 0, stream>>>(qkv, aout);

  // out-proj: 8-phase split-K=4 (grid 64x4, NT=4) -> reduce+res+LN2
  gemm256<0, 1><<<dim3(16 * 4, 4), 512, 0, stream>>>(aout, wout, nullptr, part_op, 4096, 1024, 1024, 256);
  reduce_ln<<<dim3(TOK), 256, 0, stream>>>(part_op, x, out_b, ln2_w, ln2_b, h2, m_in, 4);

  // MLP1: 256^2 8-phase (grid 256) + relu
  gemm256<1, 0><<<dim3(16 * 16), 512, 0, stream>>>(m_in, w1b, b1, act, 4096, 4096, 1024, 1024);

  // MLP2: 8-phase split-K=4 (grid 64x4, NT=16) -> reduce+bias+res
  gemm256<0, 1><<<dim3(16 * 4, 4), 512, 0, stream>>>(act, w2b, nullptr, part_m2, 4096, 1024, 4096, 1024);
  reduce_add<<<dim3(4096 * 1024 / 4 / 256), 256, 0, stream>>>(part_m2, h2, b2, out, 4096 * 1024, 1024, 4);
}

// Round 7
// 197.926 us; speedup vs baseline: 1.3596x; 1.0002x over previous
//
#include <hip/hip_runtime.h>

#define TOK 4096
#define EMB 1024

typedef __attribute__((ext_vector_type(8))) short s16x8;
typedef __attribute__((ext_vector_type(4))) float f32x4;

__device__ __forceinline__ unsigned short f2bf(float f) {
  union { float f; unsigned int u; } v; v.f = f;
  unsigned int r = v.u + 0x7FFFu + ((v.u >> 16) & 1u);
  return (unsigned short)(r >> 16);
}
__device__ __forceinline__ float bf2f(unsigned short u) {
  union { unsigned int u; float f; } v; v.u = ((unsigned int)u) << 16; return v.f;
}

#define GLOAD_LDS16(g, l) __builtin_amdgcn_global_load_lds( \
    (const __attribute__((address_space(1))) void*)(g), \
    (__attribute__((address_space(3))) void*)(l), 16, 0, 0)

// =================== 256x256 8-phase GEMM: C = A[M,K] @ B[N,K]^T (+bias/relu)
// 512 threads = 8 waves (2M x 4N). Per-wave out 128x64 (8x4 frags of 16x16).
// BK=64, double-buffered LDS (128 KiB). Optional split-K via blockIdx.y/Kc.
// Phase plan (race-free ledger, audited rounds 4/6):
//   P1: ds_read alow+bf0; stage HB1(kt+1)->buf p^1;  MFMA q00 (alow x bf0).
//   P2: ds_read ahigh;                               MFMA q10 (ahigh x bf0).
//       <- ALL buf-p A-region reads done at end-P2 barrier
//   P3: ds_read bf1; stage HA0+HA1(kt+2)->buf p;     MFMA q01 (alow x bf1).
//       <- ALL buf-p B-region reads done at end-P3 barrier
//   P4: stage HB0(kt+2)->buf p;                      MFMA q11; vmcnt(6) gate.
// Gate invariant: 6 newest outstanding = the kt+2 stages (HA0,HA1,HB0);
// everything older (incl. HB1(kt+1)) complete -> tile kt+1 fully valid at P1.
// NOTE (round 7): NO sched_barrier(0) here — m141 showed order-pinning costs
// ~40%; compiler tracks ds_read->MFMA register deps itself (rule #18 applies
// only to inline-asm ds_reads). waitcnts keep "memory" clobber so staging /
// ds_read ops cannot migrate across sync points.
template<int RELU, int PART>
__global__ __launch_bounds__(512)
void gemm256(const unsigned short* __restrict__ A,
             const unsigned short* __restrict__ B,
             const float* __restrict__ bias,
             unsigned short* __restrict__ C, int M, int N, int K, int Kc)
{
  __shared__ unsigned short lds[2][2][256 * 64];  // [buf][0=A,1=B]
  const int tid = threadIdx.x;
  const int lane = tid & 63;
  const int w = tid >> 6;                 // 0..7
  const int wr = w >> 2, wc = w & 3;      // 2 x 4 wave grid
  const int l15 = lane & 15, lhi = lane >> 4;
  const int nbm = M >> 8;
  const int bm = blockIdx.x % nbm, bn = blockIdx.x / nbm;
  const int m0 = bm << 8, n0 = bn << 8;
  const int k0 = blockIdx.y * Kc;
  const int NT = Kc >> 6;

  const char* Abase = (const char*)(A + (size_t)m0 * K) + (size_t)k0 * 2;
  const char* Bbase = (const char*)(B + (size_t)n0 * K) + (size_t)k0 * 2;
  const size_t rowb = (size_t)K * 2;      // global row stride bytes

  // staging: thread t covers LDS half-tile byte t*16 (linear); global src col
  // pre-XORed so LDS[row][cc] holds global[row][cc ^ ((row&7)<<4)].
  const int srt = tid >> 3;               // row within 64-row block
  const int sccx = ((tid & 7) << 4) ^ ((srt & 7) << 4);

  auto stage = [&](const char* Gb, int kt, int h, int ab, int buf) {
    char* ldsb = (char*)&lds[buf][ab][0] + h * 16384 + (w << 10);  // wave-uniform
    const char* g = Gb + (size_t)(h * 128 + srt) * rowb + kt * 128 + sccx;
    GLOAD_LDS16(g, ldsb);
    GLOAD_LDS16(g + 64 * rowb, ldsb + 8192);
  };

  const int rdxor = (l15 & 7) << 4;
  auto rdA = [&](int buf, int mf, int ks) -> s16x8 {
    const int r = wr * 128 + mf * 16 + l15;
    const int cc = (ks * 64 + lhi * 16) ^ rdxor;
    return *(const s16x8*)((const char*)&lds[buf][0][0] + r * 128 + cc);
  };
  auto rdB = [&](int buf, int nf, int ks) -> s16x8 {
    const int r = wc * 64 + nf * 16 + l15;
    const int cc = (ks * 64 + lhi * 16) ^ rdxor;
    return *(const s16x8*)((const char*)&lds[buf][1][0] + r * 128 + cc);
  };

  f32x4 acc[8][4];
#pragma unroll
  for (int mf = 0; mf < 8; ++mf)
#pragma unroll
    for (int nf = 0; nf < 4; ++nf)
#pragma unroll
      for (int j = 0; j < 4; ++j) acc[mf][nf][j] = 0.f;

  // ---- prologue: tile0 fully + tile1 {HA0,HA1,HB0} = 14 loads; HB1(1) in P1
  stage(Abase, 0, 0, 0, 0); stage(Abase, 0, 1, 0, 0);
  stage(Bbase, 0, 0, 1, 0); stage(Bbase, 0, 1, 1, 0);
  stage(Abase, 1, 0, 0, 1); stage(Abase, 1, 1, 0, 1);
  stage(Bbase, 1, 0, 1, 1);
  asm volatile("s_waitcnt vmcnt(6)" ::: "memory");
  __builtin_amdgcn_s_barrier();

  s16x8 af[4][2], af2[4][2], bf0[2][2], bf1[2][2];

  for (int kt = 0; kt < NT; ++kt) {
    const int p = kt & 1;

    // ---- P1: read alow + bf0; stage HB1(kt+1) -> buf p^1; mfma q00
#pragma unroll
    for (int mi = 0; mi < 4; ++mi) { af[mi][0] = rdA(p, mi, 0); af[mi][1] = rdA(p, mi, 1); }
#pragma unroll
    for (int ni = 0; ni < 2; ++ni) { bf0[ni][0] = rdB(p, ni, 0); bf0[ni][1] = rdB(p, ni, 1); }
    if (kt + 1 < NT) stage(Bbase, kt + 1, 1, 1, p ^ 1);
    __builtin_amdgcn_s_barrier();
    asm volatile("s_waitcnt lgkmcnt(0)" ::: "memory");
    __builtin_amdgcn_s_setprio(1);
#pragma unroll
    for (int mi = 0; mi < 4; ++mi)
#pragma unroll
      for (int ni = 0; ni < 2; ++ni)
#pragma unroll
        for (int ks = 0; ks < 2; ++ks)
          acc[mi][ni] = __builtin_amdgcn_mfma_f32_16x16x32_bf16(af[mi][ks], bf0[ni][ks], acc[mi][ni], 0, 0, 0);
    __builtin_amdgcn_s_setprio(0);
    __builtin_amdgcn_s_barrier();

    // ---- P2: read ahigh (completes buf-p A reads); mfma q10
#pragma unroll
    for (int mi = 0; mi < 4; ++mi) { af2[mi][0] = rdA(p, 4 + mi, 0); af2[mi][1] = rdA(p, 4 + mi, 1); }
    __builtin_amdgcn_s_barrier();
    asm volatile("s_waitcnt lgkmcnt(0)" ::: "memory");
    __builtin_amdgcn_s_setprio(1);
#pragma unroll
    for (int mi = 0; mi < 4; ++mi)
#pragma unroll
      for (int ni = 0; ni < 2; ++ni)
#pragma unroll
        for (int ks = 0; ks < 2; ++ks)
          acc[4 + mi][ni] = __builtin_amdgcn_mfma_f32_16x16x32_bf16(af2[mi][ks], bf0[ni][ks], acc[4 + mi][ni], 0, 0, 0);
    __builtin_amdgcn_s_setprio(0);
    __builtin_amdgcn_s_barrier();

    // ---- P3: read bf1 (completes buf-p B reads); stage HA0+HA1(kt+2)->buf p; mfma q01
#pragma unroll
    for (int ni = 0; ni < 2; ++ni) { bf1[ni][0] = rdB(p, 2 + ni, 0); bf1[ni][1] = rdB(p, 2 + ni, 1); }
    if (kt + 2 < NT) { stage(Abase, kt + 2, 0, 0, p); stage(Abase, kt + 2, 1, 0, p); }
    __builtin_amdgcn_s_barrier();
    asm volatile("s_waitcnt lgkmcnt(0)" ::: "memory");
    __builtin_amdgcn_s_setprio(1);
#pragma unroll
    for (int mi = 0; mi < 4; ++mi)
#pragma unroll
      for (int ni = 0; ni < 2; ++ni)
#pragma unroll
        for (int ks = 0; ks < 2; ++ks)
          acc[mi][2 + ni] = __builtin_amdgcn_mfma_f32_16x16x32_bf16(af[mi][ks], bf1[ni][ks], acc[mi][2 + ni], 0, 0, 0);
    __builtin_amdgcn_s_setprio(0);
    __builtin_amdgcn_s_barrier();

    // ---- P4: stage HB0(kt+2)->buf p; mfma q11; end-of-tile vmcnt gate
    if (kt + 2 < NT) stage(Bbase, kt + 2, 0, 1, p);
    __builtin_amdgcn_s_barrier();
    __builtin_amdgcn_s_setprio(1);
#pragma unroll
    for (int mi = 0; mi < 4; ++mi)
#pragma unroll
      for (int ni = 0; ni < 2; ++ni)
#pragma unroll
        for (int ks = 0; ks < 2; ++ks)
          acc[4 + mi][2 + ni] = __builtin_amdgcn_mfma_f32_16x16x32_bf16(af2[mi][ks], bf1[ni][ks], acc[4 + mi][2 + ni], 0, 0, 0);
    __builtin_amdgcn_s_setprio(0);
    if (kt + 1 < NT) {
      if (kt + 2 < NT) asm volatile("s_waitcnt vmcnt(6)" ::: "memory");
      else             asm volatile("s_waitcnt vmcnt(0)" ::: "memory");
      __builtin_amdgcn_s_barrier();
    }
  }

  // ---- epilogue
  unsigned short* Cw = PART ? C + (size_t)blockIdx.y * M * N : C;
#pragma unroll
  for (int mf = 0; mf < 8; ++mf) {
    const int row = m0 + wr * 128 + mf * 16 + lhi * 4;
#pragma unroll
    for (int nf = 0; nf < 4; ++nf) {
      const int col = n0 + wc * 64 + nf * 16 + l15;
      const float bv = PART ? 0.f : bias[col];
#pragma unroll
      for (int j = 0; j < 4; ++j) {
        float v = acc[mf][nf][j] + bv;
        if (RELU) v = fmaxf(v, 0.f);
        Cw[(size_t)(row + j) * N + col] = f2bf(v);
      }
    }
  }
}

// ---------------- reduce split-K partials + bias + residual -> fp32 out (MLP2 tail)
__global__ __launch_bounds__(256)
void reduce_add(const unsigned short* __restrict__ part, const float* __restrict__ res,
                const float* __restrict__ bias, float* __restrict__ out,
                int MN, int N, int S)
{
  const int i4 = (blockIdx.x * 256 + threadIdx.x) * 4;
  if (i4 >= MN) return;
  const int col = i4 & (N - 1);
  float4 v = *(const float4*)(res + i4);
  v.x += bias[col]; v.y += bias[col + 1]; v.z += bias[col + 2]; v.w += bias[col + 3];
  for (int s = 0; s < S; ++s) {
    const ushort4 p = *(const ushort4*)(part + (size_t)s * MN + i4);
    v.x += bf2f(p.x); v.y += bf2f(p.y); v.z += bf2f(p.z); v.w += bf2f(p.w);
  }
  *(float4*)(out + i4) = v;
}

// ---------------- reduce out-proj partials + bias + residual, then LayerNorm2
__global__ __launch_bounds__(256)
void reduce_ln(const unsigned short* __restrict__ part, const float* __restrict__ x,
               const float* __restrict__ ob, const float* __restrict__ ln_w,
               const float* __restrict__ ln_b, float* __restrict__ h2,
               unsigned short* __restrict__ m_in, int S)
{
  const int row = blockIdx.x;
  const int t = threadIdx.x;
  const size_t off = (size_t)row * EMB + t * 4;
  float4 v = *(const float4*)(x + off);
  const float4 obv = ((const float4*)ob)[t];
  v.x += obv.x; v.y += obv.y; v.z += obv.z; v.w += obv.w;
  for (int s = 0; s < S; ++s) {
    const ushort4 p = *(const ushort4*)(part + (size_t)s * TOK * EMB + off);
    v.x += bf2f(p.x); v.y += bf2f(p.y); v.z += bf2f(p.z); v.w += bf2f(p.w);
  }
  *(float4*)(h2 + off) = v;

  float s1 = v.x + v.y + v.z + v.w;
  float s2 = v.x * v.x + v.y * v.y + v.z * v.z + v.w * v.w;
#pragma unroll
  for (int o = 1; o < 64; o <<= 1) { s1 += __shfl_xor(s1, o); s2 += __shfl_xor(s2, o); }
  __shared__ float red[8];
  if ((t & 63) == 0) { red[t >> 6] = s1; red[4 + (t >> 6)] = s2; }
  __syncthreads();
  s1 = red[0] + red[1] + red[2] + red[3];
  s2 = red[4] + red[5] + red[6] + red[7];
  const float mu = s1 * (1.f / EMB);
  const float rs = rsqrtf(s2 * (1.f / EMB) - mu * mu + 1e-5f);
  const float4 wv = ((const float4*)ln_w)[t];
  const float4 bv = ((const float4*)ln_b)[t];
  ushort4 o;
  o.x = f2bf((v.x - mu) * rs * wv.x + bv.x);
  o.y = f2bf((v.y - mu) * rs * wv.y + bv.y);
  o.z = f2bf((v.z - mu) * rs * wv.z + bv.z);
  o.w = f2bf((v.w - mu) * rs * wv.w + bv.w);
  ((ushort4*)(m_in + (size_t)row * EMB))[t] = o;
}

// ---------------- LayerNorm fp32 -> bf16 (one block per row of 1024)
__global__ __launch_bounds__(256)
void ln_bf16(const float* __restrict__ x, const float* __restrict__ wt,
             const float* __restrict__ bs, unsigned short* __restrict__ out)
{
  const int row = blockIdx.x;
  const int t = threadIdx.x;
  const float4 v = ((const float4*)(x + (size_t)row * EMB))[t];
  float s = v.x + v.y + v.z + v.w;
  float s2 = v.x * v.x + v.y * v.y + v.z * v.z + v.w * v.w;
#pragma unroll
  for (int off = 1; off < 64; off <<= 1) { s += __shfl_xor(s, off); s2 += __shfl_xor(s2, off); }
  __shared__ float red[8];
  if ((t & 63) == 0) { red[t >> 6] = s; red[4 + (t >> 6)] = s2; }
  __syncthreads();
  s = red[0] + red[1] + red[2] + red[3];
  s2 = red[4] + red[5] + red[6] + red[7];
  const float mu = s * (1.f / EMB);
  const float rs = rsqrtf(s2 * (1.f / EMB) - mu * mu + 1e-5f);
  const float4 wv = ((const float4*)wt)[t];
  const float4 bv = ((const float4*)bs)[t];
  ushort4 o;
  o.x = f2bf((v.x - mu) * rs * wv.x + bv.x);
  o.y = f2bf((v.y - mu) * rs * wv.y + bv.y);
  o.z = f2bf((v.z - mu) * rs * wv.z + bv.z);
  o.w = f2bf((v.w - mu) * rs * wv.w + bv.w);
  ((ushort4*)(out + (size_t)row * EMB))[t] = o;
}

// ---------------- fp32 -> bf16 conversion of all four weight matrices, one launch
#define Q0 786432            // in_proj_w quads (3072*1024/4)
#define Q1 (Q0 + 262144)     // + out_w
#define Q2 (Q1 + 1048576)    // + w1
#define Q3 (Q2 + 1048576)    // + w2
__global__ __launch_bounds__(256)
void cvt4(const float* __restrict__ s0, const float* __restrict__ s1,
          const float* __restrict__ s2, const float* __restrict__ s3,
          unsigned short* __restrict__ d0, unsigned short* __restrict__ d1,
          unsigned short* __restrict__ d2, unsigned short* __restrict__ d3)
{
  const int i = blockIdx.x * 256 + threadIdx.x;
  const float* s; unsigned short* d; int off;
  if (i < Q0)      { s = s0; d = d0; off = i; }
  else if (i < Q1) { s = s1; d = d1; off = i - Q0; }
  else if (i < Q2) { s = s2; d = d2; off = i - Q1; }
  else             { s = s3; d = d3; off = i - Q2; }
  const float4 v = ((const float4*)s)[off];
  ushort4 o;
  o.x = f2bf(v.x); o.y = f2bf(v.y); o.z = f2bf(v.z); o.w = f2bf(v.w);
  ((ushort4*)d)[off] = o;
}

// ---------------- sliding-window causal attention, flash-style
__global__ __launch_bounds__(256)
void attn_win(const unsigned short* __restrict__ qkv, unsigned short* __restrict__ aout)
{
  __shared__ unsigned short Ks[64 * 136];
  __shared__ unsigned short Vt[128 * 72];
  __shared__ unsigned short Ps[4 * 16 * 72];
  const int bh = blockIdx.y;
  const int b = bh >> 3, hh = bh & 7;
  const int q0 = blockIdx.x << 6;
  const int tid = threadIdx.x, lane = tid & 63, w = tid >> 6;
  const int l15 = lane & 15, lhi = lane >> 4;
  const size_t base = (size_t)b * 2048 * 3072;

  s16x8 qf[4];
  {
    const unsigned short* qp = qkv + base + (size_t)(q0 + w * 16 + l15) * 3072 + hh * 128 + lhi * 8;
#pragma unroll
    for (int ks = 0; ks < 4; ++ks) qf[ks] = *(const s16x8*)(qp + ks * 32);
  }

  f32x4 o[8];
#pragma unroll
  for (int n = 0; n < 8; ++n)
#pragma unroll
    for (int j = 0; j < 4; ++j) o[n][j] = 0.f;
  float mrow[4] = {-1e30f, -1e30f, -1e30f, -1e30f};
  float lrow[4] = {0.f, 0.f, 0.f, 0.f};

  for (int t = 0; t < 5; ++t) {
    const int kt0 = q0 - 256 + t * 64;
    if (kt0 < 0) continue;
    __syncthreads();
    {
      const unsigned short* kg = qkv + base + (size_t)kt0 * 3072 + 1024 + hh * 128;
#pragma unroll
      for (int i = 0; i < 4; ++i) {
        const int c = tid + i * 256;
        const int r = c >> 4, cc = (c & 15) << 3;
        *(s16x8*)(Ks + r * 136 + cc) = *(const s16x8*)(kg + (size_t)r * 3072 + cc);
      }
      const unsigned short* vg = qkv + base + (size_t)kt0 * 3072 + 2048 + hh * 128;
#pragma unroll
      for (int i = 0; i < 2; ++i) {
        const int c = tid + i * 256;
        const int r2 = c >> 4, cc = (c & 15) << 3;
        s16x8 v0 = *(const s16x8*)(vg + (size_t)(2 * r2) * 3072 + cc);
        s16x8 v1 = *(const s16x8*)(vg + (size_t)(2 * r2 + 1) * 3072 + cc);
#pragma unroll
        for (int jj = 0; jj < 8; ++jj) {
          unsigned int pk = (unsigned int)(unsigned short)v0[jj] |
                            ((unsigned int)(unsigned short)v1[jj] << 16);
          *(unsigned int*)(Vt + (cc + jj) * 72 + 2 * r2) = pk;
        }
      }
    }
    __syncthreads();

    f32x4 s[4];
#pragma unroll
    for (int n = 0; n < 4; ++n)
#pragma unroll
      for (int j = 0; j < 4; ++j) s[n][j] = 0.f;
#pragma unroll
    for (int ks = 0; ks < 4; ++ks) {
#pragma unroll
      for (int n = 0; n < 4; ++n) {
        s16x8 kf = *(const s16x8*)(Ks + (n * 16 + l15) * 136 + ks * 32 + lhi * 8);
        s[n] = __builtin_amdgcn_mfma_f32_16x16x32_bf16(qf[ks], kf, s[n], 0, 0, 0);
      }
    }
    const bool mlo = (t == 0);
    const bool mhi = (kt0 == q0);
#pragma unroll
    for (int n = 0; n < 4; ++n) {
      const int kcol = n * 16 + l15;
#pragma unroll
      for (int j = 0; j < 4; ++j) {
        const int qrow = w * 16 + lhi * 4 + j;
        float v = s[n][j] * 0.08838834764831845f;
        if ((mlo && kcol < qrow) || (mhi && kcol > qrow)) v = -1e30f;
        s[n][j] = v;
      }
    }
    float alpha[4];
#pragma unroll
    for (int j = 0; j < 4; ++j) {
      float mx = fmaxf(fmaxf(s[0][j], s[1][j]), fmaxf(s[2][j], s[3][j]));
#pragma unroll
      for (int off = 1; off < 16; off <<= 1) mx = fmaxf(mx, __shfl_xor(mx, off));
      const float mn = fmaxf(mrow[j], mx);
      alpha[j] = __expf(mrow[j] - mn);
      mrow[j] = mn;
    }
    float rowsum[4] = {0.f, 0.f, 0.f, 0.f};
#pragma unroll
    for (int n = 0; n < 4; ++n)
#pragma unroll
      for (int j = 0; j < 4; ++j) {
        const float p = __expf(s[n][j] - mrow[j]);
        rowsum[j] += p;
        Ps[(w * 16 + lhi * 4 + j) * 72 + n * 16 + l15] = f2bf(p);
      }
#pragma unroll
    for (int j = 0; j < 4; ++j) {
      float rs = rowsum[j];
#pragma unroll
      for (int off = 1; off < 16; off <<= 1) rs += __shfl_xor(rs, off);
      lrow[j] = lrow[j] * alpha[j] + rs;
    }
#pragma unroll
    for (int n = 0; n < 8; ++n)
#pragma unroll
      for (int j = 0; j < 4; ++j) o[n][j] *= alpha[j];
#pragma unroll
    for (int ks = 0; ks < 2; ++ks) {
      const s16x8 pf = *(const s16x8*)(Ps + (w * 16 + l15) * 72 + ks * 32 + lhi * 8);
#pragma unroll
      for (int n = 0; n < 8; ++n) {
        const s16x8 vf = *(const s16x8*)(Vt + (n * 16 + l15) * 72 + ks * 32 + lhi * 8);
        o[n] = __builtin_amdgcn_mfma_f32_16x16x32_bf16(pf, vf, o[n], 0, 0, 0);
      }
    }
  }
  unsigned short* op = aout + (size_t)(b * 2048 + q0 + w * 16) * 1024 + hh * 128;
#pragma unroll
  for (int n = 0; n < 8; ++n)
#pragma unroll
    for (int j = 0; j < 4; ++j)
      op[(size_t)(lhi * 4 + j) * 1024 + n * 16 + l15] = f2bf(o[n][j] / lrow[j]);
}

extern "C" void kernel_launch(void* const* d_in, const int* in_sizes, int n_in,
                              void* d_out, int out_size, void* d_ws, size_t ws_size,
                              hipStream_t stream)
{
  (void)in_sizes; (void)n_in; (void)out_size; (void)ws_size;
  const float* x         = (const float*)d_in[0];
  const float* ln1_w     = (const float*)d_in[1];
  const float* ln1_b     = (const float*)d_in[2];
  const float* ln2_w     = (const float*)d_in[3];
  const float* ln2_b     = (const float*)d_in[4];
  const float* in_proj_w = (const float*)d_in[5];
  const float* in_proj_b = (const float*)d_in[6];
  const float* out_w     = (const float*)d_in[7];
  const float* out_b     = (const float*)d_in[8];
  const float* w1        = (const float*)d_in[9];
  const float* b1        = (const float*)d_in[10];
  const float* w2        = (const float*)d_in[11];
  const float* b2        = (const float*)d_in[12];
  float* out = (float*)d_out;

  char* ws = (char*)d_ws;
  unsigned short* h    = (unsigned short*)(ws);                 //  8 MiB  LN1 out bf16
  unsigned short* wqkv = (unsigned short*)(ws + (8u << 20));    //  6 MiB
  unsigned short* wout = (unsigned short*)(ws + (14u << 20));   //  2 MiB
  unsigned short* w1b  = (unsigned short*)(ws + (16u << 20));   //  8 MiB
  unsigned short* w2b  = (unsigned short*)(ws + (24u << 20));   //  8 MiB
  unsigned short* qkv  = (unsigned short*)(ws + (32u << 20));   // 24 MiB
  unsigned short* aout = (unsigned short*)(ws + (56u << 20));   //  8 MiB
  float*          h2   = (float*)(ws + (64u << 20));            // 16 MiB
  unsigned short* m_in = (unsigned short*)(ws + (80u << 20));   //  8 MiB
  unsigned short* act  = (unsigned short*)(ws + (88u << 20));   // 32 MiB (ends 120 MiB)
  unsigned short* part_op = (unsigned short*)(ws + (88u << 20)); // 32 MiB, act region (dead until MLP1)
  unsigned short* part_m2 = (unsigned short*)(ws + (32u << 20)); // 32 MiB, qkv+aout region (dead after out-proj)

  cvt4<<<dim3(Q3 / 256), 256, 0, stream>>>(in_proj_w, out_w, w1, w2, wqkv, wout, w1b, w2b);
  ln_bf16<<<dim3(TOK), 256, 0, stream>>>(x, ln1_w, ln1_b, h);

  // QKV: 256^2 8-phase (grid 192)
  gemm256<0, 0><<<dim3(16 * 12), 512, 0, stream>>>(h, wqkv, in_proj_b, qkv, 4096, 3072, 1024, 1024);
  attn_win<<<dim3(32, 16), 256, 0, stream>>>(qkv, aout);

  // out-proj: 8-phase split-K=4 (grid 64x4, NT=4) -> reduce+res+LN2
  gemm256<0, 1><<<dim3(16 * 4, 4), 512, 0, stream>>>(aout, wout, nullptr, part_op, 4096, 1024, 1024, 256);
  reduce_ln<<<dim3(TOK), 256, 0, stream>>>(part_op, x, out_b, ln2_w, ln2_b, h2, m_in, 4);

  // MLP1: 256^2 8-phase (grid 256) + relu
  gemm256<1, 0><<<dim3(16 * 16), 512, 0, stream>>>(m_in, w1b, b1, act, 4096, 4096, 1024, 1024);

  // MLP2: 8-phase split-K=4 (grid 64x4, NT=16) -> reduce+bias+res
  gemm256<0, 1><<<dim3(16 * 4, 4), 512, 0, stream>>>(act, w2b, nullptr, part_m2, 4096, 1024, 4096, 1024);
  reduce_add<<<dim3(4096 * 1024 / 4 / 256), 256, 0, stream>>>(part_m2, h2, b2, out, 4096 * 1024, 1024, 4);
}

// Round 8
// 195.476 us; speedup vs baseline: 1.3767x; 1.0125x over previous
//
#include <hip/hip_runtime.h>

#define TOK 4096
#define EMB 1024

typedef __attribute__((ext_vector_type(8))) short s16x8;
typedef __attribute__((ext_vector_type(4))) float f32x4;

__device__ __forceinline__ unsigned short f2bf(float f) {
  union { float f; unsigned int u; } v; v.f = f;
  unsigned int r = v.u + 0x7FFFu + ((v.u >> 16) & 1u);
  return (unsigned short)(r >> 16);
}
__device__ __forceinline__ float bf2f(unsigned short u) {
  union { unsigned int u; float f; } v; v.u = ((unsigned int)u) << 16; return v.f;
}

#define GLOAD_LDS16(g, l) __builtin_amdgcn_global_load_lds( \
    (const __attribute__((address_space(1))) void*)(g), \
    (__attribute__((address_space(3))) void*)(l), 16, 0, 0)

// =================== 256x256 GEMM, fused read+MFMA region (round 8)
// 512 threads = 8 waves (2M x 4N). Per-wave out 128x64 (8x4 frags of 16x16).
// BK=64, double-buffered LDS (128 KiB). Optional split-K via blockIdx.y/Kc.
// Round-8 structure: ONE region per K-tile containing all 24 ds_read_b128 AND
// all 64 MFMAs -> compiler emits fine-grained lgkmcnt(12/4/0) so the ~2300cy
// LDS drain hides under the ~2500cy MFMA stream (they were serialized by the
// old 8-barrier phase structure: reads and MFMAs in disjoint barrier regions).
// Barriers: 2 per tile.
//   region: reads(af,bf0,af2,bf1 of buf p) | stage HB1(kt+1)->p^1 | 64 MFMA
//   mid-barrier   <- every wave's reads of p consumed by its MFMAs => complete
//   stage HA0,HA1,HB0(kt+2)->buf p
//   vmcnt(6) gate (6 newest = kt+2 stages; all kt+1 data forced complete)
//   barrier
// Race ledger (audited): HB1(kt+1) writes p^1 early — p^1 has no readers during
// tile kt, and tile kt-1's readers finished before its own mid-barrier. kt+2
// stages write p only after mid-barrier. Gate invariant unchanged from round 4.
template<int RELU, int PART>
__global__ __launch_bounds__(512)
void gemm256(const unsigned short* __restrict__ A,
             const unsigned short* __restrict__ B,
             const float* __restrict__ bias,
             unsigned short* __restrict__ C, int M, int N, int K, int Kc)
{
  __shared__ unsigned short lds[2][2][256 * 64];  // [buf][0=A,1=B]
  const int tid = threadIdx.x;
  const int lane = tid & 63;
  const int w = tid >> 6;                 // 0..7
  const int wr = w >> 2, wc = w & 3;      // 2 x 4 wave grid
  const int l15 = lane & 15, lhi = lane >> 4;
  const int nbm = M >> 8;
  const int bm = blockIdx.x % nbm, bn = blockIdx.x / nbm;
  const int m0 = bm << 8, n0 = bn << 8;
  const int k0 = blockIdx.y * Kc;
  const int NT = Kc >> 6;

  const char* Abase = (const char*)(A + (size_t)m0 * K) + (size_t)k0 * 2;
  const char* Bbase = (const char*)(B + (size_t)n0 * K) + (size_t)k0 * 2;
  const size_t rowb = (size_t)K * 2;      // global row stride bytes

  // staging: thread t covers LDS half-tile byte t*16 (linear); global src col
  // pre-XORed so LDS[row][cc] holds global[row][cc ^ ((row&7)<<4)].
  const int srt = tid >> 3;               // row within 64-row block
  const int sccx = ((tid & 7) << 4) ^ ((srt & 7) << 4);

  auto stage = [&](const char* Gb, int kt, int h, int ab, int buf) {
    char* ldsb = (char*)&lds[buf][ab][0] + h * 16384 + (w << 10);  // wave-uniform
    const char* g = Gb + (size_t)(h * 128 + srt) * rowb + kt * 128 + sccx;
    GLOAD_LDS16(g, ldsb);
    GLOAD_LDS16(g + 64 * rowb, ldsb + 8192);
  };

  const int rdxor = (l15 & 7) << 4;
  auto rdA = [&](int buf, int mf, int ks) -> s16x8 {
    const int r = wr * 128 + mf * 16 + l15;
    const int cc = (ks * 64 + lhi * 16) ^ rdxor;
    return *(const s16x8*)((const char*)&lds[buf][0][0] + r * 128 + cc);
  };
  auto rdB = [&](int buf, int nf, int ks) -> s16x8 {
    const int r = wc * 64 + nf * 16 + l15;
    const int cc = (ks * 64 + lhi * 16) ^ rdxor;
    return *(const s16x8*)((const char*)&lds[buf][1][0] + r * 128 + cc);
  };

  f32x4 acc[8][4];
#pragma unroll
  for (int mf = 0; mf < 8; ++mf)
#pragma unroll
    for (int nf = 0; nf < 4; ++nf)
#pragma unroll
      for (int j = 0; j < 4; ++j) acc[mf][nf][j] = 0.f;

  // ---- prologue: tile0 fully + tile1 {HA0,HA1,HB0} = 14 loads; HB1(1) in-region
  stage(Abase, 0, 0, 0, 0); stage(Abase, 0, 1, 0, 0);
  stage(Bbase, 0, 0, 1, 0); stage(Bbase, 0, 1, 1, 0);
  stage(Abase, 1, 0, 0, 1); stage(Abase, 1, 1, 0, 1);
  stage(Bbase, 1, 0, 1, 1);
  asm volatile("s_waitcnt vmcnt(6)" ::: "memory");
  __builtin_amdgcn_s_barrier();

  s16x8 af[4][2], af2[4][2], bf0[2][2], bf1[2][2];

  for (int kt = 0; kt < NT; ++kt) {
    const int p = kt & 1;

    // ---- read ALL buf-p fragments, ordered for in-order DS completion:
    //      af+bf0 (q00) first, then af2 (q10), then bf1 (q01/q11)
#pragma unroll
    for (int mi = 0; mi < 4; ++mi) { af[mi][0] = rdA(p, mi, 0); af[mi][1] = rdA(p, mi, 1); }
#pragma unroll
    for (int ni = 0; ni < 2; ++ni) { bf0[ni][0] = rdB(p, ni, 0); bf0[ni][1] = rdB(p, ni, 1); }
#pragma unroll
    for (int mi = 0; mi < 4; ++mi) { af2[mi][0] = rdA(p, 4 + mi, 0); af2[mi][1] = rdA(p, 4 + mi, 1); }
#pragma unroll
    for (int ni = 0; ni < 2; ++ni) { bf1[ni][0] = rdB(p, 2 + ni, 0); bf1[ni][1] = rdB(p, 2 + ni, 1); }

    // ---- early stage HB1(kt+1) -> buf p^1 (p^1 has no readers this tile)
    if (kt + 1 < NT) stage(Bbase, kt + 1, 1, 1, p ^ 1);

    // ---- 64-MFMA stream; compiler interleaves with read drain (fine lgkmcnt)
    __builtin_amdgcn_s_setprio(1);
#pragma unroll
    for (int mi = 0; mi < 4; ++mi)
#pragma unroll
      for (int ni = 0; ni < 2; ++ni)
#pragma unroll
        for (int ks = 0; ks < 2; ++ks)
          acc[mi][ni] = __builtin_amdgcn_mfma_f32_16x16x32_bf16(af[mi][ks], bf0[ni][ks], acc[mi][ni], 0, 0, 0);
#pragma unroll
    for (int mi = 0; mi < 4; ++mi)
#pragma unroll
      for (int ni = 0; ni < 2; ++ni)
#pragma unroll
        for (int ks = 0; ks < 2; ++ks)
          acc[4 + mi][ni] = __builtin_amdgcn_mfma_f32_16x16x32_bf16(af2[mi][ks], bf0[ni][ks], acc[4 + mi][ni], 0, 0, 0);
#pragma unroll
    for (int mi = 0; mi < 4; ++mi)
#pragma unroll
      for (int ni = 0; ni < 2; ++ni)
#pragma unroll
        for (int ks = 0; ks < 2; ++ks)
          acc[mi][2 + ni] = __builtin_amdgcn_mfma_f32_16x16x32_bf16(af[mi][ks], bf1[ni][ks], acc[mi][2 + ni], 0, 0, 0);
#pragma unroll
    for (int mi = 0; mi < 4; ++mi)
#pragma unroll
      for (int ni = 0; ni < 2; ++ni)
#pragma unroll
        for (int ks = 0; ks < 2; ++ks)
          acc[4 + mi][2 + ni] = __builtin_amdgcn_mfma_f32_16x16x32_bf16(af2[mi][ks], bf1[ni][ks], acc[4 + mi][2 + ni], 0, 0, 0);
    __builtin_amdgcn_s_setprio(0);

    // ---- mid-barrier: all waves' reads of buf p complete (consumed by MFMAs)
    __builtin_amdgcn_s_barrier();

    // ---- stage HA0,HA1,HB0(kt+2) -> buf p (now write-safe)
    if (kt + 2 < NT) {
      stage(Abase, kt + 2, 0, 0, p);
      stage(Abase, kt + 2, 1, 0, p);
      stage(Bbase, kt + 2, 0, 1, p);
    }

    // ---- end-of-tile vmcnt gate: tile kt+1 fully valid after this barrier
    if (kt + 1 < NT) {
      if (kt + 2 < NT) asm volatile("s_waitcnt vmcnt(6)" ::: "memory");
      else             asm volatile("s_waitcnt vmcnt(0)" ::: "memory");
      __builtin_amdgcn_s_barrier();
    }
  }

  // ---- epilogue
  unsigned short* Cw = PART ? C + (size_t)blockIdx.y * M * N : C;
#pragma unroll
  for (int mf = 0; mf < 8; ++mf) {
    const int row = m0 + wr * 128 + mf * 16 + lhi * 4;
#pragma unroll
    for (int nf = 0; nf < 4; ++nf) {
      const int col = n0 + wc * 64 + nf * 16 + l15;
      const float bv = PART ? 0.f : bias[col];
#pragma unroll
      for (int j = 0; j < 4; ++j) {
        float v = acc[mf][nf][j] + bv;
        if (RELU) v = fmaxf(v, 0.f);
        Cw[(size_t)(row + j) * N + col] = f2bf(v);
      }
    }
  }
}

// ---------------- reduce split-K partials + bias + residual -> fp32 out (MLP2 tail)
__global__ __launch_bounds__(256)
void reduce_add(const unsigned short* __restrict__ part, const float* __restrict__ res,
                const float* __restrict__ bias, float* __restrict__ out,
                int MN, int N, int S)
{
  const int i4 = (blockIdx.x * 256 + threadIdx.x) * 4;
  if (i4 >= MN) return;
  const int col = i4 & (N - 1);
  float4 v = *(const float4*)(res + i4);
  v.x += bias[col]; v.y += bias[col + 1]; v.z += bias[col + 2]; v.w += bias[col + 3];
  for (int s = 0; s < S; ++s) {
    const ushort4 p = *(const ushort4*)(part + (size_t)s * MN + i4);
    v.x += bf2f(p.x); v.y += bf2f(p.y); v.z += bf2f(p.z); v.w += bf2f(p.w);
  }
  *(float4*)(out + i4) = v;
}

// ---------------- reduce out-proj partials + bias + residual, then LayerNorm2
__global__ __launch_bounds__(256)
void reduce_ln(const unsigned short* __restrict__ part, const float* __restrict__ x,
               const float* __restrict__ ob, const float* __restrict__ ln_w,
               const float* __restrict__ ln_b, float* __restrict__ h2,
               unsigned short* __restrict__ m_in, int S)
{
  const int row = blockIdx.x;
  const int t = threadIdx.x;
  const size_t off = (size_t)row * EMB + t * 4;
  float4 v = *(const float4*)(x + off);
  const float4 obv = ((const float4*)ob)[t];
  v.x += obv.x; v.y += obv.y; v.z += obv.z; v.w += obv.w;
  for (int s = 0; s < S; ++s) {
    const ushort4 p = *(const ushort4*)(part + (size_t)s * TOK * EMB + off);
    v.x += bf2f(p.x); v.y += bf2f(p.y); v.z += bf2f(p.z); v.w += bf2f(p.w);
  }
  *(float4*)(h2 + off) = v;

  float s1 = v.x + v.y + v.z + v.w;
  float s2 = v.x * v.x + v.y * v.y + v.z * v.z + v.w * v.w;
#pragma unroll
  for (int o = 1; o < 64; o <<= 1) { s1 += __shfl_xor(s1, o); s2 += __shfl_xor(s2, o); }
  __shared__ float red[8];
  if ((t & 63) == 0) { red[t >> 6] = s1; red[4 + (t >> 6)] = s2; }
  __syncthreads();
  s1 = red[0] + red[1] + red[2] + red[3];
  s2 = red[4] + red[5] + red[6] + red[7];
  const float mu = s1 * (1.f / EMB);
  const float rs = rsqrtf(s2 * (1.f / EMB) - mu * mu + 1e-5f);
  const float4 wv = ((const float4*)ln_w)[t];
  const float4 bv = ((const float4*)ln_b)[t];
  ushort4 o;
  o.x = f2bf((v.x - mu) * rs * wv.x + bv.x);
  o.y = f2bf((v.y - mu) * rs * wv.y + bv.y);
  o.z = f2bf((v.z - mu) * rs * wv.z + bv.z);
  o.w = f2bf((v.w - mu) * rs * wv.w + bv.w);
  ((ushort4*)(m_in + (size_t)row * EMB))[t] = o;
}

// ---------------- LayerNorm fp32 -> bf16 (one block per row of 1024)
__global__ __launch_bounds__(256)
void ln_bf16(const float* __restrict__ x, const float* __restrict__ wt,
             const float* __restrict__ bs, unsigned short* __restrict__ out)
{
  const int row = blockIdx.x;
  const int t = threadIdx.x;
  const float4 v = ((const float4*)(x + (size_t)row * EMB))[t];
  float s = v.x + v.y + v.z + v.w;
  float s2 = v.x * v.x + v.y * v.y + v.z * v.z + v.w * v.w;
#pragma unroll
  for (int off = 1; off < 64; off <<= 1) { s += __shfl_xor(s, off); s2 += __shfl_xor(s2, off); }
  __shared__ float red[8];
  if ((t & 63) == 0) { red[t >> 6] = s; red[4 + (t >> 6)] = s2; }
  __syncthreads();
  s = red[0] + red[1] + red[2] + red[3];
  s2 = red[4] + red[5] + red[6] + red[7];
  const float mu = s * (1.f / EMB);
  const float rs = rsqrtf(s2 * (1.f / EMB) - mu * mu + 1e-5f);
  const float4 wv = ((const float4*)wt)[t];
  const float4 bv = ((const float4*)bs)[t];
  ushort4 o;
  o.x = f2bf((v.x - mu) * rs * wv.x + bv.x);
  o.y = f2bf((v.y - mu) * rs * wv.y + bv.y);
  o.z = f2bf((v.z - mu) * rs * wv.z + bv.z);
  o.w = f2bf((v.w - mu) * rs * wv.w + bv.w);
  ((ushort4*)(out + (size_t)row * EMB))[t] = o;
}

// ---------------- fp32 -> bf16 conversion of all four weight matrices, one launch
#define Q0 786432            // in_proj_w quads (3072*1024/4)
#define Q1 (Q0 + 262144)     // + out_w
#define Q2 (Q1 + 1048576)    // + w1
#define Q3 (Q2 + 1048576)    // + w2
__global__ __launch_bounds__(256)
void cvt4(const float* __restrict__ s0, const float* __restrict__ s1,
          const float* __restrict__ s2, const float* __restrict__ s3,
          unsigned short* __restrict__ d0, unsigned short* __restrict__ d1,
          unsigned short* __restrict__ d2, unsigned short* __restrict__ d3)
{
  const int i = blockIdx.x * 256 + threadIdx.x;
  const float* s; unsigned short* d; int off;
  if (i < Q0)      { s = s0; d = d0; off = i; }
  else if (i < Q1) { s = s1; d = d1; off = i - Q0; }
  else if (i < Q2) { s = s2; d = d2; off = i - Q1; }
  else             { s = s3; d = d3; off = i - Q2; }
  const float4 v = ((const float4*)s)[off];
  ushort4 o;
  o.x = f2bf(v.x); o.y = f2bf(v.y); o.z = f2bf(v.z); o.w = f2bf(v.w);
  ((ushort4*)d)[off] = o;
}

// ---------------- sliding-window causal attention, flash-style
__global__ __launch_bounds__(256)
void attn_win(const unsigned short* __restrict__ qkv, unsigned short* __restrict__ aout)
{
  __shared__ unsigned short Ks[64 * 136];
  __shared__ unsigned short Vt[128 * 72];
  __shared__ unsigned short Ps[4 * 16 * 72];
  const int bh = blockIdx.y;
  const int b = bh >> 3, hh = bh & 7;
  const int q0 = blockIdx.x << 6;
  const int tid = threadIdx.x, lane = tid & 63, w = tid >> 6;
  const int l15 = lane & 15, lhi = lane >> 4;
  const size_t base = (size_t)b * 2048 * 3072;

  s16x8 qf[4];
  {
    const unsigned short* qp = qkv + base + (size_t)(q0 + w * 16 + l15) * 3072 + hh * 128 + lhi * 8;
#pragma unroll
    for (int ks = 0; ks < 4; ++ks) qf[ks] = *(const s16x8*)(qp + ks * 32);
  }

  f32x4 o[8];
#pragma unroll
  for (int n = 0; n < 8; ++n)
#pragma unroll
    for (int j = 0; j < 4; ++j) o[n][j] = 0.f;
  float mrow[4] = {-1e30f, -1e30f, -1e30f, -1e30f};
  float lrow[4] = {0.f, 0.f, 0.f, 0.f};

  for (int t = 0; t < 5; ++t) {
    const int kt0 = q0 - 256 + t * 64;
    if (kt0 < 0) continue;
    __syncthreads();
    {
      const unsigned short* kg = qkv + base + (size_t)kt0 * 3072 + 1024 + hh * 128;
#pragma unroll
      for (int i = 0; i < 4; ++i) {
        const int c = tid + i * 256;
        const int r = c >> 4, cc = (c & 15) << 3;
        *(s16x8*)(Ks + r * 136 + cc) = *(const s16x8*)(kg + (size_t)r * 3072 + cc);
      }
      const unsigned short* vg = qkv + base + (size_t)kt0 * 3072 + 2048 + hh * 128;
#pragma unroll
      for (int i = 0; i < 2; ++i) {
        const int c = tid + i * 256;
        const int r2 = c >> 4, cc = (c & 15) << 3;
        s16x8 v0 = *(const s16x8*)(vg + (size_t)(2 * r2) * 3072 + cc);
        s16x8 v1 = *(const s16x8*)(vg + (size_t)(2 * r2 + 1) * 3072 + cc);
#pragma unroll
        for (int jj = 0; jj < 8; ++jj) {
          unsigned int pk = (unsigned int)(unsigned short)v0[jj] |
                            ((unsigned int)(unsigned short)v1[jj] << 16);
          *(unsigned int*)(Vt + (cc + jj) * 72 + 2 * r2) = pk;
        }
      }
    }
    __syncthreads();

    f32x4 s[4];
#pragma unroll
    for (int n = 0; n < 4; ++n)
#pragma unroll
      for (int j = 0; j < 4; ++j) s[n][j] = 0.f;
#pragma unroll
    for (int ks = 0; ks < 4; ++ks) {
#pragma unroll
      for (int n = 0; n < 4; ++n) {
        s16x8 kf = *(const s16x8*)(Ks + (n * 16 + l15) * 136 + ks * 32 + lhi * 8);
        s[n] = __builtin_amdgcn_mfma_f32_16x16x32_bf16(qf[ks], kf, s[n], 0, 0, 0);
      }
    }
    const bool mlo = (t == 0);
    const bool mhi = (kt0 == q0);
#pragma unroll
    for (int n = 0; n < 4; ++n) {
      const int kcol = n * 16 + l15;
#pragma unroll
      for (int j = 0; j < 4; ++j) {
        const int qrow = w * 16 + lhi * 4 + j;
        float v = s[n][j] * 0.08838834764831845f;
        if ((mlo && kcol < qrow) || (mhi && kcol > qrow)) v = -1e30f;
        s[n][j] = v;
      }
    }
    float alpha[4];
#pragma unroll
    for (int j = 0; j < 4; ++j) {
      float mx = fmaxf(fmaxf(s[0][j], s[1][j]), fmaxf(s[2][j], s[3][j]));
#pragma unroll
      for (int off = 1; off < 16; off <<= 1) mx = fmaxf(mx, __shfl_xor(mx, off));
      const float mn = fmaxf(mrow[j], mx);
      alpha[j] = __expf(mrow[j] - mn);
      mrow[j] = mn;
    }
    float rowsum[4] = {0.f, 0.f, 0.f, 0.f};
#pragma unroll
    for (int n = 0; n < 4; ++n)
#pragma unroll
      for (int j = 0; j < 4; ++j) {
        const float p = __expf(s[n][j] - mrow[j]);
        rowsum[j] += p;
        Ps[(w * 16 + lhi * 4 + j) * 72 + n * 16 + l15] = f2bf(p);
      }
#pragma unroll
    for (int j = 0; j < 4; ++j) {
      float rs = rowsum[j];
#pragma unroll
      for (int off = 1; off < 16; off <<= 1) rs += __shfl_xor(rs, off);
      lrow[j] = lrow[j] * alpha[j] + rs;
    }
#pragma unroll
    for (int n = 0; n < 8; ++n)
#pragma unroll
      for (int j = 0; j < 4; ++j) o[n][j] *= alpha[j];
#pragma unroll
    for (int ks = 0; ks < 2; ++ks) {
      const s16x8 pf = *(const s16x8*)(Ps + (w * 16 + l15) * 72 + ks * 32 + lhi * 8);
#pragma unroll
      for (int n = 0; n < 8; ++n) {
        const s16x8 vf = *(const s16x8*)(Vt + (n * 16 + l15) * 72 + ks * 32 + lhi * 8);
        o[n] = __builtin_amdgcn_mfma_f32_16x16x32_bf16(pf, vf, o[n], 0, 0, 0);
      }
    }
  }
  unsigned short* op = aout + (size_t)(b * 2048 + q0 + w * 16) * 1024 + hh * 128;
#pragma unroll
  for (int n = 0; n < 8; ++n)
#pragma unroll
    for (int j = 0; j < 4; ++j)
      op[(size_t)(lhi * 4 + j) * 1024 + n * 16 + l15] = f2bf(o[n][j] / lrow[j]);
}

extern "C" void kernel_launch(void* const* d_in, const int* in_sizes, int n_in,
                              void* d_out, int out_size, void* d_ws, size_t ws_size,
                              hipStream_t stream)
{
  (void)in_sizes; (void)n_in; (void)out_size; (void)ws_size;
  const float* x         = (const float*)d_in[0];
  const float* ln1_w     = (const float*)d_in[1];
  const float* ln1_b     = (const float*)d_in[2];
  const float* ln2_w     = (const float*)d_in[3];
  const float* ln2_b     = (const float*)d_in[4];
  const float* in_proj_w = (const float*)d_in[5];
  const float* in_proj_b = (const float*)d_in[6];
  const float* out_w     = (const float*)d_in[7];
  const float* out_b     = (const float*)d_in[8];
  const float* w1        = (const float*)d_in[9];
  const float* b1        = (const float*)d_in[10];
  const float* w2        = (const float*)d_in[11];
  const float* b2        = (const float*)d_in[12];
  float* out = (float*)d_out;

  char* ws = (char*)d_ws;
  unsigned short* h    = (unsigned short*)(ws);                 //  8 MiB  LN1 out bf16
  unsigned short* wqkv = (unsigned short*)(ws + (8u << 20));    //  6 MiB
  unsigned short* wout = (unsigned short*)(ws + (14u << 20));   //  2 MiB
  unsigned short* w1b  = (unsigned short*)(ws + (16u << 20));   //  8 MiB
  unsigned short* w2b  = (unsigned short*)(ws + (24u << 20));   //  8 MiB
  unsigned short* qkv  = (unsigned short*)(ws + (32u << 20));   // 24 MiB
  unsigned short* aout = (unsigned short*)(ws + (56u << 20));   //  8 MiB
  float*          h2   = (float*)(ws + (64u << 20));            // 16 MiB
  unsigned short* m_in = (unsigned short*)(ws + (80u << 20));   //  8 MiB
  unsigned short* act  = (unsigned short*)(ws + (88u << 20));   // 32 MiB (ends 120 MiB)
  unsigned short* part_op = (unsigned short*)(ws + (88u << 20)); // 32 MiB, act region (dead until MLP1)
  unsigned short* part_m2 = (unsigned short*)(ws + (32u << 20)); // 32 MiB, qkv+aout region (dead after out-proj)

  cvt4<<<dim3(Q3 / 256), 256, 0, stream>>>(in_proj_w, out_w, w1, w2, wqkv, wout, w1b, w2b);
  ln_bf16<<<dim3(TOK), 256, 0, stream>>>(x, ln1_w, ln1_b, h);

  // QKV: 256^2 (grid 192)
  gemm256<0, 0><<<dim3(16 * 12), 512, 0, stream>>>(h, wqkv, in_proj_b, qkv, 4096, 3072, 1024, 1024);
  attn_win<<<dim3(32, 16), 256, 0, stream>>>(qkv, aout);

  // out-proj: split-K=4 (grid 64x4, NT=4) -> reduce+res+LN2
  gemm256<0, 1><<<dim3(16 * 4, 4), 512, 0, stream>>>(aout, wout, nullptr, part_op, 4096, 1024, 1024, 256);
  reduce_ln<<<dim3(TOK), 256, 0, stream>>>(part_op, x, out_b, ln2_w, ln2_b, h2, m_in, 4);

  // MLP1: 256^2 (grid 256) + relu
  gemm256<1, 0><<<dim3(16 * 16), 512, 0, stream>>>(m_in, w1b, b1, act, 4096, 4096, 1024, 1024);

  // MLP2: split-K=4 (grid 64x4, NT=16) -> reduce+bias+res
  gemm256<0, 1><<<dim3(16 * 4, 4), 512, 0, stream>>>(act, w2b, nullptr, part_m2, 4096, 1024, 4096, 1024);
  reduce_add<<<dim3(4096 * 1024 / 4 / 256), 256, 0, stream>>>(part_m2, h2, b2, out, 4096 * 1024, 1024, 4);
}

// Round 9
// 191.369 us; speedup vs baseline: 1.4062x; 1.0215x over previous
//
#include <hip/hip_runtime.h>

#define TOK 4096
#define EMB 1024

typedef __attribute__((ext_vector_type(8))) short s16x8;
typedef __attribute__((ext_vector_type(4))) float f32x4;

__device__ __forceinline__ unsigned short f2bf(float f) {
  union { float f; unsigned int u; } v; v.f = f;
  unsigned int r = v.u + 0x7FFFu + ((v.u >> 16) & 1u);
  return (unsigned short)(r >> 16);
}
__device__ __forceinline__ float bf2f(unsigned short u) {
  union { unsigned int u; float f; } v; v.u = ((unsigned int)u) << 16; return v.f;
}

#define GLOAD_LDS16(g, l) __builtin_amdgcn_global_load_lds( \
    (const __attribute__((address_space(1))) void*)(g), \
    (__attribute__((address_space(3))) void*)(l), 16, 0, 0)

// =================== 256x256 GEMM, fused region + hoisted addresses (round 9)
// 512 threads = 8 waves (2M x 4N), per-wave out 128x64, BK=64, dbuf LDS 128KB.
// NT is a TEMPLATE param -> K-loop fully unrolled -> kt literal:
//  * LDS layout [matrix][buf][32KB]: buf toggle = +32768B, fits ds_read's
//    16-bit offset immediate. 4 per-lane read base ptrs; every fragment read
//    = base + mf*2048 + (kt&1)*32768, all compile-time -> ZERO per-tile VALU.
//  * global stage addresses: base + kt*128 folds into load offset (<=1920B).
// Rationale: r8 counters showed VALUBusy 18.5% = ~1100cy/tile of lockstep
// per-tile address recomputation serializing with MFMA issue (HK technique 8:
// precomputed swizzled offsets). Schedule/race ledger unchanged from round 8:
//   region{ reads(24, ordered af0-3,bf0-1,af4-7,bf2-3) | stage HB1(kt+1)->p^1
//           | 64 MFMA } ; mid-barrier ; stage HA0,HA1,HB0(kt+2)->p ;
//   vmcnt(6) gate (6 newest = kt+2 stages) ; barrier.
template<int RELU, int PART, int NT>
__global__ __launch_bounds__(512)
void gemm256(const unsigned short* __restrict__ A,
             const unsigned short* __restrict__ B,
             const float* __restrict__ bias,
             unsigned short* __restrict__ C, int M, int N, int K)
{
  __shared__ unsigned short lds[2][2][128 * 128];  // [matrix][buf][16384 shorts]
  const int tid = threadIdx.x;
  const int lane = tid & 63;
  const int w = tid >> 6;                 // 0..7
  const int wr = w >> 2, wc = w & 3;      // 2 x 4 wave grid
  const int l15 = lane & 15, lhi = lane >> 4;
  const int nbm = M >> 8;
  const int bm = blockIdx.x % nbm, bn = blockIdx.x / nbm;
  const int m0 = bm << 8, n0 = bn << 8;
  const int k0 = blockIdx.y * (NT * 64);

  const char* Abase = (const char*)(A + (size_t)m0 * K) + (size_t)k0 * 2;
  const char* Bbase = (const char*)(B + (size_t)n0 * K) + (size_t)k0 * 2;
  const size_t rowb = (size_t)K * 2;      // global row stride bytes

  // staging: thread t covers LDS half-tile byte t*16 (linear); global src col
  // pre-XORed so LDS[row][cc] holds global[row][cc ^ ((row&7)<<4)].
  const int srt = tid >> 3;               // row within 64-row block
  const int sccx = ((tid & 7) << 4) ^ ((srt & 7) << 4);
  const char* gA = Abase + (size_t)srt * rowb + sccx;   // A half0 rows 0-63 base
  const char* gB = Bbase + (size_t)srt * rowb + sccx;

  // stage half h (128 rows) of K-tile ktl (LITERAL) for matrix ab into buf p
  auto STAGE_A = [&](int ktl, int h, int p) {
    char* d = (char*)&lds[0][0][0] + p * 32768 + h * 16384 + (w << 10);
    const char* g = gA + (size_t)(h * 128) * rowb + ktl * 128;
    GLOAD_LDS16(g, d);
    GLOAD_LDS16(g + 64 * rowb, d + 8192);
  };
  auto STAGE_B = [&](int ktl, int h, int p) {
    char* d = (char*)&lds[1][0][0] + p * 32768 + h * 16384 + (w << 10);
    const char* g = gB + (size_t)(h * 128) * rowb + ktl * 128;
    GLOAD_LDS16(g, d);
    GLOAD_LDS16(g + 64 * rowb, d + 8192);
  };

  // 4 hoisted per-lane read base pointers (buf0, mf/nf=0); reads use
  // compile-time adders: + frag*2048 + (kt&1)*32768  (max 47104 < 65536).
  const int rdxor = (l15 & 7) << 4;
  const char* pA0 = (const char*)&lds[0][0][0] + (wr * 128 + l15) * 128 + ((0 * 64 + lhi * 16) ^ rdxor);
  const char* pA1 = (const char*)&lds[0][0][0] + (wr * 128 + l15) * 128 + ((1 * 64 + lhi * 16) ^ rdxor);
  const char* pB0 = (const char*)&lds[1][0][0] + (wc * 64 + l15) * 128 + ((0 * 64 + lhi * 16) ^ rdxor);
  const char* pB1 = (const char*)&lds[1][0][0] + (wc * 64 + l15) * 128 + ((1 * 64 + lhi * 16) ^ rdxor);

  f32x4 acc[8][4];
#pragma unroll
  for (int mf = 0; mf < 8; ++mf)
#pragma unroll
    for (int nf = 0; nf < 4; ++nf)
#pragma unroll
      for (int j = 0; j < 4; ++j) acc[mf][nf][j] = 0.f;

  // ---- prologue: tile0 fully + tile1 {HA0,HA1,HB0} = 14 loads; HB1(1) in-region
  STAGE_A(0, 0, 0); STAGE_A(0, 1, 0);
  STAGE_B(0, 0, 0); STAGE_B(0, 1, 0);
  STAGE_A(1, 0, 1); STAGE_A(1, 1, 1);
  STAGE_B(1, 0, 1);
  asm volatile("s_waitcnt vmcnt(6)" ::: "memory");
  __builtin_amdgcn_s_barrier();

  s16x8 af[8][2], bf[4][2];

#pragma unroll
  for (int kt = 0; kt < NT; ++kt) {
    const int P = (kt & 1) << 15;   // compile-time after unroll
    const int p = kt & 1;

    // ---- reads (ordered for in-order DS completion vs MFMA groups)
#pragma unroll
    for (int mi = 0; mi < 4; ++mi) {
      af[mi][0] = *(const s16x8*)(pA0 + mi * 2048 + P);
      af[mi][1] = *(const s16x8*)(pA1 + mi * 2048 + P);
    }
#pragma unroll
    for (int ni = 0; ni < 2; ++ni) {
      bf[ni][0] = *(const s16x8*)(pB0 + ni * 2048 + P);
      bf[ni][1] = *(const s16x8*)(pB1 + ni * 2048 + P);
    }
#pragma unroll
    for (int mi = 4; mi < 8; ++mi) {
      af[mi][0] = *(const s16x8*)(pA0 + mi * 2048 + P);
      af[mi][1] = *(const s16x8*)(pA1 + mi * 2048 + P);
    }
#pragma unroll
    for (int ni = 2; ni < 4; ++ni) {
      bf[ni][0] = *(const s16x8*)(pB0 + ni * 2048 + P);
      bf[ni][1] = *(const s16x8*)(pB1 + ni * 2048 + P);
    }

    // ---- early stage HB1(kt+1) -> buf p^1 (no readers of p^1 this tile)
    if (kt + 1 < NT) STAGE_B(kt + 1, 1, p ^ 1);

    // ---- 64-MFMA stream; compiler interleaves with read drain
    __builtin_amdgcn_s_setprio(1);
#pragma unroll
    for (int mi = 0; mi < 4; ++mi)
#pragma unroll
      for (int ni = 0; ni < 2; ++ni)
#pragma unroll
        for (int ks = 0; ks < 2; ++ks)
          acc[mi][ni] = __builtin_amdgcn_mfma_f32_16x16x32_bf16(af[mi][ks], bf[ni][ks], acc[mi][ni], 0, 0, 0);
#pragma unroll
    for (int mi = 4; mi < 8; ++mi)
#pragma unroll
      for (int ni = 0; ni < 2; ++ni)
#pragma unroll
        for (int ks = 0; ks < 2; ++ks)
          acc[mi][ni] = __builtin_amdgcn_mfma_f32_16x16x32_bf16(af[mi][ks], bf[ni][ks], acc[mi][ni], 0, 0, 0);
#pragma unroll
    for (int mi = 0; mi < 4; ++mi)
#pragma unroll
      for (int ni = 2; ni < 4; ++ni)
#pragma unroll
        for (int ks = 0; ks < 2; ++ks)
          acc[mi][ni] = __builtin_amdgcn_mfma_f32_16x16x32_bf16(af[mi][ks], bf[ni][ks], acc[mi][ni], 0, 0, 0);
#pragma unroll
    for (int mi = 4; mi < 8; ++mi)
#pragma unroll
      for (int ni = 2; ni < 4; ++ni)
#pragma unroll
        for (int ks = 0; ks < 2; ++ks)
          acc[mi][ni] = __builtin_amdgcn_mfma_f32_16x16x32_bf16(af[mi][ks], bf[ni][ks], acc[mi][ni], 0, 0, 0);
    __builtin_amdgcn_s_setprio(0);

    // ---- mid-barrier: all waves' reads of buf p complete (consumed by MFMAs)
    __builtin_amdgcn_s_barrier();

    // ---- stage HA0,HA1,HB0(kt+2) -> buf p (now write-safe)
    if (kt + 2 < NT) {
      STAGE_A(kt + 2, 0, p);
      STAGE_A(kt + 2, 1, p);
      STAGE_B(kt + 2, 0, p);
    }

    // ---- end-of-tile vmcnt gate: tile kt+1 fully valid after this barrier
    if (kt + 1 < NT) {
      if (kt + 2 < NT) asm volatile("s_waitcnt vmcnt(6)" ::: "memory");
      else             asm volatile("s_waitcnt vmcnt(0)" ::: "memory");
      __builtin_amdgcn_s_barrier();
    }
  }

  // ---- epilogue
  unsigned short* Cw = PART ? C + (size_t)blockIdx.y * M * N : C;
#pragma unroll
  for (int mf = 0; mf < 8; ++mf) {
    const int row = m0 + wr * 128 + mf * 16 + lhi * 4;
#pragma unroll
    for (int nf = 0; nf < 4; ++nf) {
      const int col = n0 + wc * 64 + nf * 16 + l15;
      const float bv = PART ? 0.f : bias[col];
#pragma unroll
      for (int j = 0; j < 4; ++j) {
        float v = acc[mf][nf][j] + bv;
        if (RELU) v = fmaxf(v, 0.f);
        Cw[(size_t)(row + j) * N + col] = f2bf(v);
      }
    }
  }
}

// ---------------- reduce split-K partials + bias + residual -> fp32 out (MLP2 tail)
__global__ __launch_bounds__(256)
void reduce_add(const unsigned short* __restrict__ part, const float* __restrict__ res,
                const float* __restrict__ bias, float* __restrict__ out,
                int MN, int N, int S)
{
  const int i4 = (blockIdx.x * 256 + threadIdx.x) * 4;
  if (i4 >= MN) return;
  const int col = i4 & (N - 1);
  float4 v = *(const float4*)(res + i4);
  v.x += bias[col]; v.y += bias[col + 1]; v.z += bias[col + 2]; v.w += bias[col + 3];
  for (int s = 0; s < S; ++s) {
    const ushort4 p = *(const ushort4*)(part + (size_t)s * MN + i4);
    v.x += bf2f(p.x); v.y += bf2f(p.y); v.z += bf2f(p.z); v.w += bf2f(p.w);
  }
  *(float4*)(out + i4) = v;
}

// ---------------- reduce out-proj partials + bias + residual, then LayerNorm2
__global__ __launch_bounds__(256)
void reduce_ln(const unsigned short* __restrict__ part, const float* __restrict__ x,
               const float* __restrict__ ob, const float* __restrict__ ln_w,
               const float* __restrict__ ln_b, float* __restrict__ h2,
               unsigned short* __restrict__ m_in, int S)
{
  const int row = blockIdx.x;
  const int t = threadIdx.x;
  const size_t off = (size_t)row * EMB + t * 4;
  float4 v = *(const float4*)(x + off);
  const float4 obv = ((const float4*)ob)[t];
  v.x += obv.x; v.y += obv.y; v.z += obv.z; v.w += obv.w;
  for (int s = 0; s < S; ++s) {
    const ushort4 p = *(const ushort4*)(part + (size_t)s * TOK * EMB + off);
    v.x += bf2f(p.x); v.y += bf2f(p.y); v.z += bf2f(p.z); v.w += bf2f(p.w);
  }
  *(float4*)(h2 + off) = v;

  float s1 = v.x + v.y + v.z + v.w;
  float s2 = v.x * v.x + v.y * v.y + v.z * v.z + v.w * v.w;
#pragma unroll
  for (int o = 1; o < 64; o <<= 1) { s1 += __shfl_xor(s1, o); s2 += __shfl_xor(s2, o); }
  __shared__ float red[8];
  if ((t & 63) == 0) { red[t >> 6] = s1; red[4 + (t >> 6)] = s2; }
  __syncthreads();
  s1 = red[0] + red[1] + red[2] + red[3];
  s2 = red[4] + red[5] + red[6] + red[7];
  const float mu = s1 * (1.f / EMB);
  const float rs = rsqrtf(s2 * (1.f / EMB) - mu * mu + 1e-5f);
  const float4 wv = ((const float4*)ln_w)[t];
  const float4 bv = ((const float4*)ln_b)[t];
  ushort4 o;
  o.x = f2bf((v.x - mu) * rs * wv.x + bv.x);
  o.y = f2bf((v.y - mu) * rs * wv.y + bv.y);
  o.z = f2bf((v.z - mu) * rs * wv.z + bv.z);
  o.w = f2bf((v.w - mu) * rs * wv.w + bv.w);
  ((ushort4*)(m_in + (size_t)row * EMB))[t] = o;
}

// ---------------- LayerNorm fp32 -> bf16 (one block per row of 1024)
__global__ __launch_bounds__(256)
void ln_bf16(const float* __restrict__ x, const float* __restrict__ wt,
             const float* __restrict__ bs, unsigned short* __restrict__ out)
{
  const int row = blockIdx.x;
  const int t = threadIdx.x;
  const float4 v = ((const float4*)(x + (size_t)row * EMB))[t];
  float s = v.x + v.y + v.z + v.w;
  float s2 = v.x * v.x + v.y * v.y + v.z * v.z + v.w * v.w;
#pragma unroll
  for (int off = 1; off < 64; off <<= 1) { s += __shfl_xor(s, off); s2 += __shfl_xor(s2, off); }
  __shared__ float red[8];
  if ((t & 63) == 0) { red[t >> 6] = s; red[4 + (t >> 6)] = s2; }
  __syncthreads();
  s = red[0] + red[1] + red[2] + red[3];
  s2 = red[4] + red[5] + red[6] + red[7];
  const float mu = s * (1.f / EMB);
  const float rs = rsqrtf(s2 * (1.f / EMB) - mu * mu + 1e-5f);
  const float4 wv = ((const float4*)wt)[t];
  const float4 bv = ((const float4*)bs)[t];
  ushort4 o;
  o.x = f2bf((v.x - mu) * rs * wv.x + bv.x);
  o.y = f2bf((v.y - mu) * rs * wv.y + bv.y);
  o.z = f2bf((v.z - mu) * rs * wv.z + bv.z);
  o.w = f2bf((v.w - mu) * rs * wv.w + bv.w);
  ((ushort4*)(out + (size_t)row * EMB))[t] = o;
}

// ---------------- fp32 -> bf16 conversion of all four weight matrices, one launch
#define Q0 786432            // in_proj_w quads (3072*1024/4)
#define Q1 (Q0 + 262144)     // + out_w
#define Q2 (Q1 + 1048576)    // + w1
#define Q3 (Q2 + 1048576)    // + w2
__global__ __launch_bounds__(256)
void cvt4(const float* __restrict__ s0, const float* __restrict__ s1,
          const float* __restrict__ s2, const float* __restrict__ s3,
          unsigned short* __restrict__ d0, unsigned short* __restrict__ d1,
          unsigned short* __restrict__ d2, unsigned short* __restrict__ d3)
{
  const int i = blockIdx.x * 256 + threadIdx.x;
  const float* s; unsigned short* d; int off;
  if (i < Q0)      { s = s0; d = d0; off = i; }
  else if (i < Q1) { s = s1; d = d1; off = i - Q0; }
  else if (i < Q2) { s = s2; d = d2; off = i - Q1; }
  else             { s = s3; d = d3; off = i - Q2; }
  const float4 v = ((const float4*)s)[off];
  ushort4 o;
  o.x = f2bf(v.x); o.y = f2bf(v.y); o.z = f2bf(v.z); o.w = f2bf(v.w);
  ((ushort4*)d)[off] = o;
}

// ---------------- sliding-window causal attention, flash-style
__global__ __launch_bounds__(256)
void attn_win(const unsigned short* __restrict__ qkv, unsigned short* __restrict__ aout)
{
  __shared__ unsigned short Ks[64 * 136];
  __shared__ unsigned short Vt[128 * 72];
  __shared__ unsigned short Ps[4 * 16 * 72];
  const int bh = blockIdx.y;
  const int b = bh >> 3, hh = bh & 7;
  const int q0 = blockIdx.x << 6;
  const int tid = threadIdx.x, lane = tid & 63, w = tid >> 6;
  const int l15 = lane & 15, lhi = lane >> 4;
  const size_t base = (size_t)b * 2048 * 3072;

  s16x8 qf[4];
  {
    const unsigned short* qp = qkv + base + (size_t)(q0 + w * 16 + l15) * 3072 + hh * 128 + lhi * 8;
#pragma unroll
    for (int ks = 0; ks < 4; ++ks) qf[ks] = *(const s16x8*)(qp + ks * 32);
  }

  f32x4 o[8];
#pragma unroll
  for (int n = 0; n < 8; ++n)
#pragma unroll
    for (int j = 0; j < 4; ++j) o[n][j] = 0.f;
  float mrow[4] = {-1e30f, -1e30f, -1e30f, -1e30f};
  float lrow[4] = {0.f, 0.f, 0.f, 0.f};

  for (int t = 0; t < 5; ++t) {
    const int kt0 = q0 - 256 + t * 64;
    if (kt0 < 0) continue;
    __syncthreads();
    {
      const unsigned short* kg = qkv + base + (size_t)kt0 * 3072 + 1024 + hh * 128;
#pragma unroll
      for (int i = 0; i < 4; ++i) {
        const int c = tid + i * 256;
        const int r = c >> 4, cc = (c & 15) << 3;
        *(s16x8*)(Ks + r * 136 + cc) = *(const s16x8*)(kg + (size_t)r * 3072 + cc);
      }
      const unsigned short* vg = qkv + base + (size_t)kt0 * 3072 + 2048 + hh * 128;
#pragma unroll
      for (int i = 0; i < 2; ++i) {
        const int c = tid + i * 256;
        const int r2 = c >> 4, cc = (c & 15) << 3;
        s16x8 v0 = *(const s16x8*)(vg + (size_t)(2 * r2) * 3072 + cc);
        s16x8 v1 = *(const s16x8*)(vg + (size_t)(2 * r2 + 1) * 3072 + cc);
#pragma unroll
        for (int jj = 0; jj < 8; ++jj) {
          unsigned int pk = (unsigned int)(unsigned short)v0[jj] |
                            ((unsigned int)(unsigned short)v1[jj] << 16);
          *(unsigned int*)(Vt + (cc + jj) * 72 + 2 * r2) = pk;
        }
      }
    }
    __syncthreads();

    f32x4 s[4];
#pragma unroll
    for (int n = 0; n < 4; ++n)
#pragma unroll
      for (int j = 0; j < 4; ++j) s[n][j] = 0.f;
#pragma unroll
    for (int ks = 0; ks < 4; ++ks) {
#pragma unroll
      for (int n = 0; n < 4; ++n) {
        s16x8 kf = *(const s16x8*)(Ks + (n * 16 + l15) * 136 + ks * 32 + lhi * 8);
        s[n] = __builtin_amdgcn_mfma_f32_16x16x32_bf16(qf[ks], kf, s[n], 0, 0, 0);
      }
    }
    const bool mlo = (t == 0);
    const bool mhi = (kt0 == q0);
#pragma unroll
    for (int n = 0; n < 4; ++n) {
      const int kcol = n * 16 + l15;
#pragma unroll
      for (int j = 0; j < 4; ++j) {
        const int qrow = w * 16 + lhi * 4 + j;
        float v = s[n][j] * 0.08838834764831845f;
        if ((mlo && kcol < qrow) || (mhi && kcol > qrow)) v = -1e30f;
        s[n][j] = v;
      }
    }
    float alpha[4];
#pragma unroll
    for (int j = 0; j < 4; ++j) {
      float mx = fmaxf(fmaxf(s[0][j], s[1][j]), fmaxf(s[2][j], s[3][j]));
#pragma unroll
      for (int off = 1; off < 16; off <<= 1) mx = fmaxf(mx, __shfl_xor(mx, off));
      const float mn = fmaxf(mrow[j], mx);
      alpha[j] = __expf(mrow[j] - mn);
      mrow[j] = mn;
    }
    float rowsum[4] = {0.f, 0.f, 0.f, 0.f};
#pragma unroll
    for (int n = 0; n < 4; ++n)
#pragma unroll
      for (int j = 0; j < 4; ++j) {
        const float p = __expf(s[n][j] - mrow[j]);
        rowsum[j] += p;
        Ps[(w * 16 + lhi * 4 + j) * 72 + n * 16 + l15] = f2bf(p);
      }
#pragma unroll
    for (int j = 0; j < 4; ++j) {
      float rs = rowsum[j];
#pragma unroll
      for (int off = 1; off < 16; off <<= 1) rs += __shfl_xor(rs, off);
      lrow[j] = lrow[j] * alpha[j] + rs;
    }
#pragma unroll
    for (int n = 0; n < 8; ++n)
#pragma unroll
      for (int j = 0; j < 4; ++j) o[n][j] *= alpha[j];
#pragma unroll
    for (int ks = 0; ks < 2; ++ks) {
      const s16x8 pf = *(const s16x8*)(Ps + (w * 16 + l15) * 72 + ks * 32 + lhi * 8);
#pragma unroll
      for (int n = 0; n < 8; ++n) {
        const s16x8 vf = *(const s16x8*)(Vt + (n * 16 + l15) * 72 + ks * 32 + lhi * 8);
        o[n] = __builtin_amdgcn_mfma_f32_16x16x32_bf16(pf, vf, o[n], 0, 0, 0);
      }
    }
  }
  unsigned short* op = aout + (size_t)(b * 2048 + q0 + w * 16) * 1024 + hh * 128;
#pragma unroll
  for (int n = 0; n < 8; ++n)
#pragma unroll
    for (int j = 0; j < 4; ++j)
      op[(size_t)(lhi * 4 + j) * 1024 + n * 16 + l15] = f2bf(o[n][j] / lrow[j]);
}

extern "C" void kernel_launch(void* const* d_in, const int* in_sizes, int n_in,
                              void* d_out, int out_size, void* d_ws, size_t ws_size,
                              hipStream_t stream)
{
  (void)in_sizes; (void)n_in; (void)out_size; (void)ws_size;
  const float* x         = (const float*)d_in[0];
  const float* ln1_w     = (const float*)d_in[1];
  const float* ln1_b     = (const float*)d_in[2];
  const float* ln2_w     = (const float*)d_in[3];
  const float* ln2_b     = (const float*)d_in[4];
  const float* in_proj_w = (const float*)d_in[5];
  const float* in_proj_b = (const float*)d_in[6];
  const float* out_w     = (const float*)d_in[7];
  const float* out_b     = (const float*)d_in[8];
  const float* w1        = (const float*)d_in[9];
  const float* b1        = (const float*)d_in[10];
  const float* w2        = (const float*)d_in[11];
  const float* b2        = (const float*)d_in[12];
  float* out = (float*)d_out;

  char* ws = (char*)d_ws;
  unsigned short* h    = (unsigned short*)(ws);                 //  8 MiB  LN1 out bf16
  unsigned short* wqkv = (unsigned short*)(ws + (8u << 20));    //  6 MiB
  unsigned short* wout = (unsigned short*)(ws + (14u << 20));   //  2 MiB
  unsigned short* w1b  = (unsigned short*)(ws + (16u << 20));   //  8 MiB
  unsigned short* w2b  = (unsigned short*)(ws + (24u << 20));   //  8 MiB
  unsigned short* qkv  = (unsigned short*)(ws + (32u << 20));   // 24 MiB
  unsigned short* aout = (unsigned short*)(ws + (56u << 20));   //  8 MiB
  float*          h2   = (float*)(ws + (64u << 20));            // 16 MiB
  unsigned short* m_in = (unsigned short*)(ws + (80u << 20));   //  8 MiB
  unsigned short* act  = (unsigned short*)(ws + (88u << 20));   // 32 MiB (ends 120 MiB)
  unsigned short* part_op = (unsigned short*)(ws + (88u << 20)); // 32 MiB, act region (dead until MLP1)
  unsigned short* part_m2 = (unsigned short*)(ws + (32u << 20)); // 32 MiB, qkv+aout region (dead after out-proj)

  cvt4<<<dim3(Q3 / 256), 256, 0, stream>>>(in_proj_w, out_w, w1, w2, wqkv, wout, w1b, w2b);
  ln_bf16<<<dim3(TOK), 256, 0, stream>>>(x, ln1_w, ln1_b, h);

  // QKV: 256^2 (grid 192), NT=16
  gemm256<0, 0, 16><<<dim3(16 * 12), 512, 0, stream>>>(h, wqkv, in_proj_b, qkv, 4096, 3072, 1024);
  attn_win<<<dim3(32, 16), 256, 0, stream>>>(qkv, aout);

  // out-proj: split-K=4 (grid 64x4, NT=4) -> reduce+res+LN2
  gemm256<0, 1, 4><<<dim3(16 * 4, 4), 512, 0, stream>>>(aout, wout, nullptr, part_op, 4096, 1024, 1024);
  reduce_ln<<<dim3(TOK), 256, 0, stream>>>(part_op, x, out_b, ln2_w, ln2_b, h2, m_in, 4);

  // MLP1: 256^2 (grid 256) + relu, NT=16
  gemm256<1, 0, 16><<<dim3(16 * 16), 512, 0, stream>>>(m_in, w1b, b1, act, 4096, 4096, 1024);

  // MLP2: split-K=4 (grid 64x4, NT=16) -> reduce+bias+res
  gemm256<0, 1, 16><<<dim3(16 * 4, 4), 512, 0, stream>>>(act, w2b, nullptr, part_m2, 4096, 1024, 4096);
  reduce_add<<<dim3(4096 * 1024 / 4 / 256), 256, 0, stream>>>(part_m2, h2, b2, out, 4096 * 1024, 1024, 4);
}